// Round 3
// baseline (871.584 us; speedup 1.0000x reference)
//
#include <hip/hip_runtime.h>

#define DEVINL __device__ __forceinline__

constexpr int N_NODES = 50000;
constexpr int E_EDGES = 800000;
constexpr int HD      = 128;   // hidden dim (4 heads x 32)
constexpr int NG      = 64;    // graphs
constexpr int OUTC    = 64;    // final out channels
constexpr int NPAR    = 22;    // param tensors
constexpr int PAR_TOTAL = 3*(16384+3*128) + (8192+3*64) + 6*128;  // 59456

DEVINL float bf2f(unsigned short u){
  union { unsigned int i; float f; } v; v.i = ((unsigned int)u) << 16; return v.f;
}
DEVINL float lrelu(float v){ return v > 0.f ? v : 0.2f * v; }

// ---------------- runtime dtype detection ----------------
// flags[0] = 1 if ints are int64 (index shift), else 0
// flags[1] = 1 if floats are fp32, else 0 (bf16)
__global__ void k_detect(const unsigned short* __restrict__ x,
                         const int* __restrict__ ei, int* __restrict__ flags){
  __shared__ int s_f32, s_i64;
  int t = threadIdx.x;
  if (t == 0){ s_f32 = 0; s_i64 = 1; }
  __syncthreads();
  // float sniff: bf16-decode first 2048 ushorts; N(0,1) bf16 stays tiny,
  // fp32 low-halves are uniform bits -> huge exponents / NaN appear.
  for (int i = t; i < 2048; i += 256){
    float v = bf2f(x[i]);
    if (!(fabsf(v) < 1e4f)) s_f32 = 1;   // catches huge and NaN
  }
  // int sniff: int64 values < 2^31 have all-zero odd words
  for (int i = t; i < 512; i += 256){
    if (ei[2 * i + 1] != 0) s_i64 = 0;
  }
  __syncthreads();
  if (t == 0){ flags[0] = s_i64; flags[1] = s_f32; }
}

// ---------------- param conversion (any float storage -> fp32 table) ----------------
struct PtrTab { const void* p[NPAR]; int off[NPAR + 1]; };

__global__ void k_cvt_params(PtrTab tab, const int* __restrict__ flags,
                             float* __restrict__ dst){
  int f = flags[1];
  int i = blockIdx.x * 256 + threadIdx.x;
  if (i >= tab.off[NPAR]) return;
  int k = 0;
  while (tab.off[k + 1] <= i) k++;
  int j = i - tab.off[k];
  dst[i] = f ? ((const float*)tab.p[k])[j] : bf2f(((const unsigned short*)tab.p[k])[j]);
}

__global__ void k_cvt_x(const void* __restrict__ x, const int* __restrict__ flags,
                        float* __restrict__ A, int n){
  int i = blockIdx.x * 256 + threadIdx.x;
  if (i >= n) return;
  A[i] = flags[1] ? ((const float*)x)[i] : bf2f(((const unsigned short*)x)[i]);
}

// ---------------- CSR build ----------------
__global__ void k_hist(const int* __restrict__ ei, const int* __restrict__ flags,
                       int* __restrict__ deg){
  int e = blockIdx.x * 256 + threadIdx.x;
  if (e >= E_EDGES) return;
  int f = flags[0];
  int d = ei[(size_t)(E_EDGES + e) << f];
  atomicAdd(&deg[d], 1);
}

// per-block exclusive scan over 1024 elements (256 thr x 4)
__global__ void k_scan1(const int* __restrict__ deg, int* __restrict__ offs,
                        int* __restrict__ bTot, int n){
  __shared__ int lds[256];
  int t = threadIdx.x;
  int base = blockIdx.x * 1024 + t * 4;
  int v[4]; int s = 0;
  #pragma unroll
  for (int i = 0; i < 4; i++){ v[i] = (base + i < n) ? deg[base + i] : 0; s += v[i]; }
  lds[t] = s; __syncthreads();
  #pragma unroll
  for (int off = 1; off < 256; off <<= 1){
    int x2 = (t >= off) ? lds[t - off] : 0;
    __syncthreads();
    lds[t] += x2;
    __syncthreads();
  }
  int excl = lds[t] - s;
  if (t == 255) bTot[blockIdx.x] = lds[255];
  int run = excl;
  #pragma unroll
  for (int i = 0; i < 4; i++){
    if (base + i < n) offs[base + i] = run;
    run += v[i];
  }
}

__global__ void k_scan2(const int* __restrict__ bTot, int* __restrict__ bPref, int nb){
  if (threadIdx.x == 0){
    int run = 0;
    for (int i = 0; i < nb; i++){ bPref[i] = run; run += bTot[i]; }
  }
}

__global__ void k_scan3(int* __restrict__ offs, int* __restrict__ cursor,
                        const int* __restrict__ bPref, int n, int etot){
  int t = threadIdx.x;
  int base = blockIdx.x * 1024 + t * 4;
  int bp = bPref[blockIdx.x];
  #pragma unroll
  for (int i = 0; i < 4; i++){
    int idx = base + i;
    if (idx < n){ int v = offs[idx] + bp; offs[idx] = v; cursor[idx] = v; }
  }
  if (blockIdx.x == 0 && t == 0) offs[n] = etot;
}

__global__ void k_scatter(const int* __restrict__ ei, const int* __restrict__ flags,
                          int* __restrict__ cursor, int* __restrict__ ssrc){
  int e = blockIdx.x * 256 + threadIdx.x;
  if (e >= E_EDGES) return;
  int f = flags[0];
  int s = ei[(size_t)e << f];
  int d = ei[(size_t)(E_EDGES + e) << f];
  int pos = atomicAdd(&cursor[d], 1);
  ssrc[pos] = s;
}

// ---------------- fp32 GEMM: O[n,Mtot] = A[n,128] x W[128,Mtot] ----------------
__global__ __launch_bounds__(256) void k_gemm(const float* __restrict__ A,
                                              const float* __restrict__ W,
                                              float* __restrict__ O, int n, int Mtot){
  __shared__ float As[64][132];   // +4 pad: breaks 128-stride bank aliasing
  __shared__ float Ws[128][68];
  const int t = threadIdx.x;
  const int rowBase = blockIdx.x * 64;
  const int colBase = blockIdx.y * 64;
  for (int f = t; f < 64 * 32; f += 256){
    int r = f >> 5, c4 = (f & 31) << 2;
    float4 v = make_float4(0.f, 0.f, 0.f, 0.f);
    if (rowBase + r < n) v = *(const float4*)(A + (size_t)(rowBase + r) * 128 + c4);
    As[r][c4] = v.x; As[r][c4 + 1] = v.y; As[r][c4 + 2] = v.z; As[r][c4 + 3] = v.w;
  }
  for (int f = t; f < 128 * 16; f += 256){
    int r = f >> 4, c4 = (f & 15) << 2;
    float4 w = *(const float4*)(W + (size_t)r * Mtot + colBase + c4);
    Ws[r][c4] = w.x; Ws[r][c4 + 1] = w.y; Ws[r][c4 + 2] = w.z; Ws[r][c4 + 3] = w.w;
  }
  __syncthreads();
  const int cx = t & 15, ry = t >> 4;
  float acc[4][4];
  #pragma unroll
  for (int i = 0; i < 4; i++)
    #pragma unroll
    for (int j = 0; j < 4; j++) acc[i][j] = 0.f;
  #pragma unroll 4
  for (int k = 0; k < 128; k++){
    float a0 = As[ry][k], a1 = As[ry + 16][k], a2 = As[ry + 32][k], a3 = As[ry + 48][k];
    float4 w = *(const float4*)&Ws[k][cx << 2];
    acc[0][0] += a0 * w.x; acc[0][1] += a0 * w.y; acc[0][2] += a0 * w.z; acc[0][3] += a0 * w.w;
    acc[1][0] += a1 * w.x; acc[1][1] += a1 * w.y; acc[1][2] += a1 * w.z; acc[1][3] += a1 * w.w;
    acc[2][0] += a2 * w.x; acc[2][1] += a2 * w.y; acc[2][2] += a2 * w.z; acc[2][3] += a2 * w.w;
    acc[3][0] += a3 * w.x; acc[3][1] += a3 * w.y; acc[3][2] += a3 * w.z; acc[3][3] += a3 * w.w;
  }
  #pragma unroll
  for (int i = 0; i < 4; i++){
    int r = rowBase + ry + 16 * i;
    if (r < n){
      float4 v; v.x = acc[i][0]; v.y = acc[i][1]; v.z = acc[i][2]; v.w = acc[i][3];
      *(float4*)(O + (size_t)r * Mtot + colBase + (cx << 2)) = v;
    }
  }
}

// ---------------- attention logits: als/ald [n,H] ----------------
template<int HC, int CW>
__global__ void k_alsald(const float* __restrict__ h, const float* __restrict__ a_s,
                         const float* __restrict__ a_d, float* __restrict__ als,
                         float* __restrict__ ald, int n){
  int t = threadIdx.x;
  int node = blockIdx.x * (256 / HC) + t / HC;
  int c = t % HC;
  if (node >= n) return;
  float v = h[(size_t)node * HC + c];
  float s = v * a_s[c];
  float d = v * a_d[c];
  #pragma unroll
  for (int o = CW / 2; o >= 1; o >>= 1){ s += __shfl_xor(s, o); d += __shfl_xor(d, o); }
  if ((c & (CW - 1)) == 0){
    int head = c / CW;
    als[(size_t)node * (HC / CW) + head] = s;
    ald[(size_t)node * (HC / CW) + head] = d;
  }
}

// ---------------- per-node GAT attention + aggregation (one wave / node) ----------------
template<int H, int C>
__global__ __launch_bounds__(256) void k_attn(const float* __restrict__ h,
                      const float* __restrict__ als, const float* __restrict__ ald,
                      const int* __restrict__ offs, const int* __restrict__ ssrc,
                      const float* __restrict__ bias,
                      float* __restrict__ out, int n){
  constexpr int HC = H * C;
  constexpr int CPL = HC / 64;     // channels per lane
  int node = blockIdx.x * 4 + (threadIdx.x >> 6);
  if (node >= n) return;
  int lane = threadIdx.x & 63;
  int c0 = lane * CPL;
  int head = c0 / C;

  float als_all[H], ald_all[H];
  #pragma unroll
  for (int q = 0; q < H; q++){
    als_all[q] = als[(size_t)node * H + q];
    ald_all[q] = ald[(size_t)node * H + q];
  }
  // online softmax state; lane 0 seeds the self-loop
  float m[H], s[H];
  #pragma unroll
  for (int q = 0; q < H; q++){
    float es = lrelu(als_all[q] + ald_all[q]);
    m[q] = (lane == 0) ? es : -1e30f;
    s[q] = (lane == 0) ? 1.f : 0.f;
  }
  int beg = offs[node];
  int deg = offs[node + 1] - beg;
  // pass 1: lanes stride over edges
  for (int j = lane; j < deg; j += 64){
    int src = ssrc[beg + j];
    if constexpr (H == 4){
      float4 av = *(const float4*)(als + (size_t)src * 4);
      float ev[4] = {av.x, av.y, av.z, av.w};
      #pragma unroll
      for (int q = 0; q < 4; q++){
        float e = lrelu(ev[q] + ald_all[q]);
        float mn = fmaxf(m[q], e);
        s[q] = s[q] * __expf(m[q] - mn) + __expf(e - mn);
        m[q] = mn;
      }
    } else {
      float e = lrelu(als[src] + ald_all[0]);
      float mn = fmaxf(m[0], e);
      s[0] = s[0] * __expf(m[0] - mn) + __expf(e - mn);
      m[0] = mn;
    }
  }
  // butterfly combine of (m,s) across the wave
  #pragma unroll
  for (int o = 1; o < 64; o <<= 1){
    #pragma unroll
    for (int q = 0; q < H; q++){
      float mo = __shfl_xor(m[q], o);
      float so = __shfl_xor(s[q], o);
      float mn = fmaxf(m[q], mo);
      s[q] = s[q] * __expf(m[q] - mn) + so * __expf(mo - mn);
      m[q] = mn;
    }
  }
  float mh = m[head];
  float inv_s = 1.f / s[head];

  // pass 2: lanes-as-channels accumulation
  float acc[CPL];
  {
    float wself = __expf(lrelu(als_all[head] + ald_all[head]) - mh);
    #pragma unroll
    for (int i = 0; i < CPL; i++) acc[i] = wself * h[(size_t)node * HC + c0 + i];
  }
  for (int base = 0; base < deg; base += 64){
    int cnt = min(64, deg - base);
    int sid = (lane < cnt) ? ssrc[beg + base + lane] : 0;
    for (int j = 0; j < cnt; j++){
      int src = __shfl(sid, j);
      float e = lrelu(als[(size_t)src * H + head] + ald_all[head]);
      float w = __expf(e - mh);
      if constexpr (CPL == 2){
        float2 hv = *(const float2*)(h + (size_t)src * HC + c0);
        acc[0] += w * hv.x; acc[1] += w * hv.y;
      } else {
        acc[0] += w * h[(size_t)src * HC + c0];
      }
    }
  }
  #pragma unroll
  for (int i = 0; i < CPL; i++)
    out[(size_t)node * HC + c0 + i] = acc[i] * inv_s + bias[c0 + i];
}

// ---------------- batchnorm ----------------
__global__ void k_bn_stats(const float* __restrict__ A, float* __restrict__ bsum,
                           float* __restrict__ bsq, int n){
  __shared__ float ls[256], lq[256];
  int t = threadIdx.x;
  int col = t & 127;
  int rhalf = t >> 7;
  float s = 0.f, q = 0.f;
  for (int r = blockIdx.x * 2 + rhalf; r < n; r += gridDim.x * 2){
    float v = A[(size_t)r * 128 + col];
    s += v; q += v * v;
  }
  ls[t] = s; lq[t] = q; __syncthreads();
  if (t < 128){
    s = ls[t] + ls[t + 128];
    q = lq[t] + lq[t + 128];
    atomicAdd(&bsum[col], s);
    atomicAdd(&bsq[col], q);
  }
}

__global__ void k_bn_apply(float* __restrict__ A, const float* __restrict__ bsum,
                           const float* __restrict__ bsq, const float* __restrict__ g,
                           const float* __restrict__ be, int n){
  int i = blockIdx.x * 256 + threadIdx.x;
  if (i >= n * 128) return;
  int col = i & 127;
  float inv_n = 1.f / (float)n;
  float mu = bsum[col] * inv_n;
  float var = bsq[col] * inv_n - mu * mu;
  float x = (A[i] - mu) * rsqrtf(var + 1e-5f) * g[col] + be[col];
  A[i] = x > 0.f ? x : expm1f(x);   // ELU alpha=1
}

// ---------------- global mean pool ----------------
__global__ void k_group_bounds(const int* __restrict__ bids, const int* __restrict__ flags,
                               int* __restrict__ gstart, int* __restrict__ gend, int n){
  int i = blockIdx.x * 256 + threadIdx.x;
  if (i >= n) return;
  int f = flags[0];
  int g = bids[(size_t)i << f];
  if (i == 0 || bids[(size_t)(i - 1) << f] != g) gstart[g] = i;
  if (i == n - 1 || bids[(size_t)(i + 1) << f] != g) gend[g] = i + 1;
}

__global__ void k_pool_acc(const float* __restrict__ A, const int* __restrict__ bids,
                           const int* __restrict__ flags, float* __restrict__ sums, int n){
  int t = threadIdx.x;
  int f = flags[0];
  int col = t & 63;
  int rsub = t >> 6;                // 0..3
  int r0 = blockIdx.x * 128;
  float acc = 0.f; int cur = -1;
  for (int i = 0; i < 32; i++){
    int r = r0 + rsub + i * 4;
    if (r >= n) break;
    int g = bids[(size_t)r << f];
    if (g != cur){
      if (cur >= 0) atomicAdd(&sums[cur * 64 + col], acc);
      cur = g; acc = 0.f;
    }
    acc += A[(size_t)r * 64 + col];
  }
  if (cur >= 0) atomicAdd(&sums[cur * 64 + col], acc);
}

__global__ void k_pool_fin(const float* __restrict__ sums, const int* __restrict__ gstart,
                           const int* __restrict__ gend, float* __restrict__ out){
  int i = blockIdx.x * 256 + threadIdx.x;
  if (i >= NG * OUTC) return;
  int g = i >> 6;
  int cnt = gend[g] - gstart[g];
  float c = (float)(cnt > 1 ? cnt : 1);
  out[i] = sums[i] / c;    // OUTPUT IS FP32 (reference returns float32)
}

extern "C" void kernel_launch(void* const* d_in, const int* in_sizes, int n_in,
                              void* d_out, int out_size, void* d_ws, size_t ws_size,
                              hipStream_t stream){
  const unsigned short* x    = (const unsigned short*)d_in[0];
  const int*            ei   = (const int*)d_in[1];
  const int*            bids = (const int*)d_in[2];

  char* p = (char*)d_ws;
  auto carve = [&](size_t bytes) -> void* {
    void* r = (void*)p; p += (bytes + 255) & ~size_t(255); return r;
  };
  float* A      = (float*)carve((size_t)N_NODES * HD * 4);
  float* B      = (float*)carve((size_t)N_NODES * HD * 4);
  float* par    = (float*)carve((size_t)PAR_TOTAL * 4);
  float* als    = (float*)carve((size_t)N_NODES * 4 * 4);
  float* ald    = (float*)carve((size_t)N_NODES * 4 * 4);
  int*   deg    = (int*)carve((size_t)N_NODES * 4);
  int*   offs   = (int*)carve((size_t)(N_NODES + 1) * 4);
  int*   cursor = (int*)carve((size_t)N_NODES * 4);
  int*   ssrc   = (int*)carve((size_t)E_EDGES * 4);
  int*   bTot   = (int*)carve(256);
  int*   bPref  = (int*)carve(256);
  int*   flags  = (int*)carve(256);
  float* bnbuf  = (float*)carve(1024);          // bn_sum[128] | bn_sq[128]
  float* psum   = (float*)carve(NG * OUTC * 4); // 16384B
  int*   gstart = (int*)carve(256);
  int*   gend   = (int*)carve(256);
  float* bn_sum = bnbuf;
  float* bn_sq  = bnbuf + 128;

  // ---- build param conversion table (dict order indices 3..24) ----
  PtrTab tab;
  int sizes[NPAR];
  // order: W0,as0,ad0,b0, W1,..., W3,as3,ad3,b3, g0,be0,g1,be1,g2,be2
  for (int l = 0; l < 4; l++){
    int base = 3 + 4 * l;
    tab.p[4 * l + 0] = d_in[base + 0]; sizes[4 * l + 0] = (l < 3) ? 16384 : 8192; // W
    tab.p[4 * l + 1] = d_in[base + 1]; sizes[4 * l + 1] = (l < 3) ? 128 : 64;     // as
    tab.p[4 * l + 2] = d_in[base + 2]; sizes[4 * l + 2] = (l < 3) ? 128 : 64;     // ad
    tab.p[4 * l + 3] = d_in[base + 3]; sizes[4 * l + 3] = (l < 3) ? 128 : 64;     // b
  }
  for (int l = 0; l < 3; l++){
    tab.p[16 + 2 * l]     = d_in[19 + 2 * l];     sizes[16 + 2 * l] = 128;  // g
    tab.p[16 + 2 * l + 1] = d_in[19 + 2 * l + 1]; sizes[16 + 2 * l + 1] = 128; // be
  }
  tab.off[0] = 0;
  for (int k = 0; k < NPAR; k++) tab.off[k + 1] = tab.off[k] + sizes[k];
  const float* pW[4], *pAS[4], *pAD[4], *pB[4], *pG[3], *pBE[3];
  for (int l = 0; l < 4; l++){
    pW[l]  = par + tab.off[4 * l + 0];
    pAS[l] = par + tab.off[4 * l + 1];
    pAD[l] = par + tab.off[4 * l + 2];
    pB[l]  = par + tab.off[4 * l + 3];
  }
  for (int l = 0; l < 3; l++){
    pG[l]  = par + tab.off[16 + 2 * l];
    pBE[l] = par + tab.off[16 + 2 * l + 1];
  }

  // ---- dtype detection + conversions ----
  k_detect<<<1, 256, 0, stream>>>(x, ei, flags);
  k_cvt_params<<<(PAR_TOTAL + 255) / 256, 256, 0, stream>>>(tab, flags, par);
  k_cvt_x<<<(N_NODES * HD + 255) / 256, 256, 0, stream>>>((const void*)x, flags, A, N_NODES * HD);

  // ---- CSR build (self-loops implicit) ----
  hipMemsetAsync(deg, 0, (size_t)N_NODES * 4, stream);
  k_hist<<<(E_EDGES + 255) / 256, 256, 0, stream>>>(ei, flags, deg);
  int nb = (N_NODES + 1023) / 1024;  // 49
  k_scan1<<<nb, 256, 0, stream>>>(deg, offs, bTot, N_NODES);
  k_scan2<<<1, 64, 0, stream>>>(bTot, bPref, nb);
  k_scan3<<<nb, 256, 0, stream>>>(offs, cursor, bPref, N_NODES, E_EDGES);
  k_scatter<<<(E_EDGES + 255) / 256, 256, 0, stream>>>(ei, flags, cursor, ssrc);

  // ---- 3 GAT(4x32) + BN + ELU layers ----
  for (int l = 0; l < 3; l++){
    k_gemm<<<dim3((N_NODES + 63) / 64, 2), 256, 0, stream>>>(A, pW[l], B, N_NODES, 128);
    k_alsald<128, 32><<<(N_NODES + 1) / 2, 256, 0, stream>>>(B, pAS[l], pAD[l], als, ald, N_NODES);
    k_attn<4, 32><<<(N_NODES + 3) / 4, 256, 0, stream>>>(B, als, ald, offs, ssrc, pB[l], A, N_NODES);
    hipMemsetAsync(bnbuf, 0, 1024, stream);
    k_bn_stats<<<256, 256, 0, stream>>>(A, bn_sum, bn_sq, N_NODES);
    k_bn_apply<<<(N_NODES * HD + 255) / 256, 256, 0, stream>>>(A, bn_sum, bn_sq, pG[l], pBE[l], N_NODES);
  }

  // ---- final GAT(1x64) ----
  k_gemm<<<dim3((N_NODES + 63) / 64, 1), 256, 0, stream>>>(A, pW[3], B, N_NODES, 64);
  k_alsald<64, 64><<<(N_NODES + 3) / 4, 256, 0, stream>>>(B, pAS[3], pAD[3], als, ald, N_NODES);
  k_attn<1, 64><<<(N_NODES + 3) / 4, 256, 0, stream>>>(B, als, ald, offs, ssrc, pB[3], A, N_NODES);

  // ---- global mean pool ----
  hipMemsetAsync(psum, 0, (size_t)NG * OUTC * 4 + 512, stream);  // psum + gstart + gend
  k_group_bounds<<<(N_NODES + 255) / 256, 256, 0, stream>>>(bids, flags, gstart, gend, N_NODES);
  k_pool_acc<<<(N_NODES + 127) / 128, 256, 0, stream>>>(A, bids, flags, psum, N_NODES);
  k_pool_fin<<<16, 256, 0, stream>>>(psum, gstart, gend, (float*)d_out);
}

// Round 4
// 787.158 us; speedup vs baseline: 1.1073x; 1.1073x over previous
//
#include <hip/hip_runtime.h>

#define DEVINL __device__ __forceinline__

constexpr int N_NODES = 50000;
constexpr int E_EDGES = 800000;
constexpr int HD      = 128;   // hidden dim (4 heads x 32)
constexpr int NG      = 64;    // graphs
constexpr int OUTC    = 64;    // final out channels
constexpr int NPAR    = 22;    // param tensors
constexpr int PAR_TOTAL = 3*(16384+3*128) + (8192+3*64) + 6*128;  // 59456

DEVINL float bf2f(unsigned short u){
  union { unsigned int i; float f; } v; v.i = ((unsigned int)u) << 16; return v.f;
}
DEVINL float lrelu(float v){ return v > 0.f ? v : 0.2f * v; }

// ---------------- runtime dtype detection ----------------
// flags[0] = 1 if ints are int64 (index shift), else 0
// flags[1] = 1 if floats are fp32, else 0 (bf16)
__global__ void k_detect(const unsigned short* __restrict__ x,
                         const int* __restrict__ ei, int* __restrict__ flags){
  __shared__ int s_f32, s_i64;
  int t = threadIdx.x;
  if (t == 0){ s_f32 = 0; s_i64 = 1; }
  __syncthreads();
  for (int i = t; i < 2048; i += 256){
    float v = bf2f(x[i]);
    if (!(fabsf(v) < 1e4f)) s_f32 = 1;   // catches huge and NaN
  }
  for (int i = t; i < 512; i += 256){
    if (ei[2 * i + 1] != 0) s_i64 = 0;
  }
  __syncthreads();
  if (t == 0){ flags[0] = s_i64; flags[1] = s_f32; }
}

// ---------------- param conversion (any float storage -> fp32 table) ----------------
struct PtrTab { const void* p[NPAR]; int off[NPAR + 1]; };

__global__ void k_cvt_params(PtrTab tab, const int* __restrict__ flags,
                             float* __restrict__ dst){
  int f = flags[1];
  int i = blockIdx.x * 256 + threadIdx.x;
  if (i >= tab.off[NPAR]) return;
  int k = 0;
  while (tab.off[k + 1] <= i) k++;
  int j = i - tab.off[k];
  dst[i] = f ? ((const float*)tab.p[k])[j] : bf2f(((const unsigned short*)tab.p[k])[j]);
}

__global__ void k_cvt_x(const void* __restrict__ x, const int* __restrict__ flags,
                        float* __restrict__ A, int n){
  int i = blockIdx.x * 256 + threadIdx.x;
  if (i >= n) return;
  A[i] = flags[1] ? ((const float*)x)[i] : bf2f(((const unsigned short*)x)[i]);
}

// ---------------- CSR build ----------------
__global__ void k_hist(const int* __restrict__ ei, const int* __restrict__ flags,
                       int* __restrict__ deg){
  int e = blockIdx.x * 256 + threadIdx.x;
  if (e >= E_EDGES) return;
  int f = flags[0];
  int d = ei[(size_t)(E_EDGES + e) << f];
  atomicAdd(&deg[d], 1);
}

__global__ void k_scan1(const int* __restrict__ deg, int* __restrict__ offs,
                        int* __restrict__ bTot, int n){
  __shared__ int lds[256];
  int t = threadIdx.x;
  int base = blockIdx.x * 1024 + t * 4;
  int v[4]; int s = 0;
  #pragma unroll
  for (int i = 0; i < 4; i++){ v[i] = (base + i < n) ? deg[base + i] : 0; s += v[i]; }
  lds[t] = s; __syncthreads();
  #pragma unroll
  for (int off = 1; off < 256; off <<= 1){
    int x2 = (t >= off) ? lds[t - off] : 0;
    __syncthreads();
    lds[t] += x2;
    __syncthreads();
  }
  int excl = lds[t] - s;
  if (t == 255) bTot[blockIdx.x] = lds[255];
  int run = excl;
  #pragma unroll
  for (int i = 0; i < 4; i++){
    if (base + i < n) offs[base + i] = run;
    run += v[i];
  }
}

__global__ void k_scan2(const int* __restrict__ bTot, int* __restrict__ bPref, int nb){
  if (threadIdx.x == 0){
    int run = 0;
    for (int i = 0; i < nb; i++){ bPref[i] = run; run += bTot[i]; }
  }
}

__global__ void k_scan3(int* __restrict__ offs, int* __restrict__ cursor,
                        const int* __restrict__ bPref, int n, int etot){
  int t = threadIdx.x;
  int base = blockIdx.x * 1024 + t * 4;
  int bp = bPref[blockIdx.x];
  #pragma unroll
  for (int i = 0; i < 4; i++){
    int idx = base + i;
    if (idx < n){ int v = offs[idx] + bp; offs[idx] = v; cursor[idx] = v; }
  }
  if (blockIdx.x == 0 && t == 0) offs[n] = etot;
}

__global__ void k_scatter(const int* __restrict__ ei, const int* __restrict__ flags,
                          int* __restrict__ cursor, int* __restrict__ ssrc){
  int e = blockIdx.x * 256 + threadIdx.x;
  if (e >= E_EDGES) return;
  int f = flags[0];
  int s = ei[(size_t)e << f];
  int d = ei[(size_t)(E_EDGES + e) << f];
  int pos = atomicAdd(&cursor[d], 1);
  ssrc[pos] = s;
}

// ---------------- fp32 GEMM: O[n,Mtot] = A[n,128] x W[128,Mtot] ----------------
__global__ __launch_bounds__(256) void k_gemm(const float* __restrict__ A,
                                              const float* __restrict__ W,
                                              float* __restrict__ O, int n, int Mtot){
  __shared__ float As[64][132];   // row stride 528B (16B-aligned), +4 pad
  __shared__ float Ws[128][68];   // row stride 272B (16B-aligned)
  const int t = threadIdx.x;
  const int rowBase = blockIdx.x * 64;
  const int colBase = blockIdx.y * 64;
  for (int f = t; f < 64 * 32; f += 256){
    int r = f >> 5, c4 = (f & 31) << 2;
    float4 v = make_float4(0.f, 0.f, 0.f, 0.f);
    if (rowBase + r < n) v = *(const float4*)(A + (size_t)(rowBase + r) * 128 + c4);
    As[r][c4] = v.x; As[r][c4 + 1] = v.y; As[r][c4 + 2] = v.z; As[r][c4 + 3] = v.w;
  }
  for (int f = t; f < 128 * 16; f += 256){
    int r = f >> 4, c4 = (f & 15) << 2;
    float4 w = *(const float4*)(W + (size_t)r * Mtot + colBase + c4);
    Ws[r][c4] = w.x; Ws[r][c4 + 1] = w.y; Ws[r][c4 + 2] = w.z; Ws[r][c4 + 3] = w.w;
  }
  __syncthreads();
  const int cx = t & 15, ry = t >> 4;
  float acc[4][4];
  #pragma unroll
  for (int i = 0; i < 4; i++)
    #pragma unroll
    for (int j = 0; j < 4; j++) acc[i][j] = 0.f;
  for (int k = 0; k < 128; k += 4){
    float4 a0 = *(const float4*)&As[ry][k];
    float4 a1 = *(const float4*)&As[ry + 16][k];
    float4 a2 = *(const float4*)&As[ry + 32][k];
    float4 a3 = *(const float4*)&As[ry + 48][k];
    #pragma unroll
    for (int kk = 0; kk < 4; kk++){
      float4 w = *(const float4*)&Ws[k + kk][cx << 2];
      float v0 = (&a0.x)[kk], v1 = (&a1.x)[kk], v2 = (&a2.x)[kk], v3 = (&a3.x)[kk];
      acc[0][0] += v0 * w.x; acc[0][1] += v0 * w.y; acc[0][2] += v0 * w.z; acc[0][3] += v0 * w.w;
      acc[1][0] += v1 * w.x; acc[1][1] += v1 * w.y; acc[1][2] += v1 * w.z; acc[1][3] += v1 * w.w;
      acc[2][0] += v2 * w.x; acc[2][1] += v2 * w.y; acc[2][2] += v2 * w.z; acc[2][3] += v2 * w.w;
      acc[3][0] += v3 * w.x; acc[3][1] += v3 * w.y; acc[3][2] += v3 * w.z; acc[3][3] += v3 * w.w;
    }
  }
  #pragma unroll
  for (int i = 0; i < 4; i++){
    int r = rowBase + ry + 16 * i;
    if (r < n){
      float4 v; v.x = acc[i][0]; v.y = acc[i][1]; v.z = acc[i][2]; v.w = acc[i][3];
      *(float4*)(O + (size_t)r * Mtot + colBase + (cx << 2)) = v;
    }
  }
}

// ---------------- attention logits: als/ald [n,H] ----------------
template<int HC, int CW>
__global__ void k_alsald(const float* __restrict__ h, const float* __restrict__ a_s,
                         const float* __restrict__ a_d, float* __restrict__ als,
                         float* __restrict__ ald, int n){
  int t = threadIdx.x;
  int node = blockIdx.x * (256 / HC) + t / HC;
  int c = t % HC;
  if (node >= n) return;
  float v = h[(size_t)node * HC + c];
  float s = v * a_s[c];
  float d = v * a_d[c];
  #pragma unroll
  for (int o = CW / 2; o >= 1; o >>= 1){ s += __shfl_xor(s, o); d += __shfl_xor(d, o); }
  if ((c & (CW - 1)) == 0){
    int head = c / CW;
    als[(size_t)node * (HC / CW) + head] = s;
    ald[(size_t)node * (HC / CW) + head] = d;
  }
}

// ---------------- per-node GAT attention + aggregation ----------------
// One wave per node; 4 edge-groups x 16 lanes; single pass (no max-sub:
// logits bounded well below fp32 exp overflow, alpha is scale-invariant).
template<int H, int C>
__global__ __launch_bounds__(256) void k_attn(const float* __restrict__ h,
                      const float* __restrict__ als, const float* __restrict__ ald,
                      const int* __restrict__ offs, const int* __restrict__ ssrc,
                      const float* __restrict__ bias,
                      float* __restrict__ out, int n){
  constexpr int HC = H * C;
  constexpr int CPL = HC / 16;        // channels per lane: 8 (4x32) or 4 (1x64)
  int node = blockIdx.x * 4 + (threadIdx.x >> 6);
  if (node >= n) return;
  int lane = threadIdx.x & 63;
  int grp  = lane >> 4;               // edge slot 0..3
  int sub  = lane & 15;
  int c0   = sub * CPL;               // lane's channels (single head each)
  int head = c0 / C;

  float ald_h = ald[(size_t)node * H + head];

  float ssum = 0.f;
  float acc[CPL];
  #pragma unroll
  for (int i = 0; i < CPL; i++) acc[i] = 0.f;
  if (grp == 0){                      // self-loop seeded once
    float w = __expf(lrelu(als[(size_t)node * H + head] + ald_h));
    ssum = w;
    #pragma unroll
    for (int i = 0; i < CPL; i++) acc[i] = w * h[(size_t)node * HC + c0 + i];
  }
  int beg = offs[node];
  int deg = offs[node + 1] - beg;
  for (int base = grp; base < deg; base += 4){
    int src = ssrc[beg + base];
    float w = __expf(lrelu(als[(size_t)src * H + head] + ald_h));
    ssum += w;
    const float* hp = h + (size_t)src * HC + c0;
    if constexpr (CPL == 8){
      float4 h0 = *(const float4*)hp;
      float4 h1 = *(const float4*)(hp + 4);
      acc[0] += w * h0.x; acc[1] += w * h0.y; acc[2] += w * h0.z; acc[3] += w * h0.w;
      acc[4] += w * h1.x; acc[5] += w * h1.y; acc[6] += w * h1.z; acc[7] += w * h1.w;
    } else {
      float4 h0 = *(const float4*)hp;
      acc[0] += w * h0.x; acc[1] += w * h0.y; acc[2] += w * h0.z; acc[3] += w * h0.w;
    }
  }
  // combine the 4 edge-groups (groups partition edges; quad lanes share head)
  #pragma unroll
  for (int o = 16; o < 64; o <<= 1){
    ssum += __shfl_xor(ssum, o);
    #pragma unroll
    for (int i = 0; i < CPL; i++) acc[i] += __shfl_xor(acc[i], o);
  }
  if (grp == 0){
    float inv_s = 1.f / ssum;
    float* op = out + (size_t)node * HC + c0;
    if constexpr (CPL == 8){
      float4 o0 = make_float4(acc[0]*inv_s + bias[c0+0], acc[1]*inv_s + bias[c0+1],
                              acc[2]*inv_s + bias[c0+2], acc[3]*inv_s + bias[c0+3]);
      float4 o1 = make_float4(acc[4]*inv_s + bias[c0+4], acc[5]*inv_s + bias[c0+5],
                              acc[6]*inv_s + bias[c0+6], acc[7]*inv_s + bias[c0+7]);
      *(float4*)op = o0; *(float4*)(op + 4) = o1;
    } else {
      float4 o0 = make_float4(acc[0]*inv_s + bias[c0+0], acc[1]*inv_s + bias[c0+1],
                              acc[2]*inv_s + bias[c0+2], acc[3]*inv_s + bias[c0+3]);
      *(float4*)op = o0;
    }
  }
}

// ---------------- batchnorm ----------------
__global__ void k_bn_stats(const float* __restrict__ A, float* __restrict__ bsum,
                           float* __restrict__ bsq, int n){
  __shared__ float ls[256], lq[256];
  int t = threadIdx.x;
  int col = t & 127;
  int rhalf = t >> 7;
  float s = 0.f, q = 0.f;
  for (int r = blockIdx.x * 2 + rhalf; r < n; r += gridDim.x * 2){
    float v = A[(size_t)r * 128 + col];
    s += v; q += v * v;
  }
  ls[t] = s; lq[t] = q; __syncthreads();
  if (t < 128){
    s = ls[t] + ls[t + 128];
    q = lq[t] + lq[t + 128];
    atomicAdd(&bsum[col], s);
    atomicAdd(&bsq[col], q);
  }
}

__global__ void k_bn_apply(float* __restrict__ A, const float* __restrict__ bsum,
                           const float* __restrict__ bsq, const float* __restrict__ g,
                           const float* __restrict__ be, int n){
  int i = blockIdx.x * 256 + threadIdx.x;
  if (i >= n * 128) return;
  int col = i & 127;
  float inv_n = 1.f / (float)n;
  float mu = bsum[col] * inv_n;
  float var = bsq[col] * inv_n - mu * mu;
  float x = (A[i] - mu) * rsqrtf(var + 1e-5f) * g[col] + be[col];
  A[i] = x > 0.f ? x : expm1f(x);   // ELU alpha=1
}

// ---------------- global mean pool ----------------
__global__ void k_group_bounds(const int* __restrict__ bids, const int* __restrict__ flags,
                               int* __restrict__ gstart, int* __restrict__ gend, int n){
  int i = blockIdx.x * 256 + threadIdx.x;
  if (i >= n) return;
  int f = flags[0];
  int g = bids[(size_t)i << f];
  if (i == 0 || bids[(size_t)(i - 1) << f] != g) gstart[g] = i;
  if (i == n - 1 || bids[(size_t)(i + 1) << f] != g) gend[g] = i + 1;
}

__global__ void k_pool_acc(const float* __restrict__ A, const int* __restrict__ bids,
                           const int* __restrict__ flags, float* __restrict__ sums, int n){
  int t = threadIdx.x;
  int f = flags[0];
  int col = t & 63;
  int rsub = t >> 6;                // 0..3
  int r0 = blockIdx.x * 128;
  float acc = 0.f; int cur = -1;
  for (int i = 0; i < 32; i++){
    int r = r0 + rsub + i * 4;
    if (r >= n) break;
    int g = bids[(size_t)r << f];
    if (g != cur){
      if (cur >= 0) atomicAdd(&sums[cur * 64 + col], acc);
      cur = g; acc = 0.f;
    }
    acc += A[(size_t)r * 64 + col];
  }
  if (cur >= 0) atomicAdd(&sums[cur * 64 + col], acc);
}

__global__ void k_pool_fin(const float* __restrict__ sums, const int* __restrict__ gstart,
                           const int* __restrict__ gend, float* __restrict__ out){
  int i = blockIdx.x * 256 + threadIdx.x;
  if (i >= NG * OUTC) return;
  int g = i >> 6;
  int cnt = gend[g] - gstart[g];
  float c = (float)(cnt > 1 ? cnt : 1);
  out[i] = sums[i] / c;    // output is fp32
}

extern "C" void kernel_launch(void* const* d_in, const int* in_sizes, int n_in,
                              void* d_out, int out_size, void* d_ws, size_t ws_size,
                              hipStream_t stream){
  const unsigned short* x    = (const unsigned short*)d_in[0];
  const int*            ei   = (const int*)d_in[1];
  const int*            bids = (const int*)d_in[2];

  char* p = (char*)d_ws;
  auto carve = [&](size_t bytes) -> void* {
    void* r = (void*)p; p += (bytes + 255) & ~size_t(255); return r;
  };
  float* A      = (float*)carve((size_t)N_NODES * HD * 4);
  float* B      = (float*)carve((size_t)N_NODES * HD * 4);
  float* par    = (float*)carve((size_t)PAR_TOTAL * 4);
  float* als    = (float*)carve((size_t)N_NODES * 4 * 4);
  float* ald    = (float*)carve((size_t)N_NODES * 4 * 4);
  int*   deg    = (int*)carve((size_t)N_NODES * 4);
  int*   offs   = (int*)carve((size_t)(N_NODES + 1) * 4);
  int*   cursor = (int*)carve((size_t)N_NODES * 4);
  int*   ssrc   = (int*)carve((size_t)E_EDGES * 4);
  int*   bTot   = (int*)carve(256);
  int*   bPref  = (int*)carve(256);
  int*   flags  = (int*)carve(256);
  float* bnbuf  = (float*)carve(1024);          // bn_sum[128] | bn_sq[128]
  float* psum   = (float*)carve(NG * OUTC * 4); // 16384B
  int*   gstart = (int*)carve(256);
  int*   gend   = (int*)carve(256);
  float* bn_sum = bnbuf;
  float* bn_sq  = bnbuf + 128;

  // ---- build param conversion table (dict order indices 3..24) ----
  PtrTab tab;
  int sizes[NPAR];
  for (int l = 0; l < 4; l++){
    int base = 3 + 4 * l;
    tab.p[4 * l + 0] = d_in[base + 0]; sizes[4 * l + 0] = (l < 3) ? 16384 : 8192; // W
    tab.p[4 * l + 1] = d_in[base + 1]; sizes[4 * l + 1] = (l < 3) ? 128 : 64;     // as
    tab.p[4 * l + 2] = d_in[base + 2]; sizes[4 * l + 2] = (l < 3) ? 128 : 64;     // ad
    tab.p[4 * l + 3] = d_in[base + 3]; sizes[4 * l + 3] = (l < 3) ? 128 : 64;     // b
  }
  for (int l = 0; l < 3; l++){
    tab.p[16 + 2 * l]     = d_in[19 + 2 * l];     sizes[16 + 2 * l] = 128;  // g
    tab.p[16 + 2 * l + 1] = d_in[19 + 2 * l + 1]; sizes[16 + 2 * l + 1] = 128; // be
  }
  tab.off[0] = 0;
  for (int k = 0; k < NPAR; k++) tab.off[k + 1] = tab.off[k] + sizes[k];
  const float* pW[4], *pAS[4], *pAD[4], *pB[4], *pG[3], *pBE[3];
  for (int l = 0; l < 4; l++){
    pW[l]  = par + tab.off[4 * l + 0];
    pAS[l] = par + tab.off[4 * l + 1];
    pAD[l] = par + tab.off[4 * l + 2];
    pB[l]  = par + tab.off[4 * l + 3];
  }
  for (int l = 0; l < 3; l++){
    pG[l]  = par + tab.off[16 + 2 * l];
    pBE[l] = par + tab.off[16 + 2 * l + 1];
  }

  // ---- dtype detection + conversions ----
  k_detect<<<1, 256, 0, stream>>>(x, ei, flags);
  k_cvt_params<<<(PAR_TOTAL + 255) / 256, 256, 0, stream>>>(tab, flags, par);
  k_cvt_x<<<(N_NODES * HD + 255) / 256, 256, 0, stream>>>((const void*)x, flags, A, N_NODES * HD);

  // ---- CSR build (self-loops implicit) ----
  hipMemsetAsync(deg, 0, (size_t)N_NODES * 4, stream);
  k_hist<<<(E_EDGES + 255) / 256, 256, 0, stream>>>(ei, flags, deg);
  int nb = (N_NODES + 1023) / 1024;  // 49
  k_scan1<<<nb, 256, 0, stream>>>(deg, offs, bTot, N_NODES);
  k_scan2<<<1, 64, 0, stream>>>(bTot, bPref, nb);
  k_scan3<<<nb, 256, 0, stream>>>(offs, cursor, bPref, N_NODES, E_EDGES);
  k_scatter<<<(E_EDGES + 255) / 256, 256, 0, stream>>>(ei, flags, cursor, ssrc);

  // ---- 3 GAT(4x32) + BN + ELU layers ----
  for (int l = 0; l < 3; l++){
    k_gemm<<<dim3((N_NODES + 63) / 64, 2), 256, 0, stream>>>(A, pW[l], B, N_NODES, 128);
    k_alsald<128, 32><<<(N_NODES + 1) / 2, 256, 0, stream>>>(B, pAS[l], pAD[l], als, ald, N_NODES);
    k_attn<4, 32><<<(N_NODES + 3) / 4, 256, 0, stream>>>(B, als, ald, offs, ssrc, pB[l], A, N_NODES);
    hipMemsetAsync(bnbuf, 0, 1024, stream);
    k_bn_stats<<<256, 256, 0, stream>>>(A, bn_sum, bn_sq, N_NODES);
    k_bn_apply<<<(N_NODES * HD + 255) / 256, 256, 0, stream>>>(A, bn_sum, bn_sq, pG[l], pBE[l], N_NODES);
  }

  // ---- final GAT(1x64) ----
  k_gemm<<<dim3((N_NODES + 63) / 64, 1), 256, 0, stream>>>(A, pW[3], B, N_NODES, 64);
  k_alsald<64, 64><<<(N_NODES + 3) / 4, 256, 0, stream>>>(B, pAS[3], pAD[3], als, ald, N_NODES);
  k_attn<1, 64><<<(N_NODES + 3) / 4, 256, 0, stream>>>(B, als, ald, offs, ssrc, pB[3], A, N_NODES);

  // ---- global mean pool ----
  hipMemsetAsync(psum, 0, (size_t)NG * OUTC * 4 + 512, stream);  // psum + gstart + gend
  k_group_bounds<<<(N_NODES + 255) / 256, 256, 0, stream>>>(bids, flags, gstart, gend, N_NODES);
  k_pool_acc<<<(N_NODES + 127) / 128, 256, 0, stream>>>(A, bids, flags, psum, N_NODES);
  k_pool_fin<<<16, 256, 0, stream>>>(psum, gstart, gend, (float*)d_out);
}

// Round 5
// 651.731 us; speedup vs baseline: 1.3373x; 1.2078x over previous
//
#include <hip/hip_runtime.h>
#include <hip/hip_fp16.h>

#define DEVINL __device__ __forceinline__

constexpr int N_NODES = 50000;
constexpr int E_EDGES = 800000;
constexpr int HD      = 128;   // hidden dim (4 heads x 32)
constexpr int NG      = 64;    // graphs
constexpr int OUTC    = 64;    // final out channels
constexpr int NPAR    = 22;    // param tensors
constexpr int PAR_TOTAL = 3*(16384+3*128) + (8192+3*64) + 6*128;  // 59456

DEVINL float bf2f(unsigned short u){
  union { unsigned int i; float f; } v; v.i = ((unsigned int)u) << 16; return v.f;
}
DEVINL float lrelu(float v){ return v > 0.f ? v : 0.2f * v; }
DEVINL float2 u2f2(unsigned int u){
  __half2 h; *(unsigned int*)&h = u; return __half22float2(h);
}

// ---------------- runtime dtype detection ----------------
// flags[0] = 1 if ints are int64 (index shift), else 0
// flags[1] = 1 if floats are fp32, else 0 (bf16)
__global__ void k_detect(const unsigned short* __restrict__ x,
                         const int* __restrict__ ei, int* __restrict__ flags){
  __shared__ int s_f32, s_i64;
  int t = threadIdx.x;
  if (t == 0){ s_f32 = 0; s_i64 = 1; }
  __syncthreads();
  for (int i = t; i < 2048; i += 256){
    float v = bf2f(x[i]);
    if (!(fabsf(v) < 1e4f)) s_f32 = 1;   // catches huge and NaN
  }
  for (int i = t; i < 512; i += 256){
    if (ei[2 * i + 1] != 0) s_i64 = 0;
  }
  __syncthreads();
  if (t == 0){ flags[0] = s_i64; flags[1] = s_f32; }
}

// ---------------- param conversion (any float storage -> fp32 table) ----------------
struct PtrTab { const void* p[NPAR]; int off[NPAR + 1]; };

__global__ void k_cvt_params(PtrTab tab, const int* __restrict__ flags,
                             float* __restrict__ dst){
  int f = flags[1];
  int i = blockIdx.x * 256 + threadIdx.x;
  if (i >= tab.off[NPAR]) return;
  int k = 0;
  while (tab.off[k + 1] <= i) k++;
  int j = i - tab.off[k];
  dst[i] = f ? ((const float*)tab.p[k])[j] : bf2f(((const unsigned short*)tab.p[k])[j]);
}

// ---------------- CSR build ----------------
__global__ void k_hist(const int* __restrict__ ei, const int* __restrict__ flags,
                       int* __restrict__ deg){
  int e = blockIdx.x * 256 + threadIdx.x;
  if (e >= E_EDGES) return;
  int f = flags[0];
  int d = ei[(size_t)(E_EDGES + e) << f];
  atomicAdd(&deg[d], 1);
}

__global__ void k_scan1(const int* __restrict__ deg, int* __restrict__ offs,
                        int* __restrict__ bTot, int n){
  __shared__ int lds[256];
  int t = threadIdx.x;
  int base = blockIdx.x * 1024 + t * 4;
  int v[4]; int s = 0;
  #pragma unroll
  for (int i = 0; i < 4; i++){ v[i] = (base + i < n) ? deg[base + i] : 0; s += v[i]; }
  lds[t] = s; __syncthreads();
  #pragma unroll
  for (int off = 1; off < 256; off <<= 1){
    int x2 = (t >= off) ? lds[t - off] : 0;
    __syncthreads();
    lds[t] += x2;
    __syncthreads();
  }
  int excl = lds[t] - s;
  if (t == 255) bTot[blockIdx.x] = lds[255];
  int run = excl;
  #pragma unroll
  for (int i = 0; i < 4; i++){
    if (base + i < n) offs[base + i] = run;
    run += v[i];
  }
}

__global__ void k_scan2(const int* __restrict__ bTot, int* __restrict__ bPref, int nb){
  if (threadIdx.x == 0){
    int run = 0;
    for (int i = 0; i < nb; i++){ bPref[i] = run; run += bTot[i]; }
  }
}

__global__ void k_scan3(int* __restrict__ offs, int* __restrict__ cursor,
                        const int* __restrict__ bPref, int n, int etot){
  int t = threadIdx.x;
  int base = blockIdx.x * 1024 + t * 4;
  int bp = bPref[blockIdx.x];
  #pragma unroll
  for (int i = 0; i < 4; i++){
    int idx = base + i;
    if (idx < n){ int v = offs[idx] + bp; offs[idx] = v; cursor[idx] = v; }
  }
  if (blockIdx.x == 0 && t == 0) offs[n] = etot;
}

__global__ void k_scatter(const int* __restrict__ ei, const int* __restrict__ flags,
                          int* __restrict__ cursor, int* __restrict__ ssrc){
  int e = blockIdx.x * 256 + threadIdx.x;
  if (e >= E_EDGES) return;
  int f = flags[0];
  int s = ei[(size_t)e << f];
  int d = ei[(size_t)(E_EDGES + e) << f];
  int pos = atomicAdd(&cursor[d], 1);
  ssrc[pos] = s;
}

// ---------------- fused GEMM ----------------
// h16[n,Mtot](fp16) = act(Ain)[n,128] x W[128,Mtot]; also emits als/ald
// (attention logits, exact fp32) in the epilogue. act = BN+ELU for !FIRST
// (scale/shift from bn sums), dtype-flagged raw load for FIRST.
template<int CHEAD, bool FIRST>
__global__ __launch_bounds__(256) void k_gemm(
    const void* __restrict__ Ain, const int* __restrict__ flags,
    const float* __restrict__ bnsum, const float* __restrict__ bnsq,
    const float* __restrict__ g, const float* __restrict__ be,
    const float* __restrict__ W,
    const float* __restrict__ a_s, const float* __restrict__ a_d,
    __half* __restrict__ h16, float* __restrict__ als, float* __restrict__ ald,
    int n, int Mtot){
  __shared__ float As[64][132];
  __shared__ float Ws[128][68];
  __shared__ float scale[128], shift[128];
  const int t = threadIdx.x;
  const int rowBase = blockIdx.x * 64;
  const int colBase = blockIdx.y * 64;
  if (!FIRST){
    if (t < 128){
      float inv_n = 1.f / (float)n;
      float mu = bnsum[t] * inv_n;
      float var = bnsq[t] * inv_n - mu * mu;
      float sc = g[t] * rsqrtf(var + 1e-5f);
      scale[t] = sc; shift[t] = be[t] - mu * sc;
    }
    __syncthreads();
  }
  for (int f = t; f < 64 * 32; f += 256){
    int r = f >> 5, c4 = (f & 31) << 2;
    float4 v = make_float4(0.f, 0.f, 0.f, 0.f);
    if (rowBase + r < n){
      if (FIRST){
        if (flags[1]){
          v = *(const float4*)((const float*)Ain + (size_t)(rowBase + r) * 128 + c4);
        } else {
          ushort4 u = *(const ushort4*)((const unsigned short*)Ain + (size_t)(rowBase + r) * 128 + c4);
          v = make_float4(bf2f(u.x), bf2f(u.y), bf2f(u.z), bf2f(u.w));
        }
      } else {
        v = *(const float4*)((const float*)Ain + (size_t)(rowBase + r) * 128 + c4);
        v.x = v.x * scale[c4]     + shift[c4];
        v.y = v.y * scale[c4 + 1] + shift[c4 + 1];
        v.z = v.z * scale[c4 + 2] + shift[c4 + 2];
        v.w = v.w * scale[c4 + 3] + shift[c4 + 3];
        v.x = v.x > 0.f ? v.x : expm1f(v.x);
        v.y = v.y > 0.f ? v.y : expm1f(v.y);
        v.z = v.z > 0.f ? v.z : expm1f(v.z);
        v.w = v.w > 0.f ? v.w : expm1f(v.w);
      }
    }
    As[r][c4] = v.x; As[r][c4 + 1] = v.y; As[r][c4 + 2] = v.z; As[r][c4 + 3] = v.w;
  }
  for (int f = t; f < 128 * 16; f += 256){
    int r = f >> 4, c4 = (f & 15) << 2;
    float4 w = *(const float4*)(W + (size_t)r * Mtot + colBase + c4);
    Ws[r][c4] = w.x; Ws[r][c4 + 1] = w.y; Ws[r][c4 + 2] = w.z; Ws[r][c4 + 3] = w.w;
  }
  __syncthreads();
  const int cx = t & 15, ry = t >> 4;
  float acc[4][4];
  #pragma unroll
  for (int i = 0; i < 4; i++)
    #pragma unroll
    for (int j = 0; j < 4; j++) acc[i][j] = 0.f;
  for (int k = 0; k < 128; k += 4){
    float4 a0 = *(const float4*)&As[ry][k];
    float4 a1 = *(const float4*)&As[ry + 16][k];
    float4 a2 = *(const float4*)&As[ry + 32][k];
    float4 a3 = *(const float4*)&As[ry + 48][k];
    #pragma unroll
    for (int kk = 0; kk < 4; kk++){
      float4 w = *(const float4*)&Ws[k + kk][cx << 2];
      float v0 = (&a0.x)[kk], v1 = (&a1.x)[kk], v2 = (&a2.x)[kk], v3 = (&a3.x)[kk];
      acc[0][0] += v0 * w.x; acc[0][1] += v0 * w.y; acc[0][2] += v0 * w.z; acc[0][3] += v0 * w.w;
      acc[1][0] += v1 * w.x; acc[1][1] += v1 * w.y; acc[1][2] += v1 * w.z; acc[1][3] += v1 * w.w;
      acc[2][0] += v2 * w.x; acc[2][1] += v2 * w.y; acc[2][2] += v2 * w.z; acc[2][3] += v2 * w.w;
      acc[3][0] += v3 * w.x; acc[3][1] += v3 * w.y; acc[3][2] += v3 * w.z; acc[3][3] += v3 * w.w;
    }
  }
  // epilogue: fp16 store + als/ald shuffle-reduce (heads local to this block)
  float4 asv = *(const float4*)&a_s[colBase + (cx << 2)];
  float4 adv = *(const float4*)&a_d[colBase + (cx << 2)];
  constexpr int GL = CHEAD / 4;     // lanes per head group: 8 (C=32) or 16 (C=64)
  #pragma unroll
  for (int i = 0; i < 4; i++){
    int r = rowBase + ry + 16 * i;
    if (r < n){
      __half2* hp = (__half2*)(h16 + (size_t)r * Mtot + colBase + (cx << 2));
      hp[0] = __float22half2_rn(make_float2(acc[i][0], acc[i][1]));
      hp[1] = __float22half2_rn(make_float2(acc[i][2], acc[i][3]));
    }
    float pas = acc[i][0] * asv.x + acc[i][1] * asv.y + acc[i][2] * asv.z + acc[i][3] * asv.w;
    float pad = acc[i][0] * adv.x + acc[i][1] * adv.y + acc[i][2] * adv.z + acc[i][3] * adv.w;
    #pragma unroll
    for (int o = 1; o < GL; o <<= 1){
      pas += __shfl_xor(pas, o);
      pad += __shfl_xor(pad, o);
    }
    if ((cx & (GL - 1)) == 0 && r < n){
      int H = Mtot / CHEAD;
      int head = colBase / CHEAD + cx / GL;
      als[(size_t)r * H + head] = pas;
      ald[(size_t)r * H + head] = pad;
    }
  }
}

// ---------------- per-node GAT attention + aggregation ----------------
// One wave per node; 4 edge-groups x 16 lanes; single pass (logits bounded
// far below fp32 exp overflow; alpha scale-invariant). Messages from fp16 h.
template<int H, int C>
__global__ __launch_bounds__(256) void k_attn(const __half* __restrict__ h16,
                      const float* __restrict__ als, const float* __restrict__ ald,
                      const int* __restrict__ offs, const int* __restrict__ ssrc,
                      const float* __restrict__ bias,
                      float* __restrict__ out, int n){
  constexpr int HC = H * C;
  constexpr int CPL = HC / 16;        // channels per lane: 8 (4x32) or 4 (1x64)
  int node = blockIdx.x * 4 + (threadIdx.x >> 6);
  if (node >= n) return;
  int lane = threadIdx.x & 63;
  int grp  = lane >> 4;               // edge slot 0..3
  int sub  = lane & 15;
  int c0   = sub * CPL;               // lane's channels (single head each)
  int head = c0 / C;

  float ald_h = ald[(size_t)node * H + head];

  float ssum = 0.f;
  float acc[CPL];
  #pragma unroll
  for (int i = 0; i < CPL; i++) acc[i] = 0.f;
  if (grp == 0){                      // self-loop seeded once
    float w = __expf(lrelu(als[(size_t)node * H + head] + ald_h));
    ssum = w;
    const __half* hp = h16 + (size_t)node * HC + c0;
    if constexpr (CPL == 8){
      uint4 raw = *(const uint4*)hp;
      float2 f0 = u2f2(raw.x), f1 = u2f2(raw.y), f2 = u2f2(raw.z), f3 = u2f2(raw.w);
      acc[0] = w * f0.x; acc[1] = w * f0.y; acc[2] = w * f1.x; acc[3] = w * f1.y;
      acc[4] = w * f2.x; acc[5] = w * f2.y; acc[6] = w * f3.x; acc[7] = w * f3.y;
    } else {
      uint2 raw = *(const uint2*)hp;
      float2 f0 = u2f2(raw.x), f1 = u2f2(raw.y);
      acc[0] = w * f0.x; acc[1] = w * f0.y; acc[2] = w * f1.x; acc[3] = w * f1.y;
    }
  }
  int beg = offs[node];
  int deg = offs[node + 1] - beg;
  for (int base = grp; base < deg; base += 4){
    int src = ssrc[beg + base];
    float w = __expf(lrelu(als[(size_t)src * H + head] + ald_h));
    ssum += w;
    const __half* hp = h16 + (size_t)src * HC + c0;
    if constexpr (CPL == 8){
      uint4 raw = *(const uint4*)hp;
      float2 f0 = u2f2(raw.x), f1 = u2f2(raw.y), f2 = u2f2(raw.z), f3 = u2f2(raw.w);
      acc[0] += w * f0.x; acc[1] += w * f0.y; acc[2] += w * f1.x; acc[3] += w * f1.y;
      acc[4] += w * f2.x; acc[5] += w * f2.y; acc[6] += w * f3.x; acc[7] += w * f3.y;
    } else {
      uint2 raw = *(const uint2*)hp;
      float2 f0 = u2f2(raw.x), f1 = u2f2(raw.y);
      acc[0] += w * f0.x; acc[1] += w * f0.y; acc[2] += w * f1.x; acc[3] += w * f1.y;
    }
  }
  // combine the 4 edge-groups (groups partition edges; quad lanes share head)
  #pragma unroll
  for (int o = 16; o < 64; o <<= 1){
    ssum += __shfl_xor(ssum, o);
    #pragma unroll
    for (int i = 0; i < CPL; i++) acc[i] += __shfl_xor(acc[i], o);
  }
  if (grp == 0){
    float inv_s = 1.f / ssum;
    float* op = out + (size_t)node * HC + c0;
    if constexpr (CPL == 8){
      float4 o0 = make_float4(acc[0]*inv_s + bias[c0+0], acc[1]*inv_s + bias[c0+1],
                              acc[2]*inv_s + bias[c0+2], acc[3]*inv_s + bias[c0+3]);
      float4 o1 = make_float4(acc[4]*inv_s + bias[c0+4], acc[5]*inv_s + bias[c0+5],
                              acc[6]*inv_s + bias[c0+6], acc[7]*inv_s + bias[c0+7]);
      *(float4*)op = o0; *(float4*)(op + 4) = o1;
    } else {
      float4 o0 = make_float4(acc[0]*inv_s + bias[c0+0], acc[1]*inv_s + bias[c0+1],
                              acc[2]*inv_s + bias[c0+2], acc[3]*inv_s + bias[c0+3]);
      *(float4*)op = o0;
    }
  }
}

// ---------------- batchnorm stats ----------------
__global__ void k_bn_stats(const float* __restrict__ A, float* __restrict__ bsum,
                           float* __restrict__ bsq, int n){
  __shared__ float ls[256], lq[256];
  int t = threadIdx.x;
  int col = t & 127;
  int rhalf = t >> 7;
  float s = 0.f, q = 0.f;
  for (int r = blockIdx.x * 2 + rhalf; r < n; r += gridDim.x * 2){
    float v = A[(size_t)r * 128 + col];
    s += v; q += v * v;
  }
  ls[t] = s; lq[t] = q; __syncthreads();
  if (t < 128){
    s = ls[t] + ls[t + 128];
    q = lq[t] + lq[t + 128];
    atomicAdd(&bsum[col], s);
    atomicAdd(&bsq[col], q);
  }
}

// ---------------- global mean pool ----------------
__global__ void k_group_bounds(const int* __restrict__ bids, const int* __restrict__ flags,
                               int* __restrict__ gstart, int* __restrict__ gend, int n){
  int i = blockIdx.x * 256 + threadIdx.x;
  if (i >= n) return;
  int f = flags[0];
  int g = bids[(size_t)i << f];
  if (i == 0 || bids[(size_t)(i - 1) << f] != g) gstart[g] = i;
  if (i == n - 1 || bids[(size_t)(i + 1) << f] != g) gend[g] = i + 1;
}

__global__ void k_pool_acc(const float* __restrict__ A, const int* __restrict__ bids,
                           const int* __restrict__ flags, float* __restrict__ sums, int n){
  int t = threadIdx.x;
  int f = flags[0];
  int col = t & 63;
  int rsub = t >> 6;                // 0..3
  int r0 = blockIdx.x * 128;
  float acc = 0.f; int cur = -1;
  for (int i = 0; i < 32; i++){
    int r = r0 + rsub + i * 4;
    if (r >= n) break;
    int g = bids[(size_t)r << f];
    if (g != cur){
      if (cur >= 0) atomicAdd(&sums[cur * 64 + col], acc);
      cur = g; acc = 0.f;
    }
    acc += A[(size_t)r * 64 + col];
  }
  if (cur >= 0) atomicAdd(&sums[cur * 64 + col], acc);
}

__global__ void k_pool_fin(const float* __restrict__ sums, const int* __restrict__ gstart,
                           const int* __restrict__ gend, float* __restrict__ out){
  int i = blockIdx.x * 256 + threadIdx.x;
  if (i >= NG * OUTC) return;
  int g = i >> 6;
  int cnt = gend[g] - gstart[g];
  float c = (float)(cnt > 1 ? cnt : 1);
  out[i] = sums[i] / c;    // output is fp32
}

extern "C" void kernel_launch(void* const* d_in, const int* in_sizes, int n_in,
                              void* d_out, int out_size, void* d_ws, size_t ws_size,
                              hipStream_t stream){
  const unsigned short* x    = (const unsigned short*)d_in[0];
  const int*            ei   = (const int*)d_in[1];
  const int*            bids = (const int*)d_in[2];

  char* p = (char*)d_ws;
  auto carve = [&](size_t bytes) -> void* {
    void* r = (void*)p; p += (bytes + 255) & ~size_t(255); return r;
  };
  float*  A      = (float*)carve((size_t)N_NODES * HD * 4);     // attn out (fp32)
  __half* h16    = (__half*)carve((size_t)N_NODES * HD * 2);    // gemm out (fp16)
  float*  Afin   = (float*)carve((size_t)N_NODES * OUTC * 4);   // final attn out
  float*  par    = (float*)carve((size_t)PAR_TOTAL * 4);
  float*  als    = (float*)carve((size_t)N_NODES * 4 * 4);
  float*  ald    = (float*)carve((size_t)N_NODES * 4 * 4);
  int*    offs   = (int*)carve((size_t)(N_NODES + 1) * 4);
  int*    cursor = (int*)carve((size_t)N_NODES * 4);
  int*    ssrc   = (int*)carve((size_t)E_EDGES * 4);
  int*    bTot   = (int*)carve(256);
  int*    bPref  = (int*)carve(256);
  int*    flags  = (int*)carve(256);
  // ---- contiguous zero-region (single memset) ----
  char*   zbeg   = p;
  int*    deg    = (int*)carve((size_t)N_NODES * 4);
  float*  bnbuf  = (float*)carve(3 * 1024);        // 3 layers x (sum[128]|sq[128])
  float*  psum   = (float*)carve(NG * OUTC * 4);
  int*    gstart = (int*)carve(256);
  int*    gend   = (int*)carve(256);
  size_t  zlen   = (size_t)(p - zbeg);

  // ---- build param conversion table (dict order indices 3..24) ----
  PtrTab tab;
  int sizes[NPAR];
  for (int l = 0; l < 4; l++){
    int base = 3 + 4 * l;
    tab.p[4 * l + 0] = d_in[base + 0]; sizes[4 * l + 0] = (l < 3) ? 16384 : 8192; // W
    tab.p[4 * l + 1] = d_in[base + 1]; sizes[4 * l + 1] = (l < 3) ? 128 : 64;     // as
    tab.p[4 * l + 2] = d_in[base + 2]; sizes[4 * l + 2] = (l < 3) ? 128 : 64;     // ad
    tab.p[4 * l + 3] = d_in[base + 3]; sizes[4 * l + 3] = (l < 3) ? 128 : 64;     // b
  }
  for (int l = 0; l < 3; l++){
    tab.p[16 + 2 * l]     = d_in[19 + 2 * l];     sizes[16 + 2 * l] = 128;  // g
    tab.p[16 + 2 * l + 1] = d_in[19 + 2 * l + 1]; sizes[16 + 2 * l + 1] = 128; // be
  }
  tab.off[0] = 0;
  for (int k = 0; k < NPAR; k++) tab.off[k + 1] = tab.off[k] + sizes[k];
  const float* pW[4], *pAS[4], *pAD[4], *pB[4], *pG[3], *pBE[3];
  for (int l = 0; l < 4; l++){
    pW[l]  = par + tab.off[4 * l + 0];
    pAS[l] = par + tab.off[4 * l + 1];
    pAD[l] = par + tab.off[4 * l + 2];
    pB[l]  = par + tab.off[4 * l + 3];
  }
  for (int l = 0; l < 3; l++){
    pG[l]  = par + tab.off[16 + 2 * l];
    pBE[l] = par + tab.off[16 + 2 * l + 1];
  }
  float* bnS[3], *bnQ[3];
  for (int l = 0; l < 3; l++){ bnS[l] = bnbuf + 256 * l; bnQ[l] = bnbuf + 256 * l + 128; }

  hipMemsetAsync(zbeg, 0, zlen, stream);

  // ---- dtype detection + param conversion ----
  k_detect<<<1, 256, 0, stream>>>(x, ei, flags);
  k_cvt_params<<<(PAR_TOTAL + 255) / 256, 256, 0, stream>>>(tab, flags, par);

  // ---- CSR build (self-loops implicit) ----
  k_hist<<<(E_EDGES + 255) / 256, 256, 0, stream>>>(ei, flags, deg);
  int nb = (N_NODES + 1023) / 1024;  // 49
  k_scan1<<<nb, 256, 0, stream>>>(deg, offs, bTot, N_NODES);
  k_scan2<<<1, 64, 0, stream>>>(bTot, bPref, nb);
  k_scan3<<<nb, 256, 0, stream>>>(offs, cursor, bPref, N_NODES, E_EDGES);
  k_scatter<<<(E_EDGES + 255) / 256, 256, 0, stream>>>(ei, flags, cursor, ssrc);

  dim3 gemmGrid((N_NODES + 63) / 64, 2);
  int attnBlocks = (N_NODES + 3) / 4;

  // ---- layer 0 ----
  k_gemm<32, true><<<gemmGrid, 256, 0, stream>>>(
      (const void*)x, flags, nullptr, nullptr, nullptr, nullptr,
      pW[0], pAS[0], pAD[0], h16, als, ald, N_NODES, 128);
  k_attn<4, 32><<<attnBlocks, 256, 0, stream>>>(h16, als, ald, offs, ssrc, pB[0], A, N_NODES);
  k_bn_stats<<<256, 256, 0, stream>>>(A, bnS[0], bnQ[0], N_NODES);
  // ---- layers 1,2 ----
  for (int l = 1; l < 3; l++){
    k_gemm<32, false><<<gemmGrid, 256, 0, stream>>>(
        (const void*)A, flags, bnS[l-1], bnQ[l-1], pG[l-1], pBE[l-1],
        pW[l], pAS[l], pAD[l], h16, als, ald, N_NODES, 128);
    k_attn<4, 32><<<attnBlocks, 256, 0, stream>>>(h16, als, ald, offs, ssrc, pB[l], A, N_NODES);
    k_bn_stats<<<256, 256, 0, stream>>>(A, bnS[l], bnQ[l], N_NODES);
  }
  // ---- final layer (1 head, 64 ch) ----
  k_gemm<64, false><<<dim3((N_NODES + 63) / 64, 1), 256, 0, stream>>>(
      (const void*)A, flags, bnS[2], bnQ[2], pG[2], pBE[2],
      pW[3], pAS[3], pAD[3], h16, als, ald, N_NODES, 64);
  k_attn<1, 64><<<attnBlocks, 256, 0, stream>>>(h16, als, ald, offs, ssrc, pB[3], Afin, N_NODES);

  // ---- global mean pool ----
  k_group_bounds<<<(N_NODES + 255) / 256, 256, 0, stream>>>(bids, flags, gstart, gend, N_NODES);
  k_pool_acc<<<(N_NODES + 127) / 128, 256, 0, stream>>>(Afin, bids, flags, psum, N_NODES);
  k_pool_fin<<<16, 256, 0, stream>>>(psum, gstart, gend, (float*)d_out);
}

// Round 6
// 560.313 us; speedup vs baseline: 1.5555x; 1.1632x over previous
//
#include <hip/hip_runtime.h>

#define DEVINL __device__ __forceinline__

constexpr int N_NODES = 50000;
constexpr int E_EDGES = 800000;
constexpr int HD      = 128;
constexpr int NG      = 64;
constexpr int OUTC    = 64;
constexpr int NPAR    = 22;
constexpr int PAR_TOTAL = 3*(16384+3*128) + (8192+3*64) + 6*128;  // 59456
constexpr int EB      = 8192;                    // edges per binA block
constexpr int NBLK    = (E_EDGES + EB - 1) / EB; // 98
constexpr int NBKT    = (N_NODES + 1023) / 1024; // 49
constexpr int WT_TOTAL = 3*128*128 + 64*128;     // 57344 fp16

typedef _Float16 half8_t __attribute__((ext_vector_type(8)));
typedef float    float4_t __attribute__((ext_vector_type(4)));

DEVINL float bf2f(unsigned short u){
  union { unsigned int i; float f; } v; v.i = ((unsigned int)u) << 16; return v.f;
}
DEVINL float lrelu(float v){ return v > 0.f ? v : 0.2f * v; }
DEVINL float2 h2f2(const _Float16* p){
  return make_float2((float)p[0], (float)p[1]);
}

// ---------------- runtime dtype detection ----------------
__global__ void k_detect(const unsigned short* __restrict__ x,
                         const int* __restrict__ ei, int* __restrict__ flags){
  __shared__ int s_f32, s_i64;
  int t = threadIdx.x;
  if (t == 0){ s_f32 = 0; s_i64 = 1; }
  __syncthreads();
  for (int i = t; i < 2048; i += 256){
    float v = bf2f(x[i]);
    if (!(fabsf(v) < 1e4f)) s_f32 = 1;
  }
  for (int i = t; i < 512; i += 256){
    if (ei[2 * i + 1] != 0) s_i64 = 0;
  }
  __syncthreads();
  if (t == 0){ flags[0] = s_i64; flags[1] = s_f32; }
}

// ---------------- param conversion ----------------
struct PtrTab { const void* p[NPAR]; int off[NPAR + 1]; };

__global__ void k_cvt_params(PtrTab tab, const int* __restrict__ flags,
                             float* __restrict__ dst){
  int f = flags[1];
  int i = blockIdx.x * 256 + threadIdx.x;
  if (i >= tab.off[NPAR]) return;
  int k = 0;
  while (tab.off[k + 1] <= i) k++;
  int j = i - tab.off[k];
  dst[i] = f ? ((const float*)tab.p[k])[j] : bf2f(((const unsigned short*)tab.p[k])[j]);
}

// W -> fp16 transposed table wt16: layers 0..2 at l*16384 ([n][k], n<128),
// layer 3 at 49152 ([n][k], n<64). k stride 128.
__global__ void k_prep_w(const void* __restrict__ W0, const void* __restrict__ W1,
                         const void* __restrict__ W2, const void* __restrict__ W3,
                         const int* __restrict__ flags, _Float16* __restrict__ wt16){
  int i = blockIdx.x * 256 + threadIdx.x;
  if (i >= WT_TOTAL) return;
  int f = flags[1];
  const void* W; int base, Mt;
  if (i < 49152){ int l = i >> 14; base = i & 16383; Mt = 128; W = (l == 0) ? W0 : (l == 1 ? W1 : W2); }
  else { base = i - 49152; Mt = 64; W = W3; }
  int nn = base >> 7, k = base & 127;
  float val = f ? ((const float*)W)[(size_t)k * Mt + nn]
                : bf2f(((const unsigned short*)W)[(size_t)k * Mt + nn]);
  wt16[i] = (_Float16)val;
}

// ---------------- CSR build: LDS-binned 3-phase ----------------
// Phase A: bin 8192 edges per block into 49 dst-buckets (pack src|dst<<16).
__global__ __launch_bounds__(256) void k_binA(const int* __restrict__ ei,
                      const int* __restrict__ flags,
                      unsigned int* __restrict__ ebuf, int* __restrict__ bofs){
  __shared__ int cnt[64];
  __shared__ int lofs[64];
  __shared__ unsigned int sorted[EB];
  int t = threadIdx.x, blk = blockIdx.x;
  int e0 = blk * EB, ecnt = min(EB, E_EDGES - e0);
  if (t < 64) cnt[t] = 0;
  __syncthreads();
  int f = flags[0];
  unsigned int my[EB / 256];
  #pragma unroll
  for (int j = 0; j < EB / 256; j++){
    int i = t + j * 256;
    my[j] = 0xFFFFFFFFu;
    if (i < ecnt){
      int s = ei[(size_t)(e0 + i) << f];
      int d = ei[(size_t)(E_EDGES + e0 + i) << f];
      unsigned int pk = (unsigned int)s | ((unsigned int)d << 16);
      my[j] = pk;
      atomicAdd(&cnt[d >> 10], 1);
    }
  }
  __syncthreads();
  if (t == 0){
    int run = 0;
    for (int b = 0; b < NBKT; b++){ int c = cnt[b]; lofs[b] = run; cnt[b] = run; run += c; }
    lofs[NBKT] = run;   // == ecnt
  }
  __syncthreads();
  if (t < NBKT + 1) bofs[blk * (NBKT + 1) + t] = lofs[t];
  #pragma unroll
  for (int j = 0; j < EB / 256; j++){
    unsigned int pk = my[j];
    if (pk != 0xFFFFFFFFu){
      int p = atomicAdd(&cnt[pk >> 26], 1);
      sorted[p] = pk;
    }
  }
  __syncthreads();
  for (int i = t; i < ecnt; i += 256) ebuf[(size_t)e0 + i] = sorted[i];
}

// Phase A2: bucket totals -> bases
__global__ void k_bscan(const int* __restrict__ bofs, int* __restrict__ bbase){
  __shared__ int tot[64];
  int t = threadIdx.x;
  if (t < 64) tot[t] = 0;
  __syncthreads();
  for (int i = t; i < NBLK * NBKT; i += 256){
    int blk = i / NBKT, b = i - blk * NBKT;
    atomicAdd(&tot[b], bofs[blk * (NBKT + 1) + b + 1] - bofs[blk * (NBKT + 1) + b]);
  }
  __syncthreads();
  if (t == 0){
    int run = 0;
    for (int b = 0; b < NBKT; b++){ bbase[b] = run; run += tot[b]; }
    bbase[NBKT] = run;
  }
}

// Phase B: one block per bucket: local hist+scan -> offs, then scatter ssrc.
__global__ __launch_bounds__(256) void k_csrB(const unsigned int* __restrict__ ebuf,
                      const int* __restrict__ bofs, const int* __restrict__ bbase,
                      int* __restrict__ offs, int* __restrict__ ssrc, int n){
  __shared__ int hist[1024];
  __shared__ int wsum[256];
  int t = threadIdx.x, b = blockIdx.x;
  int nbase = b << 10;
  for (int i = t; i < 1024; i += 256) hist[i] = 0;
  __syncthreads();
  for (int blk = 0; blk < NBLK; blk++){
    int s0 = bofs[blk * (NBKT + 1) + b], s1 = bofs[blk * (NBKT + 1) + b + 1];
    for (int i = s0 + t; i < s1; i += 256){
      unsigned int pk = ebuf[(size_t)blk * EB + i];
      atomicAdd(&hist[(int)(pk >> 16) - nbase], 1);
    }
  }
  __syncthreads();
  int base4 = t * 4;
  int v0 = hist[base4], v1 = hist[base4 + 1], v2 = hist[base4 + 2], v3 = hist[base4 + 3];
  int s = v0 + v1 + v2 + v3;
  wsum[t] = s; __syncthreads();
  for (int off = 1; off < 256; off <<= 1){
    int x2 = (t >= off) ? wsum[t - off] : 0;
    __syncthreads();
    wsum[t] += x2;
    __syncthreads();
  }
  int run = bbase[b] + wsum[t] - s;
  int node = nbase + base4;
  if (node < n) offs[node] = run;  hist[base4] = run;  run += v0;
  if (node + 1 < n) offs[node + 1] = run;  hist[base4 + 1] = run;  run += v1;
  if (node + 2 < n) offs[node + 2] = run;  hist[base4 + 2] = run;  run += v2;
  if (node + 3 < n) offs[node + 3] = run;  hist[base4 + 3] = run;
  if (b == NBKT - 1 && t == 255) offs[n] = bbase[NBKT];
  __syncthreads();
  for (int blk = 0; blk < NBLK; blk++){
    int s0 = bofs[blk * (NBKT + 1) + b], s1 = bofs[blk * (NBKT + 1) + b + 1];
    for (int i = s0 + t; i < s1; i += 256){
      unsigned int pk = ebuf[(size_t)blk * EB + i];
      int p = atomicAdd(&hist[(int)(pk >> 16) - nbase], 1);
      ssrc[p] = (int)(pk & 0xFFFFu);
    }
  }
}

// ---------------- fused MFMA GEMM ----------------
// h16[n,MT] = act(Ain)[n,128] x W[128,MT] via v_mfma_f32_16x16x32_f16.
// Wt16 = W^T fp16 [MT][128]. Epilogue: coalesced fp16 store + als/ald.
template<int MT, bool FIRST>
__global__ __launch_bounds__(256) void k_gemm(
    const void* __restrict__ Ain, const int* __restrict__ flags,
    const float* __restrict__ bnsum, const float* __restrict__ bnsq,
    const float* __restrict__ g, const float* __restrict__ be,
    const _Float16* __restrict__ Wt16,
    const float* __restrict__ a_s, const float* __restrict__ a_d,
    _Float16* __restrict__ h16, float* __restrict__ als, float* __restrict__ ald,
    int n){
  __shared__ _Float16 AhL[64 * 136];     // stride 136: 2-way banks (free)
  __shared__ _Float16 WtL[MT * 72];      // K-half staged, stride 72
  __shared__ float scale[128], shift[128];
  const int t = threadIdx.x;
  const int rowBase = blockIdx.x * 64;
  if (!FIRST){
    if (t < 128){
      float inv_n = 1.f / (float)n;
      float mu = bnsum[t] * inv_n;
      float var = bnsq[t] * inv_n - mu * mu;
      float sc = g[t] * rsqrtf(var + 1e-5f);
      scale[t] = sc; shift[t] = be[t] - mu * sc;
    }
    __syncthreads();
  }
  // stage A (full K=128) as fp16 with activation fused
  for (int f = t; f < 64 * 16; f += 256){
    int r = f >> 4, c8 = (f & 15) << 3;
    int row = rowBase + r;
    float v[8];
    if (row < n){
      if (FIRST){
        if (flags[1]){
          float4 x0 = *(const float4*)((const float*)Ain + (size_t)row * 128 + c8);
          float4 x1 = *(const float4*)((const float*)Ain + (size_t)row * 128 + c8 + 4);
          v[0]=x0.x; v[1]=x0.y; v[2]=x0.z; v[3]=x0.w;
          v[4]=x1.x; v[5]=x1.y; v[6]=x1.z; v[7]=x1.w;
        } else {
          const unsigned short* xp = (const unsigned short*)Ain + (size_t)row * 128 + c8;
          ushort4 u0 = *(const ushort4*)xp; ushort4 u1 = *(const ushort4*)(xp + 4);
          v[0]=bf2f(u0.x); v[1]=bf2f(u0.y); v[2]=bf2f(u0.z); v[3]=bf2f(u0.w);
          v[4]=bf2f(u1.x); v[5]=bf2f(u1.y); v[6]=bf2f(u1.z); v[7]=bf2f(u1.w);
        }
      } else {
        float4 x0 = *(const float4*)((const float*)Ain + (size_t)row * 128 + c8);
        float4 x1 = *(const float4*)((const float*)Ain + (size_t)row * 128 + c8 + 4);
        v[0]=x0.x; v[1]=x0.y; v[2]=x0.z; v[3]=x0.w;
        v[4]=x1.x; v[5]=x1.y; v[6]=x1.z; v[7]=x1.w;
        #pragma unroll
        for (int j = 0; j < 8; j++){
          float xv = v[j] * scale[c8 + j] + shift[c8 + j];
          v[j] = xv > 0.f ? xv : expm1f(xv);
        }
      }
    } else {
      #pragma unroll
      for (int j = 0; j < 8; j++) v[j] = 0.f;
    }
    half8_t h;
    #pragma unroll
    for (int j = 0; j < 8; j++) h[j] = (_Float16)v[j];
    *(half8_t*)&AhL[r * 136 + c8] = h;
  }
  const int lane = t & 63;
  const int m = lane & 15, quad = lane >> 4;
  const int band = (t >> 6) * 16;
  float4_t acc[MT / 16];
  #pragma unroll
  for (int ct = 0; ct < MT / 16; ct++) acc[ct] = (float4_t){0.f, 0.f, 0.f, 0.f};
  #pragma unroll
  for (int kh = 0; kh < 2; kh++){
    __syncthreads();
    for (int f = t; f < MT * 8; f += 256){
      int nn = f >> 3, c8 = (f & 7) << 3;
      *(half8_t*)&WtL[nn * 72 + c8] = *(const half8_t*)&Wt16[nn * 128 + kh * 64 + c8];
    }
    __syncthreads();
    half8_t a0 = *(half8_t*)&AhL[(band + m) * 136 + kh * 64 + quad * 8];
    half8_t a1 = *(half8_t*)&AhL[(band + m) * 136 + kh * 64 + 32 + quad * 8];
    #pragma unroll
    for (int ct = 0; ct < MT / 16; ct++){
      half8_t b0 = *(half8_t*)&WtL[(ct * 16 + m) * 72 + quad * 8];
      half8_t b1 = *(half8_t*)&WtL[(ct * 16 + m) * 72 + 32 + quad * 8];
      acc[ct] = __builtin_amdgcn_mfma_f32_16x16x32_f16(a0, b0, acc[ct], 0, 0, 0);
      acc[ct] = __builtin_amdgcn_mfma_f32_16x16x32_f16(a1, b1, acc[ct], 0, 0, 0);
    }
  }
  __syncthreads();
  // acc -> LDS (C/D layout: col=lane&15, row=quad*4+reg)
  #pragma unroll
  for (int ct = 0; ct < MT / 16; ct++)
    #pragma unroll
    for (int rg = 0; rg < 4; rg++)
      AhL[(band + quad * 4 + rg) * 136 + ct * 16 + m] = (_Float16)acc[ct][rg];
  __syncthreads();
  // epilogue: coalesced fp16 store + exact als/ald
  int r = t >> 2, q = t & 3;
  int row = rowBase + r;
  if (MT == 128){
    if (row < n){
      half8_t h0 = *(half8_t*)&AhL[r * 136 + q * 32];
      half8_t h1 = *(half8_t*)&AhL[r * 136 + q * 32 + 8];
      half8_t h2 = *(half8_t*)&AhL[r * 136 + q * 32 + 16];
      half8_t h3 = *(half8_t*)&AhL[r * 136 + q * 32 + 24];
      float pas = 0.f, pad = 0.f;
      #pragma unroll
      for (int j = 0; j < 8; j++){
        pas += (float)h0[j] * a_s[q * 32 + j]      + (float)h1[j] * a_s[q * 32 + 8 + j]
             + (float)h2[j] * a_s[q * 32 + 16 + j] + (float)h3[j] * a_s[q * 32 + 24 + j];
        pad += (float)h0[j] * a_d[q * 32 + j]      + (float)h1[j] * a_d[q * 32 + 8 + j]
             + (float)h2[j] * a_d[q * 32 + 16 + j] + (float)h3[j] * a_d[q * 32 + 24 + j];
      }
      als[(size_t)row * 4 + q] = pas;
      ald[(size_t)row * 4 + q] = pad;
      _Float16* hp = h16 + (size_t)row * 128 + q * 32;
      *(half8_t*)hp = h0; *(half8_t*)(hp + 8) = h1;
      *(half8_t*)(hp + 16) = h2; *(half8_t*)(hp + 24) = h3;
    }
  } else {
    half8_t h0 = *(half8_t*)&AhL[r * 136 + q * 16];
    half8_t h1 = *(half8_t*)&AhL[r * 136 + q * 16 + 8];
    float pas = 0.f, pad = 0.f;
    #pragma unroll
    for (int j = 0; j < 8; j++){
      pas += (float)h0[j] * a_s[q * 16 + j] + (float)h1[j] * a_s[q * 16 + 8 + j];
      pad += (float)h0[j] * a_d[q * 16 + j] + (float)h1[j] * a_d[q * 16 + 8 + j];
    }
    pas += __shfl_xor(pas, 1); pas += __shfl_xor(pas, 2);
    pad += __shfl_xor(pad, 1); pad += __shfl_xor(pad, 2);
    if (row < n){
      _Float16* hp = h16 + (size_t)row * 64 + q * 16;
      *(half8_t*)hp = h0; *(half8_t*)(hp + 8) = h1;
      if (q == 0){ als[row] = pas; ald[row] = pad; }
    }
  }
}

// ---------------- per-node GAT attention + aggregation ----------------
template<int H, int C>
__global__ __launch_bounds__(256) void k_attn(const _Float16* __restrict__ h16,
                      const float* __restrict__ als, const float* __restrict__ ald,
                      const int* __restrict__ offs, const int* __restrict__ ssrc,
                      const float* __restrict__ bias,
                      float* __restrict__ out, int n){
  constexpr int HC = H * C;
  constexpr int CPL = HC / 16;        // 8 (4x32) or 4 (1x64)
  int node = blockIdx.x * 4 + (threadIdx.x >> 6);
  if (node >= n) return;
  int lane = threadIdx.x & 63;
  int grp  = lane >> 4;
  int sub  = lane & 15;
  int c0   = sub * CPL;
  int head = c0 / C;

  float ald_h = ald[(size_t)node * H + head];
  float ssum = 0.f;
  float acc[CPL];
  #pragma unroll
  for (int i = 0; i < CPL; i++) acc[i] = 0.f;
  if (grp == 0){
    float w = __expf(lrelu(als[(size_t)node * H + head] + ald_h));
    ssum = w;
    const _Float16* hp = h16 + (size_t)node * HC + c0;
    #pragma unroll
    for (int i = 0; i < CPL; i++) acc[i] = w * (float)hp[i];
  }
  int beg = offs[node];
  int deg = offs[node + 1] - beg;
  for (int base = grp; base < deg; base += 4){
    int src = ssrc[beg + base];
    float w = __expf(lrelu(als[(size_t)src * H + head] + ald_h));
    ssum += w;
    const _Float16* hp = h16 + (size_t)src * HC + c0;
    if constexpr (CPL == 8){
      half8_t hv = *(const half8_t*)hp;
      #pragma unroll
      for (int i = 0; i < 8; i++) acc[i] += w * (float)hv[i];
    } else {
      uint2 raw = *(const uint2*)hp;
      const _Float16* hh = (const _Float16*)&raw;
      #pragma unroll
      for (int i = 0; i < 4; i++) acc[i] += w * (float)hh[i];
    }
  }
  #pragma unroll
  for (int o = 16; o < 64; o <<= 1){
    ssum += __shfl_xor(ssum, o);
    #pragma unroll
    for (int i = 0; i < CPL; i++) acc[i] += __shfl_xor(acc[i], o);
  }
  if (grp == 0){
    float inv_s = 1.f / ssum;
    float* op = out + (size_t)node * HC + c0;
    #pragma unroll
    for (int i = 0; i < CPL; i += 4){
      float4 o0 = make_float4(acc[i]*inv_s + bias[c0+i], acc[i+1]*inv_s + bias[c0+i+1],
                              acc[i+2]*inv_s + bias[c0+i+2], acc[i+3]*inv_s + bias[c0+i+3]);
      *(float4*)(op + i) = o0;
    }
  }
}

// ---------------- batchnorm stats ----------------
__global__ void k_bn_stats(const float* __restrict__ A, float* __restrict__ bsum,
                           float* __restrict__ bsq, int n){
  __shared__ float ls[256], lq[256];
  int t = threadIdx.x;
  int col = t & 127;
  int rhalf = t >> 7;
  float s = 0.f, q = 0.f;
  for (int r = blockIdx.x * 2 + rhalf; r < n; r += gridDim.x * 2){
    float v = A[(size_t)r * 128 + col];
    s += v; q += v * v;
  }
  ls[t] = s; lq[t] = q; __syncthreads();
  if (t < 128){
    s = ls[t] + ls[t + 128];
    q = lq[t] + lq[t + 128];
    atomicAdd(&bsum[col], s);
    atomicAdd(&bsq[col], q);
  }
}

// ---------------- global mean pool ----------------
__global__ void k_group_bounds(const int* __restrict__ bids, const int* __restrict__ flags,
                               int* __restrict__ gstart, int* __restrict__ gend, int n){
  int i = blockIdx.x * 256 + threadIdx.x;
  if (i >= n) return;
  int f = flags[0];
  int g = bids[(size_t)i << f];
  if (i == 0 || bids[(size_t)(i - 1) << f] != g) gstart[g] = i;
  if (i == n - 1 || bids[(size_t)(i + 1) << f] != g) gend[g] = i + 1;
}

__global__ void k_pool_acc(const float* __restrict__ A, const int* __restrict__ bids,
                           const int* __restrict__ flags, float* __restrict__ sums, int n){
  int t = threadIdx.x;
  int f = flags[0];
  int col = t & 63;
  int rsub = t >> 6;
  int r0 = blockIdx.x * 128;
  float acc = 0.f; int cur = -1;
  for (int i = 0; i < 32; i++){
    int r = r0 + rsub + i * 4;
    if (r >= n) break;
    int g = bids[(size_t)r << f];
    if (g != cur){
      if (cur >= 0) atomicAdd(&sums[cur * 64 + col], acc);
      cur = g; acc = 0.f;
    }
    acc += A[(size_t)r * 64 + col];
  }
  if (cur >= 0) atomicAdd(&sums[cur * 64 + col], acc);
}

__global__ void k_pool_fin(const float* __restrict__ sums, const int* __restrict__ gstart,
                           const int* __restrict__ gend, float* __restrict__ out){
  int i = blockIdx.x * 256 + threadIdx.x;
  if (i >= NG * OUTC) return;
  int g = i >> 6;
  int cnt = gend[g] - gstart[g];
  float c = (float)(cnt > 1 ? cnt : 1);
  out[i] = sums[i] / c;
}

extern "C" void kernel_launch(void* const* d_in, const int* in_sizes, int n_in,
                              void* d_out, int out_size, void* d_ws, size_t ws_size,
                              hipStream_t stream){
  const unsigned short* x    = (const unsigned short*)d_in[0];
  const int*            ei   = (const int*)d_in[1];
  const int*            bids = (const int*)d_in[2];

  char* p = (char*)d_ws;
  auto carve = [&](size_t bytes) -> void* {
    void* r = (void*)p; p += (bytes + 255) & ~size_t(255); return r;
  };
  float*    A      = (float*)carve((size_t)N_NODES * HD * 4);
  _Float16* h16    = (_Float16*)carve((size_t)N_NODES * HD * 2);
  float*    Afin   = (float*)carve((size_t)N_NODES * OUTC * 4);
  float*    par    = (float*)carve((size_t)PAR_TOTAL * 4);
  _Float16* wt16   = (_Float16*)carve((size_t)WT_TOTAL * 2);
  float*    als    = (float*)carve((size_t)N_NODES * 4 * 4);
  float*    ald    = (float*)carve((size_t)N_NODES * 4 * 4);
  int*      offs   = (int*)carve((size_t)(N_NODES + 1) * 4);
  int*      ssrc   = (int*)carve((size_t)E_EDGES * 4);
  unsigned int* ebuf = (unsigned int*)carve((size_t)NBLK * EB * 4);
  int*      bofs   = (int*)carve((size_t)NBLK * (NBKT + 1) * 4);
  int*      bbase  = (int*)carve((size_t)(NBKT + 1) * 4);
  int*      flags  = (int*)carve(256);
  // contiguous zero-region (single memset)
  char*     zbeg   = p;
  float*    bnbuf  = (float*)carve(3 * 1024);
  float*    psum   = (float*)carve(NG * OUTC * 4);
  int*      gstart = (int*)carve(256);
  int*      gend   = (int*)carve(256);
  size_t    zlen   = (size_t)(p - zbeg);

  // param table (dict order indices 3..24)
  PtrTab tab;
  int sizes[NPAR];
  for (int l = 0; l < 4; l++){
    int base = 3 + 4 * l;
    tab.p[4 * l + 0] = d_in[base + 0]; sizes[4 * l + 0] = (l < 3) ? 16384 : 8192;
    tab.p[4 * l + 1] = d_in[base + 1]; sizes[4 * l + 1] = (l < 3) ? 128 : 64;
    tab.p[4 * l + 2] = d_in[base + 2]; sizes[4 * l + 2] = (l < 3) ? 128 : 64;
    tab.p[4 * l + 3] = d_in[base + 3]; sizes[4 * l + 3] = (l < 3) ? 128 : 64;
  }
  for (int l = 0; l < 3; l++){
    tab.p[16 + 2 * l]     = d_in[19 + 2 * l];     sizes[16 + 2 * l] = 128;
    tab.p[16 + 2 * l + 1] = d_in[19 + 2 * l + 1]; sizes[16 + 2 * l + 1] = 128;
  }
  tab.off[0] = 0;
  for (int k = 0; k < NPAR; k++) tab.off[k + 1] = tab.off[k] + sizes[k];
  const float* pAS[4], *pAD[4], *pB[4], *pG[3], *pBE[3];
  for (int l = 0; l < 4; l++){
    pAS[l] = par + tab.off[4 * l + 1];
    pAD[l] = par + tab.off[4 * l + 2];
    pB[l]  = par + tab.off[4 * l + 3];
  }
  for (int l = 0; l < 3; l++){
    pG[l]  = par + tab.off[16 + 2 * l];
    pBE[l] = par + tab.off[16 + 2 * l + 1];
  }
  const _Float16* pWT[4] = { wt16, wt16 + 16384, wt16 + 32768, wt16 + 49152 };
  float* bnS[3], *bnQ[3];
  for (int l = 0; l < 3; l++){ bnS[l] = bnbuf + 256 * l; bnQ[l] = bnbuf + 256 * l + 128; }

  hipMemsetAsync(zbeg, 0, zlen, stream);

  // dtype detect + param prep
  k_detect<<<1, 256, 0, stream>>>(x, ei, flags);
  k_cvt_params<<<(PAR_TOTAL + 255) / 256, 256, 0, stream>>>(tab, flags, par);
  k_prep_w<<<(WT_TOTAL + 255) / 256, 256, 0, stream>>>(d_in[3], d_in[7], d_in[11], d_in[15],
                                                       flags, wt16);
  // CSR build (LDS-binned)
  k_binA<<<NBLK, 256, 0, stream>>>(ei, flags, ebuf, bofs);
  k_bscan<<<1, 256, 0, stream>>>(bofs, bbase);
  k_csrB<<<NBKT, 256, 0, stream>>>(ebuf, bofs, bbase, offs, ssrc, N_NODES);

  int gemmBlocks = (N_NODES + 63) / 64;
  int attnBlocks = (N_NODES + 3) / 4;

  // layer 0
  k_gemm<128, true><<<gemmBlocks, 256, 0, stream>>>(
      (const void*)x, flags, nullptr, nullptr, nullptr, nullptr,
      pWT[0], pAS[0], pAD[0], h16, als, ald, N_NODES);
  k_attn<4, 32><<<attnBlocks, 256, 0, stream>>>(h16, als, ald, offs, ssrc, pB[0], A, N_NODES);
  k_bn_stats<<<256, 256, 0, stream>>>(A, bnS[0], bnQ[0], N_NODES);
  // layers 1,2
  for (int l = 1; l < 3; l++){
    k_gemm<128, false><<<gemmBlocks, 256, 0, stream>>>(
        (const void*)A, flags, bnS[l-1], bnQ[l-1], pG[l-1], pBE[l-1],
        pWT[l], pAS[l], pAD[l], h16, als, ald, N_NODES);
    k_attn<4, 32><<<attnBlocks, 256, 0, stream>>>(h16, als, ald, offs, ssrc, pB[l], A, N_NODES);
    k_bn_stats<<<256, 256, 0, stream>>>(A, bnS[l], bnQ[l], N_NODES);
  }
  // final layer (1 head, 64 ch)
  k_gemm<64, false><<<gemmBlocks, 256, 0, stream>>>(
      (const void*)A, flags, bnS[2], bnQ[2], pG[2], pBE[2],
      pWT[3], pAS[3], pAD[3], h16, als, ald, N_NODES);
  k_attn<1, 64><<<attnBlocks, 256, 0, stream>>>(h16, als, ald, offs, ssrc, pB[3], Afin, N_NODES);

  // global mean pool
  k_group_bounds<<<(N_NODES + 255) / 256, 256, 0, stream>>>(bids, flags, gstart, gend, N_NODES);
  k_pool_acc<<<(N_NODES + 127) / 128, 256, 0, stream>>>(Afin, bids, flags, psum, N_NODES);
  k_pool_fin<<<16, 256, 0, stream>>>(psum, gstart, gend, (float*)d_out);
}

// Round 7
// 556.133 us; speedup vs baseline: 1.5672x; 1.0075x over previous
//
#include <hip/hip_runtime.h>

#define DEVINL __device__ __forceinline__

constexpr int N_NODES = 50000;
constexpr int E_EDGES = 800000;
constexpr int HD      = 128;
constexpr int NG      = 64;
constexpr int OUTC    = 64;
constexpr int NPAR    = 22;
constexpr int PAR_TOTAL = 3*(16384+3*128) + (8192+3*64) + 6*128;  // 59456
constexpr int WT_TOTAL = 3*128*128 + 64*128;     // 57344 fp16
constexpr int NB      = (N_NODES + 1023) / 1024; // 49 buckets (1024 nodes)
constexpr int EBC     = 2048;                    // edges per count/scatter block
constexpr int NBLKC   = (E_EDGES + EBC - 1) / EBC; // 391

typedef _Float16 half8_t __attribute__((ext_vector_type(8)));
typedef float    float4_t __attribute__((ext_vector_type(4)));

DEVINL float bf2f(unsigned short u){
  union { unsigned int i; float f; } v; v.i = ((unsigned int)u) << 16; return v.f;
}
DEVINL float lrelu(float v){ return v > 0.f ? v : 0.2f * v; }

// ---------------- runtime dtype detection ----------------
__global__ void k_detect(const unsigned short* __restrict__ x,
                         const int* __restrict__ ei, int* __restrict__ flags){
  __shared__ int s_f32, s_i64;
  int t = threadIdx.x;
  if (t == 0){ s_f32 = 0; s_i64 = 1; }
  __syncthreads();
  for (int i = t; i < 2048; i += 256){
    float v = bf2f(x[i]);
    if (!(fabsf(v) < 1e4f)) s_f32 = 1;
  }
  for (int i = t; i < 512; i += 256){
    if (ei[2 * i + 1] != 0) s_i64 = 0;
  }
  __syncthreads();
  if (t == 0){ flags[0] = s_i64; flags[1] = s_f32; }
}

// ---------------- param conversion ----------------
struct PtrTab { const void* p[NPAR]; int off[NPAR + 1]; };

__global__ void k_cvt_params(PtrTab tab, const int* __restrict__ flags,
                             float* __restrict__ dst){
  int f = flags[1];
  int i = blockIdx.x * 256 + threadIdx.x;
  if (i >= tab.off[NPAR]) return;
  int k = 0;
  while (tab.off[k + 1] <= i) k++;
  int j = i - tab.off[k];
  dst[i] = f ? ((const float*)tab.p[k])[j] : bf2f(((const unsigned short*)tab.p[k])[j]);
}

// W -> fp16 transposed table wt16: layers 0..2 at l*16384 ([n][k]), layer 3 at 49152.
__global__ void k_prep_w(const void* __restrict__ W0, const void* __restrict__ W1,
                         const void* __restrict__ W2, const void* __restrict__ W3,
                         const int* __restrict__ flags, _Float16* __restrict__ wt16){
  int i = blockIdx.x * 256 + threadIdx.x;
  if (i >= WT_TOTAL) return;
  int f = flags[1];
  const void* W; int base, Mt;
  if (i < 49152){ int l = i >> 14; base = i & 16383; Mt = 128; W = (l == 0) ? W0 : (l == 1 ? W1 : W2); }
  else { base = i - 49152; Mt = 64; W = W3; }
  int nn = base >> 7, k = base & 127;
  float val = f ? ((const float*)W)[(size_t)k * Mt + nn]
                : bf2f(((const unsigned short*)W)[(size_t)k * Mt + nn]);
  wt16[i] = (_Float16)val;
}

// ---------------- CSR build: wide 4-phase ----------------
// Phase 1: per-block bucket counts -> cntmat[b][blk]
__global__ __launch_bounds__(256) void k_count(const int* __restrict__ ei,
                      const int* __restrict__ flags, int* __restrict__ cntmat){
  __shared__ int cnt[NB];
  int t = threadIdx.x, blk = blockIdx.x;
  if (t < NB) cnt[t] = 0;
  __syncthreads();
  int f = flags[0];
  int e0 = blk * EBC;
  #pragma unroll
  for (int j = 0; j < EBC / 256; j++){
    int e = e0 + t + j * 256;
    if (e < E_EDGES){
      int d = ei[(size_t)(E_EDGES + e) << f];
      atomicAdd(&cnt[d >> 10], 1);
    }
  }
  __syncthreads();
  if (t < NB) cntmat[t * NBLKC + blk] = cnt[t];
}

// Phase 2: bucket bases + per-(blk,bucket) destination bases
__global__ void k_scanmat(const int* __restrict__ cntmat, int* __restrict__ gbase,
                          int* __restrict__ bbase){
  __shared__ int csum[NB];
  __shared__ int cbase[NB + 1];
  int t = threadIdx.x;
  if (t < NB){
    int s = 0;
    for (int blk = 0; blk < NBLKC; blk++) s += cntmat[t * NBLKC + blk];
    csum[t] = s;
  }
  __syncthreads();
  if (t == 0){
    int run = 0;
    for (int b = 0; b < NB; b++){ cbase[b] = run; run += csum[b]; }
    cbase[NB] = run;
  }
  __syncthreads();
  if (t <= NB) bbase[t] = cbase[t];
  if (t < NB){
    int run = cbase[t];
    for (int blk = 0; blk < NBLKC; blk++){
      gbase[blk * NB + t] = run;
      run += cntmat[t * NBLKC + blk];
    }
  }
}

// Phase 3: scatter packed edges directly into bucket-major ebuf2 (exclusive windows)
__global__ __launch_bounds__(256) void k_binscatter(const int* __restrict__ ei,
                      const int* __restrict__ flags, const int* __restrict__ gbase,
                      unsigned int* __restrict__ ebuf2){
  __shared__ int cur[NB];
  int t = threadIdx.x, blk = blockIdx.x;
  if (t < NB) cur[t] = gbase[blk * NB + t];
  __syncthreads();
  int f = flags[0];
  int e0 = blk * EBC;
  #pragma unroll
  for (int j = 0; j < EBC / 256; j++){
    int e = e0 + t + j * 256;
    if (e < E_EDGES){
      int s = ei[(size_t)e << f];
      int d = ei[(size_t)(E_EDGES + e) << f];
      int p = atomicAdd(&cur[d >> 10], 1);
      ebuf2[p] = (unsigned int)s | ((unsigned int)d << 16);
    }
  }
}

// Phase 4: per-bucket (contiguous data): hist -> scan -> offs, then scatter ssrc
__global__ __launch_bounds__(256) void k_csrD(const unsigned int* __restrict__ ebuf2,
                      const int* __restrict__ bbase, int* __restrict__ offs,
                      int* __restrict__ ssrc, int n){
  __shared__ int hist[1024];
  __shared__ int wsum[256];
  int t = threadIdx.x, b = blockIdx.x;
  int nbase = b << 10;
  int s0 = bbase[b], s1 = bbase[b + 1];
  for (int i = t; i < 1024; i += 256) hist[i] = 0;
  __syncthreads();
  for (int i = s0 + t; i < s1; i += 256){
    unsigned int pk = ebuf2[i];
    atomicAdd(&hist[(int)(pk >> 16) - nbase], 1);
  }
  __syncthreads();
  int base4 = t * 4;
  int v0 = hist[base4], v1 = hist[base4 + 1], v2 = hist[base4 + 2], v3 = hist[base4 + 3];
  int s = v0 + v1 + v2 + v3;
  wsum[t] = s; __syncthreads();
  for (int off = 1; off < 256; off <<= 1){
    int x2 = (t >= off) ? wsum[t - off] : 0;
    __syncthreads();
    wsum[t] += x2;
    __syncthreads();
  }
  int run = s0 + wsum[t] - s;
  int node = nbase + base4;
  if (node < n) offs[node] = run;  hist[base4] = run;  run += v0;
  if (node + 1 < n) offs[node + 1] = run;  hist[base4 + 1] = run;  run += v1;
  if (node + 2 < n) offs[node + 2] = run;  hist[base4 + 2] = run;  run += v2;
  if (node + 3 < n) offs[node + 3] = run;  hist[base4 + 3] = run;
  if (b == NB - 1 && t == 255) offs[n] = s1;
  __syncthreads();
  for (int i = s0 + t; i < s1; i += 256){
    unsigned int pk = ebuf2[i];
    int p = atomicAdd(&hist[(int)(pk >> 16) - nbase], 1);
    ssrc[p] = (int)(pk & 0xFFFFu);
  }
}

// ---------------- fused MFMA GEMM ----------------
template<int MT, bool FIRST>
__global__ __launch_bounds__(256) void k_gemm(
    const void* __restrict__ Ain, const int* __restrict__ flags,
    const float* __restrict__ bnsum, const float* __restrict__ bnsq,
    const float* __restrict__ g, const float* __restrict__ be,
    const _Float16* __restrict__ Wt16,
    const float* __restrict__ a_s, const float* __restrict__ a_d,
    _Float16* __restrict__ h16, float* __restrict__ als, float* __restrict__ ald,
    int n){
  __shared__ _Float16 AhL[64 * 136];
  __shared__ _Float16 WtL[MT * 72];
  __shared__ float scale[128], shift[128];
  const int t = threadIdx.x;
  const int rowBase = blockIdx.x * 64;
  if (!FIRST){
    if (t < 128){
      float inv_n = 1.f / (float)n;
      float mu = bnsum[t] * inv_n;
      float var = bnsq[t] * inv_n - mu * mu;
      float sc = g[t] * rsqrtf(var + 1e-5f);
      scale[t] = sc; shift[t] = be[t] - mu * sc;
    }
    __syncthreads();
  }
  for (int f = t; f < 64 * 16; f += 256){
    int r = f >> 4, c8 = (f & 15) << 3;
    int row = rowBase + r;
    float v[8];
    if (row < n){
      if (FIRST){
        if (flags[1]){
          float4 x0 = *(const float4*)((const float*)Ain + (size_t)row * 128 + c8);
          float4 x1 = *(const float4*)((const float*)Ain + (size_t)row * 128 + c8 + 4);
          v[0]=x0.x; v[1]=x0.y; v[2]=x0.z; v[3]=x0.w;
          v[4]=x1.x; v[5]=x1.y; v[6]=x1.z; v[7]=x1.w;
        } else {
          const unsigned short* xp = (const unsigned short*)Ain + (size_t)row * 128 + c8;
          ushort4 u0 = *(const ushort4*)xp; ushort4 u1 = *(const ushort4*)(xp + 4);
          v[0]=bf2f(u0.x); v[1]=bf2f(u0.y); v[2]=bf2f(u0.z); v[3]=bf2f(u0.w);
          v[4]=bf2f(u1.x); v[5]=bf2f(u1.y); v[6]=bf2f(u1.z); v[7]=bf2f(u1.w);
        }
      } else {
        float4 x0 = *(const float4*)((const float*)Ain + (size_t)row * 128 + c8);
        float4 x1 = *(const float4*)((const float*)Ain + (size_t)row * 128 + c8 + 4);
        v[0]=x0.x; v[1]=x0.y; v[2]=x0.z; v[3]=x0.w;
        v[4]=x1.x; v[5]=x1.y; v[6]=x1.z; v[7]=x1.w;
        #pragma unroll
        for (int j = 0; j < 8; j++){
          float xv = v[j] * scale[c8 + j] + shift[c8 + j];
          v[j] = xv > 0.f ? xv : expm1f(xv);
        }
      }
    } else {
      #pragma unroll
      for (int j = 0; j < 8; j++) v[j] = 0.f;
    }
    half8_t h;
    #pragma unroll
    for (int j = 0; j < 8; j++) h[j] = (_Float16)v[j];
    *(half8_t*)&AhL[r * 136 + c8] = h;
  }
  const int lane = t & 63;
  const int m = lane & 15, quad = lane >> 4;
  const int band = (t >> 6) * 16;
  float4_t acc[MT / 16];
  #pragma unroll
  for (int ct = 0; ct < MT / 16; ct++) acc[ct] = (float4_t){0.f, 0.f, 0.f, 0.f};
  #pragma unroll
  for (int kh = 0; kh < 2; kh++){
    __syncthreads();
    for (int f = t; f < MT * 8; f += 256){
      int nn = f >> 3, c8 = (f & 7) << 3;
      *(half8_t*)&WtL[nn * 72 + c8] = *(const half8_t*)&Wt16[nn * 128 + kh * 64 + c8];
    }
    __syncthreads();
    half8_t a0 = *(half8_t*)&AhL[(band + m) * 136 + kh * 64 + quad * 8];
    half8_t a1 = *(half8_t*)&AhL[(band + m) * 136 + kh * 64 + 32 + quad * 8];
    #pragma unroll
    for (int ct = 0; ct < MT / 16; ct++){
      half8_t b0 = *(half8_t*)&WtL[(ct * 16 + m) * 72 + quad * 8];
      half8_t b1 = *(half8_t*)&WtL[(ct * 16 + m) * 72 + 32 + quad * 8];
      acc[ct] = __builtin_amdgcn_mfma_f32_16x16x32_f16(a0, b0, acc[ct], 0, 0, 0);
      acc[ct] = __builtin_amdgcn_mfma_f32_16x16x32_f16(a1, b1, acc[ct], 0, 0, 0);
    }
  }
  __syncthreads();
  #pragma unroll
  for (int ct = 0; ct < MT / 16; ct++)
    #pragma unroll
    for (int rg = 0; rg < 4; rg++)
      AhL[(band + quad * 4 + rg) * 136 + ct * 16 + m] = (_Float16)acc[ct][rg];
  __syncthreads();
  int r = t >> 2, q = t & 3;
  int row = rowBase + r;
  if (MT == 128){
    if (row < n){
      half8_t h0 = *(half8_t*)&AhL[r * 136 + q * 32];
      half8_t h1 = *(half8_t*)&AhL[r * 136 + q * 32 + 8];
      half8_t h2 = *(half8_t*)&AhL[r * 136 + q * 32 + 16];
      half8_t h3 = *(half8_t*)&AhL[r * 136 + q * 32 + 24];
      float pas = 0.f, pad = 0.f;
      #pragma unroll
      for (int j = 0; j < 8; j++){
        pas += (float)h0[j] * a_s[q * 32 + j]      + (float)h1[j] * a_s[q * 32 + 8 + j]
             + (float)h2[j] * a_s[q * 32 + 16 + j] + (float)h3[j] * a_s[q * 32 + 24 + j];
        pad += (float)h0[j] * a_d[q * 32 + j]      + (float)h1[j] * a_d[q * 32 + 8 + j]
             + (float)h2[j] * a_d[q * 32 + 16 + j] + (float)h3[j] * a_d[q * 32 + 24 + j];
      }
      als[(size_t)row * 4 + q] = pas;
      ald[(size_t)row * 4 + q] = pad;
      _Float16* hp = h16 + (size_t)row * 128 + q * 32;
      *(half8_t*)hp = h0; *(half8_t*)(hp + 8) = h1;
      *(half8_t*)(hp + 16) = h2; *(half8_t*)(hp + 24) = h3;
    }
  } else {
    half8_t h0 = *(half8_t*)&AhL[r * 136 + q * 16];
    half8_t h1 = *(half8_t*)&AhL[r * 136 + q * 16 + 8];
    float pas = 0.f, pad = 0.f;
    #pragma unroll
    for (int j = 0; j < 8; j++){
      pas += (float)h0[j] * a_s[q * 16 + j] + (float)h1[j] * a_s[q * 16 + 8 + j];
      pad += (float)h0[j] * a_d[q * 16 + j] + (float)h1[j] * a_d[q * 16 + 8 + j];
    }
    pas += __shfl_xor(pas, 1); pas += __shfl_xor(pas, 2);
    pad += __shfl_xor(pad, 1); pad += __shfl_xor(pad, 2);
    if (row < n){
      _Float16* hp = h16 + (size_t)row * 64 + q * 16;
      *(half8_t*)hp = h0; *(half8_t*)(hp + 8) = h1;
      if (q == 0){ als[row] = pas; ald[row] = pad; }
    }
  }
}

// ---------------- per-node GAT attention + aggregation ----------------
template<int H, int C>
__global__ __launch_bounds__(256) void k_attn(const _Float16* __restrict__ h16,
                      const float* __restrict__ als, const float* __restrict__ ald,
                      const int* __restrict__ offs, const int* __restrict__ ssrc,
                      const float* __restrict__ bias,
                      float* __restrict__ out, int n){
  constexpr int HC = H * C;
  constexpr int CPL = HC / 16;
  int node = blockIdx.x * 4 + (threadIdx.x >> 6);
  if (node >= n) return;
  int lane = threadIdx.x & 63;
  int grp  = lane >> 4;
  int sub  = lane & 15;
  int c0   = sub * CPL;
  int head = c0 / C;

  float ald_h = ald[(size_t)node * H + head];
  float ssum = 0.f;
  float acc[CPL];
  #pragma unroll
  for (int i = 0; i < CPL; i++) acc[i] = 0.f;
  if (grp == 0){
    float w = __expf(lrelu(als[(size_t)node * H + head] + ald_h));
    ssum = w;
    const _Float16* hp = h16 + (size_t)node * HC + c0;
    #pragma unroll
    for (int i = 0; i < CPL; i++) acc[i] = w * (float)hp[i];
  }
  int beg = offs[node];
  int deg = offs[node + 1] - beg;
  for (int base = grp; base < deg; base += 4){
    int src = ssrc[beg + base];
    float w = __expf(lrelu(als[(size_t)src * H + head] + ald_h));
    ssum += w;
    const _Float16* hp = h16 + (size_t)src * HC + c0;
    if constexpr (CPL == 8){
      half8_t hv = *(const half8_t*)hp;
      #pragma unroll
      for (int i = 0; i < 8; i++) acc[i] += w * (float)hv[i];
    } else {
      uint2 raw = *(const uint2*)hp;
      const _Float16* hh = (const _Float16*)&raw;
      #pragma unroll
      for (int i = 0; i < 4; i++) acc[i] += w * (float)hh[i];
    }
  }
  #pragma unroll
  for (int o = 16; o < 64; o <<= 1){
    ssum += __shfl_xor(ssum, o);
    #pragma unroll
    for (int i = 0; i < CPL; i++) acc[i] += __shfl_xor(acc[i], o);
  }
  if (grp == 0){
    float inv_s = 1.f / ssum;
    float* op = out + (size_t)node * HC + c0;
    #pragma unroll
    for (int i = 0; i < CPL; i += 4){
      float4 o0 = make_float4(acc[i]*inv_s + bias[c0+i], acc[i+1]*inv_s + bias[c0+i+1],
                              acc[i+2]*inv_s + bias[c0+i+2], acc[i+3]*inv_s + bias[c0+i+3]);
      *(float4*)(op + i) = o0;
    }
  }
}

// ---------------- batchnorm stats ----------------
__global__ void k_bn_stats(const float* __restrict__ A, float* __restrict__ bsum,
                           float* __restrict__ bsq, int n){
  __shared__ float ls[256], lq[256];
  int t = threadIdx.x;
  int col = t & 127;
  int rhalf = t >> 7;
  float s = 0.f, q = 0.f;
  for (int r = blockIdx.x * 2 + rhalf; r < n; r += gridDim.x * 2){
    float v = A[(size_t)r * 128 + col];
    s += v; q += v * v;
  }
  ls[t] = s; lq[t] = q; __syncthreads();
  if (t < 128){
    s = ls[t] + ls[t + 128];
    q = lq[t] + lq[t + 128];
    atomicAdd(&bsum[col], s);
    atomicAdd(&bsq[col], q);
  }
}

// ---------------- global mean pool ----------------
__global__ void k_pool_acc(const float* __restrict__ A, const int* __restrict__ bids,
                           const int* __restrict__ flags, float* __restrict__ sums,
                           int* __restrict__ gcnt, int n){
  int t = threadIdx.x;
  int f = flags[0];
  int col = t & 63;
  int rsub = t >> 6;
  int r0 = blockIdx.x * 128;
  float acc = 0.f; int cnt = 0; int cur = -1;
  for (int i = 0; i < 32; i++){
    int r = r0 + rsub + i * 4;
    if (r >= n) break;
    int g = bids[(size_t)r << f];
    if (g != cur){
      if (cur >= 0){
        atomicAdd(&sums[cur * 64 + col], acc);
        if (col == 0) atomicAdd(&gcnt[cur], cnt);
      }
      cur = g; acc = 0.f; cnt = 0;
    }
    acc += A[(size_t)r * 64 + col];
    cnt++;
  }
  if (cur >= 0){
    atomicAdd(&sums[cur * 64 + col], acc);
    if (col == 0) atomicAdd(&gcnt[cur], cnt);
  }
}

__global__ void k_pool_fin(const float* __restrict__ sums, const int* __restrict__ gcnt,
                           float* __restrict__ out){
  int i = blockIdx.x * 256 + threadIdx.x;
  if (i >= NG * OUTC) return;
  int g = i >> 6;
  int cnt = gcnt[g];
  float c = (float)(cnt > 1 ? cnt : 1);
  out[i] = sums[i] / c;
}

extern "C" void kernel_launch(void* const* d_in, const int* in_sizes, int n_in,
                              void* d_out, int out_size, void* d_ws, size_t ws_size,
                              hipStream_t stream){
  const unsigned short* x    = (const unsigned short*)d_in[0];
  const int*            ei   = (const int*)d_in[1];
  const int*            bids = (const int*)d_in[2];

  char* p = (char*)d_ws;
  auto carve = [&](size_t bytes) -> void* {
    void* r = (void*)p; p += (bytes + 255) & ~size_t(255); return r;
  };
  float*    A      = (float*)carve((size_t)N_NODES * HD * 4);
  _Float16* h16    = (_Float16*)carve((size_t)N_NODES * HD * 2);
  float*    Afin   = (float*)carve((size_t)N_NODES * OUTC * 4);
  float*    par    = (float*)carve((size_t)PAR_TOTAL * 4);
  _Float16* wt16   = (_Float16*)carve((size_t)WT_TOTAL * 2);
  float*    als    = (float*)carve((size_t)N_NODES * 4 * 4);
  float*    ald    = (float*)carve((size_t)N_NODES * 4 * 4);
  int*      offs   = (int*)carve((size_t)(N_NODES + 1) * 4);
  int*      ssrc   = (int*)carve((size_t)E_EDGES * 4);
  unsigned int* ebuf2 = (unsigned int*)carve((size_t)E_EDGES * 4);
  int*      cntmat = (int*)carve((size_t)NB * NBLKC * 4);
  int*      gbase  = (int*)carve((size_t)NBLKC * NB * 4);
  int*      bbase  = (int*)carve((size_t)(NB + 1) * 4);
  int*      flags  = (int*)carve(256);
  // contiguous zero-region (single memset)
  char*     zbeg   = p;
  float*    bnbuf  = (float*)carve(3 * 1024);
  float*    psum   = (float*)carve(NG * OUTC * 4);
  int*      gcnt   = (int*)carve(256);
  size_t    zlen   = (size_t)(p - zbeg);

  // param table (dict order indices 3..24)
  PtrTab tab;
  int sizes[NPAR];
  for (int l = 0; l < 4; l++){
    int base = 3 + 4 * l;
    tab.p[4 * l + 0] = d_in[base + 0]; sizes[4 * l + 0] = (l < 3) ? 16384 : 8192;
    tab.p[4 * l + 1] = d_in[base + 1]; sizes[4 * l + 1] = (l < 3) ? 128 : 64;
    tab.p[4 * l + 2] = d_in[base + 2]; sizes[4 * l + 2] = (l < 3) ? 128 : 64;
    tab.p[4 * l + 3] = d_in[base + 3]; sizes[4 * l + 3] = (l < 3) ? 128 : 64;
  }
  for (int l = 0; l < 3; l++){
    tab.p[16 + 2 * l]     = d_in[19 + 2 * l];     sizes[16 + 2 * l] = 128;
    tab.p[16 + 2 * l + 1] = d_in[19 + 2 * l + 1]; sizes[16 + 2 * l + 1] = 128;
  }
  tab.off[0] = 0;
  for (int k = 0; k < NPAR; k++) tab.off[k + 1] = tab.off[k] + sizes[k];
  const float* pAS[4], *pAD[4], *pB[4], *pG[3], *pBE[3];
  for (int l = 0; l < 4; l++){
    pAS[l] = par + tab.off[4 * l + 1];
    pAD[l] = par + tab.off[4 * l + 2];
    pB[l]  = par + tab.off[4 * l + 3];
  }
  for (int l = 0; l < 3; l++){
    pG[l]  = par + tab.off[16 + 2 * l];
    pBE[l] = par + tab.off[16 + 2 * l + 1];
  }
  const _Float16* pWT[4] = { wt16, wt16 + 16384, wt16 + 32768, wt16 + 49152 };
  float* bnS[3], *bnQ[3];
  for (int l = 0; l < 3; l++){ bnS[l] = bnbuf + 256 * l; bnQ[l] = bnbuf + 256 * l + 128; }

  hipMemsetAsync(zbeg, 0, zlen, stream);

  // dtype detect + param prep
  k_detect<<<1, 256, 0, stream>>>(x, ei, flags);
  k_cvt_params<<<(PAR_TOTAL + 255) / 256, 256, 0, stream>>>(tab, flags, par);
  k_prep_w<<<(WT_TOTAL + 255) / 256, 256, 0, stream>>>(d_in[3], d_in[7], d_in[11], d_in[15],
                                                       flags, wt16);
  // CSR build (wide 4-phase)
  k_count<<<NBLKC, 256, 0, stream>>>(ei, flags, cntmat);
  k_scanmat<<<1, 256, 0, stream>>>(cntmat, gbase, bbase);
  k_binscatter<<<NBLKC, 256, 0, stream>>>(ei, flags, gbase, ebuf2);
  k_csrD<<<NB, 256, 0, stream>>>(ebuf2, bbase, offs, ssrc, N_NODES);

  int gemmBlocks = (N_NODES + 63) / 64;
  int attnBlocks = (N_NODES + 3) / 4;

  // layer 0
  k_gemm<128, true><<<gemmBlocks, 256, 0, stream>>>(
      (const void*)x, flags, nullptr, nullptr, nullptr, nullptr,
      pWT[0], pAS[0], pAD[0], h16, als, ald, N_NODES);
  k_attn<4, 32><<<attnBlocks, 256, 0, stream>>>(h16, als, ald, offs, ssrc, pB[0], A, N_NODES);
  k_bn_stats<<<256, 256, 0, stream>>>(A, bnS[0], bnQ[0], N_NODES);
  // layers 1,2
  for (int l = 1; l < 3; l++){
    k_gemm<128, false><<<gemmBlocks, 256, 0, stream>>>(
        (const void*)A, flags, bnS[l-1], bnQ[l-1], pG[l-1], pBE[l-1],
        pWT[l], pAS[l], pAD[l], h16, als, ald, N_NODES);
    k_attn<4, 32><<<attnBlocks, 256, 0, stream>>>(h16, als, ald, offs, ssrc, pB[l], A, N_NODES);
    k_bn_stats<<<256, 256, 0, stream>>>(A, bnS[l], bnQ[l], N_NODES);
  }
  // final layer (1 head, 64 ch)
  k_gemm<64, false><<<gemmBlocks, 256, 0, stream>>>(
      (const void*)A, flags, bnS[2], bnQ[2], pG[2], pBE[2],
      pWT[3], pAS[3], pAD[3], h16, als, ald, N_NODES);
  k_attn<1, 64><<<attnBlocks, 256, 0, stream>>>(h16, als, ald, offs, ssrc, pB[3], Afin, N_NODES);

  // global mean pool
  k_pool_acc<<<(N_NODES + 127) / 128, 256, 0, stream>>>(Afin, bids, flags, psum, gcnt, N_NODES);
  k_pool_fin<<<16, 256, 0, stream>>>(psum, gcnt, (float*)d_out);
}

// Round 8
// 527.110 us; speedup vs baseline: 1.6535x; 1.0551x over previous
//
#include <hip/hip_runtime.h>

#define DEVINL __device__ __forceinline__

constexpr int N_NODES = 50000;
constexpr int E_EDGES = 800000;
constexpr int HD      = 128;
constexpr int NG      = 64;
constexpr int OUTC    = 64;
constexpr int NPAR    = 22;
constexpr int PAR_TOTAL = 3*(16384+3*128) + (8192+3*64) + 6*128;  // 59456
constexpr int WT_TOTAL = 3*128*128 + 64*128;     // 57344 fp16
constexpr int NB      = (N_NODES + 1023) / 1024; // 49 buckets (1024 nodes)
constexpr int EBC     = 2048;                    // edges per count/scatter block
constexpr int NBLKC   = (E_EDGES + EBC - 1) / EBC; // 391

typedef _Float16 half8_t __attribute__((ext_vector_type(8)));
typedef _Float16 half4_t __attribute__((ext_vector_type(4)));
typedef float    float4_t __attribute__((ext_vector_type(4)));

DEVINL float bf2f(unsigned short u){
  union { unsigned int i; float f; } v; v.i = ((unsigned int)u) << 16; return v.f;
}
DEVINL float lrelu(float v){ return v > 0.f ? v : 0.2f * v; }

// ---------------- runtime dtype detection ----------------
__global__ void k_detect(const unsigned short* __restrict__ x,
                         const int* __restrict__ ei, int* __restrict__ flags){
  __shared__ int s_f32, s_i64;
  int t = threadIdx.x;
  if (t == 0){ s_f32 = 0; s_i64 = 1; }
  __syncthreads();
  for (int i = t; i < 2048; i += 256){
    float v = bf2f(x[i]);
    if (!(fabsf(v) < 1e4f)) s_f32 = 1;
  }
  for (int i = t; i < 512; i += 256){
    if (ei[2 * i + 1] != 0) s_i64 = 0;
  }
  __syncthreads();
  if (t == 0){ flags[0] = s_i64; flags[1] = s_f32; }
}

// ---------------- param conversion ----------------
struct PtrTab { const void* p[NPAR]; int off[NPAR + 1]; };

__global__ void k_cvt_params(PtrTab tab, const int* __restrict__ flags,
                             float* __restrict__ dst){
  int f = flags[1];
  int i = blockIdx.x * 256 + threadIdx.x;
  if (i >= tab.off[NPAR]) return;
  int k = 0;
  while (tab.off[k + 1] <= i) k++;
  int j = i - tab.off[k];
  dst[i] = f ? ((const float*)tab.p[k])[j] : bf2f(((const unsigned short*)tab.p[k])[j]);
}

// W -> fp16 transposed table wt16: layers 0..2 at l*16384 ([n][k]), layer 3 at 49152.
__global__ void k_prep_w(const void* __restrict__ W0, const void* __restrict__ W1,
                         const void* __restrict__ W2, const void* __restrict__ W3,
                         const int* __restrict__ flags, _Float16* __restrict__ wt16){
  int i = blockIdx.x * 256 + threadIdx.x;
  if (i >= WT_TOTAL) return;
  int f = flags[1];
  const void* W; int base, Mt;
  if (i < 49152){ int l = i >> 14; base = i & 16383; Mt = 128; W = (l == 0) ? W0 : (l == 1 ? W1 : W2); }
  else { base = i - 49152; Mt = 64; W = W3; }
  int nn = base >> 7, k = base & 127;
  float val = f ? ((const float*)W)[(size_t)k * Mt + nn]
                : bf2f(((const unsigned short*)W)[(size_t)k * Mt + nn]);
  wt16[i] = (_Float16)val;
}

// ---------------- CSR build: wide 4-phase (block-major count matrix) ----------------
// Phase 1: per-block bucket counts -> cntmat[blk][b]  (coalesced)
__global__ __launch_bounds__(256) void k_count(const int* __restrict__ ei,
                      const int* __restrict__ flags, int* __restrict__ cntmat){
  __shared__ int cnt[NB];
  int t = threadIdx.x, blk = blockIdx.x;
  if (t < NB) cnt[t] = 0;
  __syncthreads();
  int f = flags[0];
  int e0 = blk * EBC;
  #pragma unroll
  for (int j = 0; j < EBC / 256; j++){
    int e = e0 + t + j * 256;
    if (e < E_EDGES){
      int d = ei[(size_t)(E_EDGES + e) << f];
      atomicAdd(&cnt[d >> 10], 1);
    }
  }
  __syncthreads();
  if (t < NB) cntmat[blk * NB + t] = cnt[t];
}

// Phase 2: bucket bases + per-(blk,bucket) destination bases (coalesced rows)
__global__ void k_scanmat(const int* __restrict__ cntmat, int* __restrict__ gbase,
                          int* __restrict__ bbase){
  __shared__ int cbase[NB + 1];
  int t = threadIdx.x;
  int s = 0;
  if (t < NB){
    for (int blk = 0; blk < NBLKC; blk++) s += cntmat[blk * NB + t];
  }
  __shared__ int csum[NB];
  if (t < NB) csum[t] = s;
  __syncthreads();
  if (t == 0){
    int run = 0;
    for (int b = 0; b < NB; b++){ cbase[b] = run; run += csum[b]; }
    cbase[NB] = run;
  }
  __syncthreads();
  if (t <= NB) bbase[t] = cbase[t];
  if (t < NB){
    int run = cbase[t];
    for (int blk = 0; blk < NBLKC; blk++){
      gbase[blk * NB + t] = run;
      run += cntmat[blk * NB + t];
    }
  }
}

// Phase 3: scatter packed edges into bucket-major ebuf2 (exclusive windows)
__global__ __launch_bounds__(256) void k_binscatter(const int* __restrict__ ei,
                      const int* __restrict__ flags, const int* __restrict__ gbase,
                      unsigned int* __restrict__ ebuf2){
  __shared__ int cur[NB];
  int t = threadIdx.x, blk = blockIdx.x;
  if (t < NB) cur[t] = gbase[blk * NB + t];
  __syncthreads();
  int f = flags[0];
  int e0 = blk * EBC;
  #pragma unroll
  for (int j = 0; j < EBC / 256; j++){
    int e = e0 + t + j * 256;
    if (e < E_EDGES){
      int s = ei[(size_t)e << f];
      int d = ei[(size_t)(E_EDGES + e) << f];
      int p = atomicAdd(&cur[d >> 10], 1);
      ebuf2[p] = (unsigned int)s | ((unsigned int)d << 16);
    }
  }
}

// Phase 4: per-bucket (contiguous data): hist -> scan -> offs, then scatter ssrc
__global__ __launch_bounds__(256) void k_csrD(const unsigned int* __restrict__ ebuf2,
                      const int* __restrict__ bbase, int* __restrict__ offs,
                      int* __restrict__ ssrc, int n){
  __shared__ int hist[1024];
  __shared__ int wsum[256];
  int t = threadIdx.x, b = blockIdx.x;
  int nbase = b << 10;
  int s0 = bbase[b], s1 = bbase[b + 1];
  for (int i = t; i < 1024; i += 256) hist[i] = 0;
  __syncthreads();
  for (int i = s0 + t; i < s1; i += 256){
    unsigned int pk = ebuf2[i];
    atomicAdd(&hist[(int)(pk >> 16) - nbase], 1);
  }
  __syncthreads();
  int base4 = t * 4;
  int v0 = hist[base4], v1 = hist[base4 + 1], v2 = hist[base4 + 2], v3 = hist[base4 + 3];
  int s = v0 + v1 + v2 + v3;
  wsum[t] = s; __syncthreads();
  for (int off = 1; off < 256; off <<= 1){
    int x2 = (t >= off) ? wsum[t - off] : 0;
    __syncthreads();
    wsum[t] += x2;
    __syncthreads();
  }
  int run = s0 + wsum[t] - s;
  int node = nbase + base4;
  if (node < n) offs[node] = run;  hist[base4] = run;  run += v0;
  if (node + 1 < n) offs[node + 1] = run;  hist[base4 + 1] = run;  run += v1;
  if (node + 2 < n) offs[node + 2] = run;  hist[base4 + 2] = run;  run += v2;
  if (node + 3 < n) offs[node + 3] = run;  hist[base4 + 3] = run;
  if (b == NB - 1 && t == 255) offs[n] = s1;
  __syncthreads();
  for (int i = s0 + t; i < s1; i += 256){
    unsigned int pk = ebuf2[i];
    int p = atomicAdd(&hist[(int)(pk >> 16) - nbase], 1);
    ssrc[p] = (int)(pk & 0xFFFFu);
  }
}

// ---------------- fused MFMA GEMM ----------------
template<int MT, bool FIRST>
__global__ __launch_bounds__(256) void k_gemm(
    const void* __restrict__ Ain, const int* __restrict__ flags,
    const float* __restrict__ bnsum, const float* __restrict__ bnsq,
    const float* __restrict__ g, const float* __restrict__ be,
    const _Float16* __restrict__ Wt16,
    const float* __restrict__ a_s, const float* __restrict__ a_d,
    _Float16* __restrict__ h16, float* __restrict__ als, float* __restrict__ ald,
    int n){
  __shared__ _Float16 AhL[64 * 136];
  __shared__ _Float16 WtL[MT * 72];
  __shared__ float scale[128], shift[128];
  const int t = threadIdx.x;
  const int rowBase = blockIdx.x * 64;
  if (!FIRST){
    if (t < 128){
      float inv_n = 1.f / (float)n;
      float mu = bnsum[t] * inv_n;
      float var = bnsq[t] * inv_n - mu * mu;
      float sc = g[t] * rsqrtf(var + 1e-5f);
      scale[t] = sc; shift[t] = be[t] - mu * sc;
    }
    __syncthreads();
  }
  for (int f = t; f < 64 * 16; f += 256){
    int r = f >> 4, c8 = (f & 15) << 3;
    int row = rowBase + r;
    float v[8];
    if (row < n){
      if (FIRST){
        if (flags[1]){
          float4 x0 = *(const float4*)((const float*)Ain + (size_t)row * 128 + c8);
          float4 x1 = *(const float4*)((const float*)Ain + (size_t)row * 128 + c8 + 4);
          v[0]=x0.x; v[1]=x0.y; v[2]=x0.z; v[3]=x0.w;
          v[4]=x1.x; v[5]=x1.y; v[6]=x1.z; v[7]=x1.w;
        } else {
          const unsigned short* xp = (const unsigned short*)Ain + (size_t)row * 128 + c8;
          ushort4 u0 = *(const ushort4*)xp; ushort4 u1 = *(const ushort4*)(xp + 4);
          v[0]=bf2f(u0.x); v[1]=bf2f(u0.y); v[2]=bf2f(u0.z); v[3]=bf2f(u0.w);
          v[4]=bf2f(u1.x); v[5]=bf2f(u1.y); v[6]=bf2f(u1.z); v[7]=bf2f(u1.w);
        }
      } else {
        float4 x0 = *(const float4*)((const float*)Ain + (size_t)row * 128 + c8);
        float4 x1 = *(const float4*)((const float*)Ain + (size_t)row * 128 + c8 + 4);
        v[0]=x0.x; v[1]=x0.y; v[2]=x0.z; v[3]=x0.w;
        v[4]=x1.x; v[5]=x1.y; v[6]=x1.z; v[7]=x1.w;
        #pragma unroll
        for (int j = 0; j < 8; j++){
          float xv = v[j] * scale[c8 + j] + shift[c8 + j];
          v[j] = xv > 0.f ? xv : expm1f(xv);
        }
      }
    } else {
      #pragma unroll
      for (int j = 0; j < 8; j++) v[j] = 0.f;
    }
    half8_t h;
    #pragma unroll
    for (int j = 0; j < 8; j++) h[j] = (_Float16)v[j];
    *(half8_t*)&AhL[r * 136 + c8] = h;
  }
  const int lane = t & 63;
  const int m = lane & 15, quad = lane >> 4;
  const int band = (t >> 6) * 16;
  float4_t acc[MT / 16];
  #pragma unroll
  for (int ct = 0; ct < MT / 16; ct++) acc[ct] = (float4_t){0.f, 0.f, 0.f, 0.f};
  #pragma unroll
  for (int kh = 0; kh < 2; kh++){
    __syncthreads();
    for (int f = t; f < MT * 8; f += 256){
      int nn = f >> 3, c8 = (f & 7) << 3;
      *(half8_t*)&WtL[nn * 72 + c8] = *(const half8_t*)&Wt16[nn * 128 + kh * 64 + c8];
    }
    __syncthreads();
    half8_t a0 = *(half8_t*)&AhL[(band + m) * 136 + kh * 64 + quad * 8];
    half8_t a1 = *(half8_t*)&AhL[(band + m) * 136 + kh * 64 + 32 + quad * 8];
    #pragma unroll
    for (int ct = 0; ct < MT / 16; ct++){
      half8_t b0 = *(half8_t*)&WtL[(ct * 16 + m) * 72 + quad * 8];
      half8_t b1 = *(half8_t*)&WtL[(ct * 16 + m) * 72 + 32 + quad * 8];
      acc[ct] = __builtin_amdgcn_mfma_f32_16x16x32_f16(a0, b0, acc[ct], 0, 0, 0);
      acc[ct] = __builtin_amdgcn_mfma_f32_16x16x32_f16(a1, b1, acc[ct], 0, 0, 0);
    }
  }
  __syncthreads();
  #pragma unroll
  for (int ct = 0; ct < MT / 16; ct++)
    #pragma unroll
    for (int rg = 0; rg < 4; rg++)
      AhL[(band + quad * 4 + rg) * 136 + ct * 16 + m] = (_Float16)acc[ct][rg];
  __syncthreads();
  int r = t >> 2, q = t & 3;
  int row = rowBase + r;
  if (MT == 128){
    if (row < n){
      half8_t h0 = *(half8_t*)&AhL[r * 136 + q * 32];
      half8_t h1 = *(half8_t*)&AhL[r * 136 + q * 32 + 8];
      half8_t h2 = *(half8_t*)&AhL[r * 136 + q * 32 + 16];
      half8_t h3 = *(half8_t*)&AhL[r * 136 + q * 32 + 24];
      float pas = 0.f, pad = 0.f;
      #pragma unroll
      for (int j = 0; j < 8; j++){
        pas += (float)h0[j] * a_s[q * 32 + j]      + (float)h1[j] * a_s[q * 32 + 8 + j]
             + (float)h2[j] * a_s[q * 32 + 16 + j] + (float)h3[j] * a_s[q * 32 + 24 + j];
        pad += (float)h0[j] * a_d[q * 32 + j]      + (float)h1[j] * a_d[q * 32 + 8 + j]
             + (float)h2[j] * a_d[q * 32 + 16 + j] + (float)h3[j] * a_d[q * 32 + 24 + j];
      }
      als[(size_t)row * 4 + q] = pas;
      ald[(size_t)row * 4 + q] = pad;
      _Float16* hp = h16 + (size_t)row * 128 + q * 32;
      *(half8_t*)hp = h0; *(half8_t*)(hp + 8) = h1;
      *(half8_t*)(hp + 16) = h2; *(half8_t*)(hp + 24) = h3;
    }
  } else {
    half8_t h0 = *(half8_t*)&AhL[r * 136 + q * 16];
    half8_t h1 = *(half8_t*)&AhL[r * 136 + q * 16 + 8];
    float pas = 0.f, pad = 0.f;
    #pragma unroll
    for (int j = 0; j < 8; j++){
      pas += (float)h0[j] * a_s[q * 16 + j] + (float)h1[j] * a_s[q * 16 + 8 + j];
      pad += (float)h0[j] * a_d[q * 16 + j] + (float)h1[j] * a_d[q * 16 + 8 + j];
    }
    pas += __shfl_xor(pas, 1); pas += __shfl_xor(pas, 2);
    pad += __shfl_xor(pad, 1); pad += __shfl_xor(pad, 2);
    if (row < n){
      _Float16* hp = h16 + (size_t)row * 64 + q * 16;
      *(half8_t*)hp = h0; *(half8_t*)(hp + 8) = h1;
      if (q == 0){ als[row] = pas; ald[row] = pad; }
    }
  }
}

// ---------------- per-node GAT attention + aggregation ----------------
// 16-lane group per node (16 nodes/block). Each lane owns CPL channels of one
// head: ssum is per-lane, no cross-group combine. Edge loop 4-wide unrolled
// for memory-level parallelism. Single-pass softmax (logits bounded).
template<int H, int C>
__global__ __launch_bounds__(256) void k_attn(const _Float16* __restrict__ h16,
                      const float* __restrict__ als, const float* __restrict__ ald,
                      const int* __restrict__ offs, const int* __restrict__ ssrc,
                      const float* __restrict__ bias,
                      float* __restrict__ out, int n){
  constexpr int HC = H * C;
  constexpr int CPL = HC / 16;                 // 8 (4x32) or 4 (1x64)
  int node = blockIdx.x * 16 + (threadIdx.x >> 4);
  if (node >= n) return;
  int sub  = threadIdx.x & 15;
  int c0   = sub * CPL;
  int head = c0 / C;

  float ald_h = ald[(size_t)node * H + head];
  float acc[CPL];
  float ssum;
  {
    float w = __expf(lrelu(als[(size_t)node * H + head] + ald_h));
    ssum = w;
    const _Float16* hp = h16 + (size_t)node * HC + c0;
    #pragma unroll
    for (int i = 0; i < CPL; i++) acc[i] = w * (float)hp[i];
  }
  int beg = offs[node];
  int deg = offs[node + 1] - beg;
  int j = 0;
  // 4-wide main loop: 4 independent src->als,h chains in flight
  for (; j + 4 <= deg; j += 4){
    int s0 = ssrc[beg + j], s1 = ssrc[beg + j + 1];
    int s2 = ssrc[beg + j + 2], s3 = ssrc[beg + j + 3];
    float al0 = als[(size_t)s0 * H + head], al1 = als[(size_t)s1 * H + head];
    float al2 = als[(size_t)s2 * H + head], al3 = als[(size_t)s3 * H + head];
    if constexpr (CPL == 8){
      half8_t v0 = *(const half8_t*)(h16 + (size_t)s0 * HC + c0);
      half8_t v1 = *(const half8_t*)(h16 + (size_t)s1 * HC + c0);
      half8_t v2 = *(const half8_t*)(h16 + (size_t)s2 * HC + c0);
      half8_t v3 = *(const half8_t*)(h16 + (size_t)s3 * HC + c0);
      float w0 = __expf(lrelu(al0 + ald_h)), w1 = __expf(lrelu(al1 + ald_h));
      float w2 = __expf(lrelu(al2 + ald_h)), w3 = __expf(lrelu(al3 + ald_h));
      ssum += (w0 + w1) + (w2 + w3);
      #pragma unroll
      for (int i = 0; i < 8; i++)
        acc[i] += w0 * (float)v0[i] + w1 * (float)v1[i]
                + w2 * (float)v2[i] + w3 * (float)v3[i];
    } else {
      half4_t v0 = *(const half4_t*)(h16 + (size_t)s0 * HC + c0);
      half4_t v1 = *(const half4_t*)(h16 + (size_t)s1 * HC + c0);
      half4_t v2 = *(const half4_t*)(h16 + (size_t)s2 * HC + c0);
      half4_t v3 = *(const half4_t*)(h16 + (size_t)s3 * HC + c0);
      float w0 = __expf(lrelu(al0 + ald_h)), w1 = __expf(lrelu(al1 + ald_h));
      float w2 = __expf(lrelu(al2 + ald_h)), w3 = __expf(lrelu(al3 + ald_h));
      ssum += (w0 + w1) + (w2 + w3);
      #pragma unroll
      for (int i = 0; i < 4; i++)
        acc[i] += w0 * (float)v0[i] + w1 * (float)v1[i]
                + w2 * (float)v2[i] + w3 * (float)v3[i];
    }
  }
  for (; j < deg; j++){
    int s0 = ssrc[beg + j];
    float al0 = als[(size_t)s0 * H + head];
    float w0 = __expf(lrelu(al0 + ald_h));
    ssum += w0;
    const _Float16* hp = h16 + (size_t)s0 * HC + c0;
    #pragma unroll
    for (int i = 0; i < CPL; i++) acc[i] += w0 * (float)hp[i];
  }
  float inv_s = 1.f / ssum;
  float* op = out + (size_t)node * HC + c0;
  #pragma unroll
  for (int i = 0; i < CPL; i += 4){
    float4 o0 = make_float4(acc[i]*inv_s + bias[c0+i], acc[i+1]*inv_s + bias[c0+i+1],
                            acc[i+2]*inv_s + bias[c0+i+2], acc[i+3]*inv_s + bias[c0+i+3]);
    *(float4*)(op + i) = o0;
  }
}

// ---------------- batchnorm stats ----------------
__global__ void k_bn_stats(const float* __restrict__ A, float* __restrict__ bsum,
                           float* __restrict__ bsq, int n){
  __shared__ float ls[256], lq[256];
  int t = threadIdx.x;
  int col = t & 127;
  int rhalf = t >> 7;
  float s = 0.f, q = 0.f;
  for (int r = blockIdx.x * 2 + rhalf; r < n; r += gridDim.x * 2){
    float v = A[(size_t)r * 128 + col];
    s += v; q += v * v;
  }
  ls[t] = s; lq[t] = q; __syncthreads();
  if (t < 128){
    s = ls[t] + ls[t + 128];
    q = lq[t] + lq[t + 128];
    atomicAdd(&bsum[col], s);
    atomicAdd(&bsq[col], q);
  }
}

// ---------------- global mean pool ----------------
__global__ void k_pool_acc(const float* __restrict__ A, const int* __restrict__ bids,
                           const int* __restrict__ flags, float* __restrict__ sums,
                           int* __restrict__ gcnt, int n){
  int t = threadIdx.x;
  int f = flags[0];
  int col = t & 63;
  int rsub = t >> 6;
  int r0 = blockIdx.x * 128;
  float acc = 0.f; int cnt = 0; int cur = -1;
  for (int i = 0; i < 32; i++){
    int r = r0 + rsub + i * 4;
    if (r >= n) break;
    int g = bids[(size_t)r << f];
    if (g != cur){
      if (cur >= 0){
        atomicAdd(&sums[cur * 64 + col], acc);
        if (col == 0) atomicAdd(&gcnt[cur], cnt);
      }
      cur = g; acc = 0.f; cnt = 0;
    }
    acc += A[(size_t)r * 64 + col];
    cnt++;
  }
  if (cur >= 0){
    atomicAdd(&sums[cur * 64 + col], acc);
    if (col == 0) atomicAdd(&gcnt[cur], cnt);
  }
}

__global__ void k_pool_fin(const float* __restrict__ sums, const int* __restrict__ gcnt,
                           float* __restrict__ out){
  int i = blockIdx.x * 256 + threadIdx.x;
  if (i >= NG * OUTC) return;
  int g = i >> 6;
  int cnt = gcnt[g];
  float c = (float)(cnt > 1 ? cnt : 1);
  out[i] = sums[i] / c;
}

extern "C" void kernel_launch(void* const* d_in, const int* in_sizes, int n_in,
                              void* d_out, int out_size, void* d_ws, size_t ws_size,
                              hipStream_t stream){
  const unsigned short* x    = (const unsigned short*)d_in[0];
  const int*            ei   = (const int*)d_in[1];
  const int*            bids = (const int*)d_in[2];

  char* p = (char*)d_ws;
  auto carve = [&](size_t bytes) -> void* {
    void* r = (void*)p; p += (bytes + 255) & ~size_t(255); return r;
  };
  float*    A      = (float*)carve((size_t)N_NODES * HD * 4);
  _Float16* h16    = (_Float16*)carve((size_t)N_NODES * HD * 2);
  float*    Afin   = (float*)carve((size_t)N_NODES * OUTC * 4);
  float*    par    = (float*)carve((size_t)PAR_TOTAL * 4);
  _Float16* wt16   = (_Float16*)carve((size_t)WT_TOTAL * 2);
  float*    als    = (float*)carve((size_t)N_NODES * 4 * 4);
  float*    ald    = (float*)carve((size_t)N_NODES * 4 * 4);
  int*      offs   = (int*)carve((size_t)(N_NODES + 1) * 4);
  int*      ssrc   = (int*)carve((size_t)E_EDGES * 4);
  unsigned int* ebuf2 = (unsigned int*)carve((size_t)E_EDGES * 4);
  int*      cntmat = (int*)carve((size_t)NBLKC * NB * 4);
  int*      gbase  = (int*)carve((size_t)NBLKC * NB * 4);
  int*      bbase  = (int*)carve((size_t)(NB + 1) * 4);
  int*      flags  = (int*)carve(256);
  // contiguous zero-region (single memset)
  char*     zbeg   = p;
  float*    bnbuf  = (float*)carve(3 * 1024);
  float*    psum   = (float*)carve(NG * OUTC * 4);
  int*      gcnt   = (int*)carve(256);
  size_t    zlen   = (size_t)(p - zbeg);

  // param table (dict order indices 3..24)
  PtrTab tab;
  int sizes[NPAR];
  for (int l = 0; l < 4; l++){
    int base = 3 + 4 * l;
    tab.p[4 * l + 0] = d_in[base + 0]; sizes[4 * l + 0] = (l < 3) ? 16384 : 8192;
    tab.p[4 * l + 1] = d_in[base + 1]; sizes[4 * l + 1] = (l < 3) ? 128 : 64;
    tab.p[4 * l + 2] = d_in[base + 2]; sizes[4 * l + 2] = (l < 3) ? 128 : 64;
    tab.p[4 * l + 3] = d_in[base + 3]; sizes[4 * l + 3] = (l < 3) ? 128 : 64;
  }
  for (int l = 0; l < 3; l++){
    tab.p[16 + 2 * l]     = d_in[19 + 2 * l];     sizes[16 + 2 * l] = 128;
    tab.p[16 + 2 * l + 1] = d_in[19 + 2 * l + 1]; sizes[16 + 2 * l + 1] = 128;
  }
  tab.off[0] = 0;
  for (int k = 0; k < NPAR; k++) tab.off[k + 1] = tab.off[k] + sizes[k];
  const float* pAS[4], *pAD[4], *pB[4], *pG[3], *pBE[3];
  for (int l = 0; l < 4; l++){
    pAS[l] = par + tab.off[4 * l + 1];
    pAD[l] = par + tab.off[4 * l + 2];
    pB[l]  = par + tab.off[4 * l + 3];
  }
  for (int l = 0; l < 3; l++){
    pG[l]  = par + tab.off[16 + 2 * l];
    pBE[l] = par + tab.off[16 + 2 * l + 1];
  }
  const _Float16* pWT[4] = { wt16, wt16 + 16384, wt16 + 32768, wt16 + 49152 };
  float* bnS[3], *bnQ[3];
  for (int l = 0; l < 3; l++){ bnS[l] = bnbuf + 256 * l; bnQ[l] = bnbuf + 256 * l + 128; }

  hipMemsetAsync(zbeg, 0, zlen, stream);

  // dtype detect + param prep
  k_detect<<<1, 256, 0, stream>>>(x, ei, flags);
  k_cvt_params<<<(PAR_TOTAL + 255) / 256, 256, 0, stream>>>(tab, flags, par);
  k_prep_w<<<(WT_TOTAL + 255) / 256, 256, 0, stream>>>(d_in[3], d_in[7], d_in[11], d_in[15],
                                                       flags, wt16);
  // CSR build (wide 4-phase)
  k_count<<<NBLKC, 256, 0, stream>>>(ei, flags, cntmat);
  k_scanmat<<<1, 256, 0, stream>>>(cntmat, gbase, bbase);
  k_binscatter<<<NBLKC, 256, 0, stream>>>(ei, flags, gbase, ebuf2);
  k_csrD<<<NB, 256, 0, stream>>>(ebuf2, bbase, offs, ssrc, N_NODES);

  int gemmBlocks = (N_NODES + 63) / 64;
  int attnBlocks = (N_NODES + 15) / 16;

  // layer 0
  k_gemm<128, true><<<gemmBlocks, 256, 0, stream>>>(
      (const void*)x, flags, nullptr, nullptr, nullptr, nullptr,
      pWT[0], pAS[0], pAD[0], h16, als, ald, N_NODES);
  k_attn<4, 32><<<attnBlocks, 256, 0, stream>>>(h16, als, ald, offs, ssrc, pB[0], A, N_NODES);
  k_bn_stats<<<256, 256, 0, stream>>>(A, bnS[0], bnQ[0], N_NODES);
  // layers 1,2
  for (int l = 1; l < 3; l++){
    k_gemm<128, false><<<gemmBlocks, 256, 0, stream>>>(
        (const void*)A, flags, bnS[l-1], bnQ[l-1], pG[l-1], pBE[l-1],
        pWT[l], pAS[l], pAD[l], h16, als, ald, N_NODES);
    k_attn<4, 32><<<attnBlocks, 256, 0, stream>>>(h16, als, ald, offs, ssrc, pB[l], A, N_NODES);
    k_bn_stats<<<256, 256, 0, stream>>>(A, bnS[l], bnQ[l], N_NODES);
  }
  // final layer (1 head, 64 ch)
  k_gemm<64, false><<<gemmBlocks, 256, 0, stream>>>(
      (const void*)A, flags, bnS[2], bnQ[2], pG[2], pBE[2],
      pWT[3], pAS[3], pAD[3], h16, als, ald, N_NODES);
  k_attn<1, 64><<<attnBlocks, 256, 0, stream>>>(h16, als, ald, offs, ssrc, pB[3], Afin, N_NODES);

  // global mean pool
  k_pool_acc<<<(N_NODES + 127) / 128, 256, 0, stream>>>(Afin, bids, flags, psum, gcnt, N_NODES);
  k_pool_fin<<<16, 256, 0, stream>>>(psum, gcnt, (float*)d_out);
}

// Round 9
// 511.589 us; speedup vs baseline: 1.7037x; 1.0303x over previous
//
#include <hip/hip_runtime.h>

#define DEVINL __device__ __forceinline__

constexpr int N_NODES = 50000;
constexpr int E_EDGES = 800000;
constexpr int HD      = 128;
constexpr int NG      = 64;
constexpr int OUTC    = 64;
constexpr int NPAR    = 22;
constexpr int PAR_TOTAL = 3*(16384+3*128) + (8192+3*64) + 6*128;  // 59456
constexpr int WT_TOTAL = 3*128*128 + 64*128;     // 57344 fp16
constexpr int NB      = (N_NODES + 1023) / 1024; // 49 buckets (1024 nodes)
constexpr int EBC     = 2048;                    // edges per count/scatter block
constexpr int NBLKC   = (E_EDGES + EBC - 1) / EBC; // 391

typedef _Float16 half8_t __attribute__((ext_vector_type(8)));
typedef _Float16 half4_t __attribute__((ext_vector_type(4)));
typedef float    float4_t __attribute__((ext_vector_type(4)));

DEVINL float bf2f(unsigned short u){
  union { unsigned int i; float f; } v; v.i = ((unsigned int)u) << 16; return v.f;
}
DEVINL float lrelu(float v){ return v > 0.f ? v : 0.2f * v; }

// ---------------- runtime dtype detection ----------------
__global__ void k_detect(const unsigned short* __restrict__ x,
                         const int* __restrict__ ei, int* __restrict__ flags){
  __shared__ int s_f32, s_i64;
  int t = threadIdx.x;
  if (t == 0){ s_f32 = 0; s_i64 = 1; }
  __syncthreads();
  for (int i = t; i < 2048; i += 256){
    float v = bf2f(x[i]);
    if (!(fabsf(v) < 1e4f)) s_f32 = 1;
  }
  for (int i = t; i < 512; i += 256){
    if (ei[2 * i + 1] != 0) s_i64 = 0;
  }
  __syncthreads();
  if (t == 0){ flags[0] = s_i64; flags[1] = s_f32; }
}

// ---------------- param conversion + W transpose (merged) ----------------
struct PtrTab { const void* p[NPAR]; int off[NPAR + 1]; };

__global__ void k_prep(PtrTab tab, const int* __restrict__ flags,
                       float* __restrict__ dst,
                       const void* __restrict__ W0, const void* __restrict__ W1,
                       const void* __restrict__ W2, const void* __restrict__ W3,
                       _Float16* __restrict__ wt16){
  int f = flags[1];
  int i = blockIdx.x * 256 + threadIdx.x;
  if (i < PAR_TOTAL){
    int k = 0;
    while (tab.off[k + 1] <= i) k++;
    int j = i - tab.off[k];
    dst[i] = f ? ((const float*)tab.p[k])[j] : bf2f(((const unsigned short*)tab.p[k])[j]);
    return;
  }
  int w = i - PAR_TOTAL;
  if (w >= WT_TOTAL) return;
  const void* W; int base, Mt;
  if (w < 49152){ int l = w >> 14; base = w & 16383; Mt = 128; W = (l == 0) ? W0 : (l == 1 ? W1 : W2); }
  else { base = w - 49152; Mt = 64; W = W3; }
  int nn = base >> 7, k = base & 127;
  float val = f ? ((const float*)W)[(size_t)k * Mt + nn]
                : bf2f(((const unsigned short*)W)[(size_t)k * Mt + nn]);
  wt16[w] = (_Float16)val;
}

// ---------------- CSR build: wide 4-phase (block-major count matrix) ----------------
__global__ __launch_bounds__(256) void k_count(const int* __restrict__ ei,
                      const int* __restrict__ flags, int* __restrict__ cntmat){
  __shared__ int cnt[NB];
  int t = threadIdx.x, blk = blockIdx.x;
  if (t < NB) cnt[t] = 0;
  __syncthreads();
  int f = flags[0];
  int e0 = blk * EBC;
  #pragma unroll
  for (int j = 0; j < EBC / 256; j++){
    int e = e0 + t + j * 256;
    if (e < E_EDGES){
      int d = ei[(size_t)(E_EDGES + e) << f];
      atomicAdd(&cnt[d >> 10], 1);
    }
  }
  __syncthreads();
  if (t < NB) cntmat[blk * NB + t] = cnt[t];
}

__global__ void k_scanmat(const int* __restrict__ cntmat, int* __restrict__ gbase,
                          int* __restrict__ bbase){
  __shared__ int cbase[NB + 1];
  __shared__ int csum[NB];
  int t = threadIdx.x;
  int s = 0;
  if (t < NB){
    for (int blk = 0; blk < NBLKC; blk++) s += cntmat[blk * NB + t];
    csum[t] = s;
  }
  __syncthreads();
  if (t == 0){
    int run = 0;
    for (int b = 0; b < NB; b++){ cbase[b] = run; run += csum[b]; }
    cbase[NB] = run;
  }
  __syncthreads();
  if (t <= NB) bbase[t] = cbase[t];
  if (t < NB){
    int run = cbase[t];
    for (int blk = 0; blk < NBLKC; blk++){
      gbase[blk * NB + t] = run;
      run += cntmat[blk * NB + t];
    }
  }
}

__global__ __launch_bounds__(256) void k_binscatter(const int* __restrict__ ei,
                      const int* __restrict__ flags, const int* __restrict__ gbase,
                      unsigned int* __restrict__ ebuf2){
  __shared__ int cur[NB];
  int t = threadIdx.x, blk = blockIdx.x;
  if (t < NB) cur[t] = gbase[blk * NB + t];
  __syncthreads();
  int f = flags[0];
  int e0 = blk * EBC;
  #pragma unroll
  for (int j = 0; j < EBC / 256; j++){
    int e = e0 + t + j * 256;
    if (e < E_EDGES){
      int s = ei[(size_t)e << f];
      int d = ei[(size_t)(E_EDGES + e) << f];
      int p = atomicAdd(&cur[d >> 10], 1);
      ebuf2[p] = (unsigned int)s | ((unsigned int)d << 16);
    }
  }
}

__global__ __launch_bounds__(256) void k_csrD(const unsigned int* __restrict__ ebuf2,
                      const int* __restrict__ bbase, int* __restrict__ offs,
                      int* __restrict__ ssrc, int n){
  __shared__ int hist[1024];
  __shared__ int wsum[256];
  int t = threadIdx.x, b = blockIdx.x;
  int nbase = b << 10;
  int s0 = bbase[b], s1 = bbase[b + 1];
  for (int i = t; i < 1024; i += 256) hist[i] = 0;
  __syncthreads();
  for (int i = s0 + t; i < s1; i += 256){
    unsigned int pk = ebuf2[i];
    atomicAdd(&hist[(int)(pk >> 16) - nbase], 1);
  }
  __syncthreads();
  int base4 = t * 4;
  int v0 = hist[base4], v1 = hist[base4 + 1], v2 = hist[base4 + 2], v3 = hist[base4 + 3];
  int s = v0 + v1 + v2 + v3;
  wsum[t] = s; __syncthreads();
  for (int off = 1; off < 256; off <<= 1){
    int x2 = (t >= off) ? wsum[t - off] : 0;
    __syncthreads();
    wsum[t] += x2;
    __syncthreads();
  }
  int run = s0 + wsum[t] - s;
  int node = nbase + base4;
  if (node < n) offs[node] = run;  hist[base4] = run;  run += v0;
  if (node + 1 < n) offs[node + 1] = run;  hist[base4 + 1] = run;  run += v1;
  if (node + 2 < n) offs[node + 2] = run;  hist[base4 + 2] = run;  run += v2;
  if (node + 3 < n) offs[node + 3] = run;  hist[base4 + 3] = run;
  if (b == NB - 1 && t == 255) offs[n] = s1;
  __syncthreads();
  for (int i = s0 + t; i < s1; i += 256){
    unsigned int pk = ebuf2[i];
    int p = atomicAdd(&hist[(int)(pk >> 16) - nbase], 1);
    ssrc[p] = (int)(pk & 0xFFFFu);
  }
}

// ---------------- fused MFMA GEMM ----------------
// FIRST: Ain = raw x (dtype-flagged). else: Ain = fp16 post-attn, BN+ELU fused.
template<int MT, bool FIRST>
__global__ __launch_bounds__(256) void k_gemm(
    const void* __restrict__ Ain, const int* __restrict__ flags,
    const float* __restrict__ bnsum, const float* __restrict__ bnsq,
    const float* __restrict__ g, const float* __restrict__ be,
    const _Float16* __restrict__ Wt16,
    const float* __restrict__ a_s, const float* __restrict__ a_d,
    _Float16* __restrict__ h16, float* __restrict__ als, float* __restrict__ ald,
    int n){
  __shared__ _Float16 AhL[64 * 136];
  __shared__ _Float16 WtL[MT * 72];
  __shared__ float scale[128], shift[128];
  const int t = threadIdx.x;
  const int rowBase = blockIdx.x * 64;
  if (!FIRST){
    if (t < 128){
      float inv_n = 1.f / (float)n;
      float mu = bnsum[t] * inv_n;
      float var = bnsq[t] * inv_n - mu * mu;
      float sc = g[t] * rsqrtf(var + 1e-5f);
      scale[t] = sc; shift[t] = be[t] - mu * sc;
    }
    __syncthreads();
  }
  for (int f = t; f < 64 * 16; f += 256){
    int r = f >> 4, c8 = (f & 15) << 3;
    int row = rowBase + r;
    float v[8];
    if (row < n){
      if (FIRST){
        if (flags[1]){
          float4 x0 = *(const float4*)((const float*)Ain + (size_t)row * 128 + c8);
          float4 x1 = *(const float4*)((const float*)Ain + (size_t)row * 128 + c8 + 4);
          v[0]=x0.x; v[1]=x0.y; v[2]=x0.z; v[3]=x0.w;
          v[4]=x1.x; v[5]=x1.y; v[6]=x1.z; v[7]=x1.w;
        } else {
          const unsigned short* xp = (const unsigned short*)Ain + (size_t)row * 128 + c8;
          ushort4 u0 = *(const ushort4*)xp; ushort4 u1 = *(const ushort4*)(xp + 4);
          v[0]=bf2f(u0.x); v[1]=bf2f(u0.y); v[2]=bf2f(u0.z); v[3]=bf2f(u0.w);
          v[4]=bf2f(u1.x); v[5]=bf2f(u1.y); v[6]=bf2f(u1.z); v[7]=bf2f(u1.w);
        }
      } else {
        half8_t a8 = *(const half8_t*)((const _Float16*)Ain + (size_t)row * 128 + c8);
        #pragma unroll
        for (int j = 0; j < 8; j++){
          float xv = (float)a8[j] * scale[c8 + j] + shift[c8 + j];
          v[j] = xv > 0.f ? xv : (__expf(xv) - 1.f);
        }
      }
    } else {
      #pragma unroll
      for (int j = 0; j < 8; j++) v[j] = 0.f;
    }
    half8_t h;
    #pragma unroll
    for (int j = 0; j < 8; j++) h[j] = (_Float16)v[j];
    *(half8_t*)&AhL[r * 136 + c8] = h;
  }
  const int lane = t & 63;
  const int m = lane & 15, quad = lane >> 4;
  const int band = (t >> 6) * 16;
  float4_t acc[MT / 16];
  #pragma unroll
  for (int ct = 0; ct < MT / 16; ct++) acc[ct] = (float4_t){0.f, 0.f, 0.f, 0.f};
  #pragma unroll
  for (int kh = 0; kh < 2; kh++){
    __syncthreads();
    for (int f = t; f < MT * 8; f += 256){
      int nn = f >> 3, c8 = (f & 7) << 3;
      *(half8_t*)&WtL[nn * 72 + c8] = *(const half8_t*)&Wt16[nn * 128 + kh * 64 + c8];
    }
    __syncthreads();
    half8_t a0 = *(half8_t*)&AhL[(band + m) * 136 + kh * 64 + quad * 8];
    half8_t a1 = *(half8_t*)&AhL[(band + m) * 136 + kh * 64 + 32 + quad * 8];
    #pragma unroll
    for (int ct = 0; ct < MT / 16; ct++){
      half8_t b0 = *(half8_t*)&WtL[(ct * 16 + m) * 72 + quad * 8];
      half8_t b1 = *(half8_t*)&WtL[(ct * 16 + m) * 72 + 32 + quad * 8];
      acc[ct] = __builtin_amdgcn_mfma_f32_16x16x32_f16(a0, b0, acc[ct], 0, 0, 0);
      acc[ct] = __builtin_amdgcn_mfma_f32_16x16x32_f16(a1, b1, acc[ct], 0, 0, 0);
    }
  }
  __syncthreads();
  #pragma unroll
  for (int ct = 0; ct < MT / 16; ct++)
    #pragma unroll
    for (int rg = 0; rg < 4; rg++)
      AhL[(band + quad * 4 + rg) * 136 + ct * 16 + m] = (_Float16)acc[ct][rg];
  __syncthreads();
  int r = t >> 2, q = t & 3;
  int row = rowBase + r;
  if (MT == 128){
    if (row < n){
      half8_t h0 = *(half8_t*)&AhL[r * 136 + q * 32];
      half8_t h1 = *(half8_t*)&AhL[r * 136 + q * 32 + 8];
      half8_t h2 = *(half8_t*)&AhL[r * 136 + q * 32 + 16];
      half8_t h3 = *(half8_t*)&AhL[r * 136 + q * 32 + 24];
      float pas = 0.f, pad = 0.f;
      #pragma unroll
      for (int j = 0; j < 8; j++){
        pas += (float)h0[j] * a_s[q * 32 + j]      + (float)h1[j] * a_s[q * 32 + 8 + j]
             + (float)h2[j] * a_s[q * 32 + 16 + j] + (float)h3[j] * a_s[q * 32 + 24 + j];
        pad += (float)h0[j] * a_d[q * 32 + j]      + (float)h1[j] * a_d[q * 32 + 8 + j]
             + (float)h2[j] * a_d[q * 32 + 16 + j] + (float)h3[j] * a_d[q * 32 + 24 + j];
      }
      als[(size_t)row * 4 + q] = pas;
      ald[(size_t)row * 4 + q] = pad;
      _Float16* hp = h16 + (size_t)row * 128 + q * 32;
      *(half8_t*)hp = h0; *(half8_t*)(hp + 8) = h1;
      *(half8_t*)(hp + 16) = h2; *(half8_t*)(hp + 24) = h3;
    }
  } else {
    half8_t h0 = *(half8_t*)&AhL[r * 136 + q * 16];
    half8_t h1 = *(half8_t*)&AhL[r * 136 + q * 16 + 8];
    float pas = 0.f, pad = 0.f;
    #pragma unroll
    for (int j = 0; j < 8; j++){
      pas += (float)h0[j] * a_s[q * 16 + j] + (float)h1[j] * a_s[q * 16 + 8 + j];
      pad += (float)h0[j] * a_d[q * 16 + j] + (float)h1[j] * a_d[q * 16 + 8 + j];
    }
    pas += __shfl_xor(pas, 1); pas += __shfl_xor(pas, 2);
    pad += __shfl_xor(pad, 1); pad += __shfl_xor(pad, 2);
    if (row < n){
      _Float16* hp = h16 + (size_t)row * 64 + q * 16;
      *(half8_t*)hp = h0; *(half8_t*)(hp + 8) = h1;
      if (q == 0){ als[row] = pas; ald[row] = pad; }
    }
  }
}

// ---------------- per-node GAT attention + aggregation ----------------
// 16-lane group per node; per-lane ssum (head-local channels); 4-wide MLP loop.
// F16OUT: layers 0-2 write fp16 (next gemm rounds to fp16 anyway).
template<int H, int C, bool F16OUT>
__global__ __launch_bounds__(256) void k_attn(const _Float16* __restrict__ h16,
                      const float* __restrict__ als, const float* __restrict__ ald,
                      const int* __restrict__ offs, const int* __restrict__ ssrc,
                      const float* __restrict__ bias,
                      void* __restrict__ out, int n){
  constexpr int HC = H * C;
  constexpr int CPL = HC / 16;                 // 8 (4x32) or 4 (1x64)
  int node = blockIdx.x * 16 + (threadIdx.x >> 4);
  if (node >= n) return;
  int sub  = threadIdx.x & 15;
  int c0   = sub * CPL;
  int head = c0 / C;

  float ald_h = ald[(size_t)node * H + head];
  float acc[CPL];
  float ssum;
  {
    float w = __expf(lrelu(als[(size_t)node * H + head] + ald_h));
    ssum = w;
    const _Float16* hp = h16 + (size_t)node * HC + c0;
    #pragma unroll
    for (int i = 0; i < CPL; i++) acc[i] = w * (float)hp[i];
  }
  int beg = offs[node];
  int deg = offs[node + 1] - beg;
  int j = 0;
  for (; j + 4 <= deg; j += 4){
    int s0 = ssrc[beg + j], s1 = ssrc[beg + j + 1];
    int s2 = ssrc[beg + j + 2], s3 = ssrc[beg + j + 3];
    float al0 = als[(size_t)s0 * H + head], al1 = als[(size_t)s1 * H + head];
    float al2 = als[(size_t)s2 * H + head], al3 = als[(size_t)s3 * H + head];
    if constexpr (CPL == 8){
      half8_t v0 = *(const half8_t*)(h16 + (size_t)s0 * HC + c0);
      half8_t v1 = *(const half8_t*)(h16 + (size_t)s1 * HC + c0);
      half8_t v2 = *(const half8_t*)(h16 + (size_t)s2 * HC + c0);
      half8_t v3 = *(const half8_t*)(h16 + (size_t)s3 * HC + c0);
      float w0 = __expf(lrelu(al0 + ald_h)), w1 = __expf(lrelu(al1 + ald_h));
      float w2 = __expf(lrelu(al2 + ald_h)), w3 = __expf(lrelu(al3 + ald_h));
      ssum += (w0 + w1) + (w2 + w3);
      #pragma unroll
      for (int i = 0; i < 8; i++)
        acc[i] += w0 * (float)v0[i] + w1 * (float)v1[i]
                + w2 * (float)v2[i] + w3 * (float)v3[i];
    } else {
      half4_t v0 = *(const half4_t*)(h16 + (size_t)s0 * HC + c0);
      half4_t v1 = *(const half4_t*)(h16 + (size_t)s1 * HC + c0);
      half4_t v2 = *(const half4_t*)(h16 + (size_t)s2 * HC + c0);
      half4_t v3 = *(const half4_t*)(h16 + (size_t)s3 * HC + c0);
      float w0 = __expf(lrelu(al0 + ald_h)), w1 = __expf(lrelu(al1 + ald_h));
      float w2 = __expf(lrelu(al2 + ald_h)), w3 = __expf(lrelu(al3 + ald_h));
      ssum += (w0 + w1) + (w2 + w3);
      #pragma unroll
      for (int i = 0; i < 4; i++)
        acc[i] += w0 * (float)v0[i] + w1 * (float)v1[i]
                + w2 * (float)v2[i] + w3 * (float)v3[i];
    }
  }
  for (; j < deg; j++){
    int s0 = ssrc[beg + j];
    float al0 = als[(size_t)s0 * H + head];
    float w0 = __expf(lrelu(al0 + ald_h));
    ssum += w0;
    const _Float16* hp = h16 + (size_t)s0 * HC + c0;
    #pragma unroll
    for (int i = 0; i < CPL; i++) acc[i] += w0 * (float)hp[i];
  }
  float inv_s = 1.f / ssum;
  if constexpr (F16OUT){
    _Float16* op = (_Float16*)out + (size_t)node * HC + c0;
    half8_t o;
    #pragma unroll
    for (int i = 0; i < CPL; i++) o[i] = (_Float16)(acc[i] * inv_s + bias[c0 + i]);
    *(half8_t*)op = o;   // CPL==8 for F16OUT path
  } else {
    float* op = (float*)out + (size_t)node * HC + c0;
    #pragma unroll
    for (int i = 0; i < CPL; i += 4){
      float4 o0 = make_float4(acc[i]*inv_s + bias[c0+i], acc[i+1]*inv_s + bias[c0+i+1],
                              acc[i+2]*inv_s + bias[c0+i+2], acc[i+3]*inv_s + bias[c0+i+3]);
      *(float4*)(op + i) = o0;
    }
  }
}

// ---------------- batchnorm stats (fp16 input) ----------------
__global__ void k_bn_stats(const _Float16* __restrict__ A16, float* __restrict__ bsum,
                           float* __restrict__ bsq, int n){
  __shared__ float ls[256], lq[256];
  int t = threadIdx.x;
  int col = t & 127;
  int rhalf = t >> 7;
  float s = 0.f, q = 0.f;
  for (int r = blockIdx.x * 2 + rhalf; r < n; r += gridDim.x * 2){
    float v = (float)A16[(size_t)r * 128 + col];
    s += v; q += v * v;
  }
  ls[t] = s; lq[t] = q; __syncthreads();
  if (t < 128){
    s = ls[t] + ls[t + 128];
    q = lq[t] + lq[t + 128];
    atomicAdd(&bsum[col], s);
    atomicAdd(&bsq[col], q);
  }
}

// ---------------- global mean pool ----------------
__global__ void k_pool_acc(const float* __restrict__ A, const int* __restrict__ bids,
                           const int* __restrict__ flags, float* __restrict__ sums,
                           int* __restrict__ gcnt, int n){
  int t = threadIdx.x;
  int f = flags[0];
  int col = t & 63;
  int rsub = t >> 6;
  int r0 = blockIdx.x * 128;
  float acc = 0.f; int cnt = 0; int cur = -1;
  for (int i = 0; i < 32; i++){
    int r = r0 + rsub + i * 4;
    if (r >= n) break;
    int g = bids[(size_t)r << f];
    if (g != cur){
      if (cur >= 0){
        atomicAdd(&sums[cur * 64 + col], acc);
        if (col == 0) atomicAdd(&gcnt[cur], cnt);
      }
      cur = g; acc = 0.f; cnt = 0;
    }
    acc += A[(size_t)r * 64 + col];
    cnt++;
  }
  if (cur >= 0){
    atomicAdd(&sums[cur * 64 + col], acc);
    if (col == 0) atomicAdd(&gcnt[cur], cnt);
  }
}

__global__ void k_pool_fin(const float* __restrict__ sums, const int* __restrict__ gcnt,
                           float* __restrict__ out){
  int i = blockIdx.x * 256 + threadIdx.x;
  if (i >= NG * OUTC) return;
  int g = i >> 6;
  int cnt = gcnt[g];
  float c = (float)(cnt > 1 ? cnt : 1);
  out[i] = sums[i] / c;
}

extern "C" void kernel_launch(void* const* d_in, const int* in_sizes, int n_in,
                              void* d_out, int out_size, void* d_ws, size_t ws_size,
                              hipStream_t stream){
  const unsigned short* x    = (const unsigned short*)d_in[0];
  const int*            ei   = (const int*)d_in[1];
  const int*            bids = (const int*)d_in[2];

  char* p = (char*)d_ws;
  auto carve = [&](size_t bytes) -> void* {
    void* r = (void*)p; p += (bytes + 255) & ~size_t(255); return r;
  };
  _Float16* a16    = (_Float16*)carve((size_t)N_NODES * HD * 2);  // post-attn (fp16)
  _Float16* h16    = (_Float16*)carve((size_t)N_NODES * HD * 2);  // post-gemm (fp16)
  float*    Afin   = (float*)carve((size_t)N_NODES * OUTC * 4);   // final attn out
  float*    par    = (float*)carve((size_t)PAR_TOTAL * 4);
  _Float16* wt16   = (_Float16*)carve((size_t)WT_TOTAL * 2);
  float*    als    = (float*)carve((size_t)N_NODES * 4 * 4);
  float*    ald    = (float*)carve((size_t)N_NODES * 4 * 4);
  int*      offs   = (int*)carve((size_t)(N_NODES + 1) * 4);
  int*      ssrc   = (int*)carve((size_t)E_EDGES * 4);
  unsigned int* ebuf2 = (unsigned int*)carve((size_t)E_EDGES * 4);
  int*      cntmat = (int*)carve((size_t)NBLKC * NB * 4);
  int*      gbase  = (int*)carve((size_t)NBLKC * NB * 4);
  int*      bbase  = (int*)carve((size_t)(NB + 1) * 4);
  int*      flags  = (int*)carve(256);
  // contiguous zero-region (single memset)
  char*     zbeg   = p;
  float*    bnbuf  = (float*)carve(3 * 1024);
  float*    psum   = (float*)carve(NG * OUTC * 4);
  int*      gcnt   = (int*)carve(256);
  size_t    zlen   = (size_t)(p - zbeg);

  // param table (dict order indices 3..24)
  PtrTab tab;
  int sizes[NPAR];
  for (int l = 0; l < 4; l++){
    int base = 3 + 4 * l;
    tab.p[4 * l + 0] = d_in[base + 0]; sizes[4 * l + 0] = (l < 3) ? 16384 : 8192;
    tab.p[4 * l + 1] = d_in[base + 1]; sizes[4 * l + 1] = (l < 3) ? 128 : 64;
    tab.p[4 * l + 2] = d_in[base + 2]; sizes[4 * l + 2] = (l < 3) ? 128 : 64;
    tab.p[4 * l + 3] = d_in[base + 3]; sizes[4 * l + 3] = (l < 3) ? 128 : 64;
  }
  for (int l = 0; l < 3; l++){
    tab.p[16 + 2 * l]     = d_in[19 + 2 * l];     sizes[16 + 2 * l] = 128;
    tab.p[16 + 2 * l + 1] = d_in[19 + 2 * l + 1]; sizes[16 + 2 * l + 1] = 128;
  }
  tab.off[0] = 0;
  for (int k = 0; k < NPAR; k++) tab.off[k + 1] = tab.off[k] + sizes[k];
  const float* pAS[4], *pAD[4], *pB[4], *pG[3], *pBE[3];
  for (int l = 0; l < 4; l++){
    pAS[l] = par + tab.off[4 * l + 1];
    pAD[l] = par + tab.off[4 * l + 2];
    pB[l]  = par + tab.off[4 * l + 3];
  }
  for (int l = 0; l < 3; l++){
    pG[l]  = par + tab.off[16 + 2 * l];
    pBE[l] = par + tab.off[16 + 2 * l + 1];
  }
  const _Float16* pWT[4] = { wt16, wt16 + 16384, wt16 + 32768, wt16 + 49152 };
  float* bnS[3], *bnQ[3];
  for (int l = 0; l < 3; l++){ bnS[l] = bnbuf + 256 * l; bnQ[l] = bnbuf + 256 * l + 128; }

  hipMemsetAsync(zbeg, 0, zlen, stream);

  // dtype detect + param prep (merged)
  k_detect<<<1, 256, 0, stream>>>(x, ei, flags);
  k_prep<<<(PAR_TOTAL + WT_TOTAL + 255) / 256, 256, 0, stream>>>(
      tab, flags, par, d_in[3], d_in[7], d_in[11], d_in[15], wt16);

  // CSR build (wide 4-phase)
  k_count<<<NBLKC, 256, 0, stream>>>(ei, flags, cntmat);
  k_scanmat<<<1, 256, 0, stream>>>(cntmat, gbase, bbase);
  k_binscatter<<<NBLKC, 256, 0, stream>>>(ei, flags, gbase, ebuf2);
  k_csrD<<<NB, 256, 0, stream>>>(ebuf2, bbase, offs, ssrc, N_NODES);

  int gemmBlocks = (N_NODES + 63) / 64;
  int attnBlocks = (N_NODES + 15) / 16;

  // layer 0
  k_gemm<128, true><<<gemmBlocks, 256, 0, stream>>>(
      (const void*)x, flags, nullptr, nullptr, nullptr, nullptr,
      pWT[0], pAS[0], pAD[0], h16, als, ald, N_NODES);
  k_attn<4, 32, true><<<attnBlocks, 256, 0, stream>>>(h16, als, ald, offs, ssrc, pB[0],
                                                      (void*)a16, N_NODES);
  k_bn_stats<<<256, 256, 0, stream>>>(a16, bnS[0], bnQ[0], N_NODES);
  // layers 1,2
  for (int l = 1; l < 3; l++){
    k_gemm<128, false><<<gemmBlocks, 256, 0, stream>>>(
        (const void*)a16, flags, bnS[l-1], bnQ[l-1], pG[l-1], pBE[l-1],
        pWT[l], pAS[l], pAD[l], h16, als, ald, N_NODES);
    k_attn<4, 32, true><<<attnBlocks, 256, 0, stream>>>(h16, als, ald, offs, ssrc, pB[l],
                                                        (void*)a16, N_NODES);
    k_bn_stats<<<256, 256, 0, stream>>>(a16, bnS[l], bnQ[l], N_NODES);
  }
  // final layer (1 head, 64 ch)
  k_gemm<64, false><<<gemmBlocks, 256, 0, stream>>>(
      (const void*)a16, flags, bnS[2], bnQ[2], pG[2], pBE[2],
      pWT[3], pAS[3], pAD[3], h16, als, ald, N_NODES);
  k_attn<1, 64, false><<<attnBlocks, 256, 0, stream>>>(h16, als, ald, offs, ssrc, pB[3],
                                                       (void*)Afin, N_NODES);

  // global mean pool
  k_pool_acc<<<(N_NODES + 127) / 128, 256, 0, stream>>>(Afin, bids, flags, psum, gcnt, N_NODES);
  k_pool_fin<<<16, 256, 0, stream>>>(psum, gcnt, (float*)d_out);
}

// Round 10
// 437.073 us; speedup vs baseline: 1.9941x; 1.1705x over previous
//
#include <hip/hip_runtime.h>

#define DEVINL __device__ __forceinline__

constexpr int N_NODES = 50000;
constexpr int E_EDGES = 800000;
constexpr int HD      = 128;
constexpr int NG      = 64;
constexpr int OUTC    = 64;
constexpr int NPAR    = 22;
constexpr int PAR_TOTAL = 3*(16384+3*128) + (8192+3*64) + 6*128;  // 59456
constexpr int WT_TOTAL = 3*128*128 + 64*128;     // 57344 fp16
constexpr int NB      = (N_NODES + 1023) / 1024; // 49 buckets
constexpr int EBC     = 2048;
constexpr int NBLKC   = (E_EDGES + EBC - 1) / EBC; // 391
constexpr int BNSLOTS = 16;

typedef _Float16 half8_t __attribute__((ext_vector_type(8)));
typedef _Float16 half4_t __attribute__((ext_vector_type(4)));
typedef float    float4_t __attribute__((ext_vector_type(4)));

DEVINL float bf2f(unsigned short u){
  union { unsigned int i; float f; } v; v.i = ((unsigned int)u) << 16; return v.f;
}
DEVINL float lrelu(float v){ return v > 0.f ? v : 0.2f * v; }

// ---------------- param conversion + W transpose + dtype sniff (merged) ----------------
struct PtrTab { const void* p[NPAR]; int off[NPAR + 1]; };

__global__ void k_prep(PtrTab tab, const unsigned short* __restrict__ x,
                       const int* __restrict__ ei, int* __restrict__ flags,
                       float* __restrict__ dst,
                       const void* __restrict__ W0, const void* __restrict__ W1,
                       const void* __restrict__ W2, const void* __restrict__ W3,
                       _Float16* __restrict__ wt16){
  __shared__ int s_f32, s_i64;
  int t = threadIdx.x;
  if (t == 0){ s_f32 = 0; s_i64 = 1; }
  __syncthreads();
  for (int i = t; i < 2048; i += 256){
    float v = bf2f(x[i]);
    if (!(fabsf(v) < 1e4f)) s_f32 = 1;
  }
  for (int i = t; i < 512; i += 256){
    if (ei[2 * i + 1] != 0) s_i64 = 0;
  }
  __syncthreads();
  int f = s_f32;
  if (blockIdx.x == 0 && t == 0){ flags[0] = s_i64; flags[1] = s_f32; }

  int i = blockIdx.x * 256 + t;
  if (i < PAR_TOTAL){
    int k = 0;
    while (tab.off[k + 1] <= i) k++;
    int j = i - tab.off[k];
    dst[i] = f ? ((const float*)tab.p[k])[j] : bf2f(((const unsigned short*)tab.p[k])[j]);
    return;
  }
  int w = i - PAR_TOTAL;
  if (w >= WT_TOTAL) return;
  const void* W; int base, Mt;
  if (w < 49152){ int l = w >> 14; base = w & 16383; Mt = 128; W = (l == 0) ? W0 : (l == 1 ? W1 : W2); }
  else { base = w - 49152; Mt = 64; W = W3; }
  int nn = base >> 7, k = base & 127;
  float val = f ? ((const float*)W)[(size_t)k * Mt + nn]
                : bf2f(((const unsigned short*)W)[(size_t)k * Mt + nn]);
  wt16[w] = (_Float16)val;
}

// ---------------- CSR build: wide 4-phase ----------------
__global__ __launch_bounds__(256) void k_count(const int* __restrict__ ei,
                      const int* __restrict__ flags, int* __restrict__ cntmat){
  __shared__ int cnt[NB];
  int t = threadIdx.x, blk = blockIdx.x;
  if (t < NB) cnt[t] = 0;
  __syncthreads();
  int f = flags[0];
  int e0 = blk * EBC;
  #pragma unroll
  for (int j = 0; j < EBC / 256; j++){
    int e = e0 + t + j * 256;
    if (e < E_EDGES){
      int d = ei[(size_t)(E_EDGES + e) << f];
      atomicAdd(&cnt[d >> 10], 1);
    }
  }
  __syncthreads();
  if (t < NB) cntmat[blk * NB + t] = cnt[t];
}

__global__ void k_scanmat(const int* __restrict__ cntmat, int* __restrict__ gbase,
                          int* __restrict__ bbase){
  __shared__ int cbase[NB + 1];
  __shared__ int csum[NB];
  int t = threadIdx.x;
  int s = 0;
  if (t < NB){
    for (int blk = 0; blk < NBLKC; blk++) s += cntmat[blk * NB + t];
    csum[t] = s;
  }
  __syncthreads();
  if (t == 0){
    int run = 0;
    for (int b = 0; b < NB; b++){ cbase[b] = run; run += csum[b]; }
    cbase[NB] = run;
  }
  __syncthreads();
  if (t <= NB) bbase[t] = cbase[t];
  if (t < NB){
    int run = cbase[t];
    for (int blk = 0; blk < NBLKC; blk++){
      gbase[blk * NB + t] = run;
      run += cntmat[blk * NB + t];
    }
  }
}

__global__ __launch_bounds__(256) void k_binscatter(const int* __restrict__ ei,
                      const int* __restrict__ flags, const int* __restrict__ gbase,
                      unsigned int* __restrict__ ebuf2){
  __shared__ int cur[NB];
  int t = threadIdx.x, blk = blockIdx.x;
  if (t < NB) cur[t] = gbase[blk * NB + t];
  __syncthreads();
  int f = flags[0];
  int e0 = blk * EBC;
  #pragma unroll
  for (int j = 0; j < EBC / 256; j++){
    int e = e0 + t + j * 256;
    if (e < E_EDGES){
      int s = ei[(size_t)e << f];
      int d = ei[(size_t)(E_EDGES + e) << f];
      int p = atomicAdd(&cur[d >> 10], 1);
      ebuf2[p] = (unsigned int)s | ((unsigned int)d << 16);
    }
  }
}

__global__ __launch_bounds__(256) void k_csrD(const unsigned int* __restrict__ ebuf2,
                      const int* __restrict__ bbase, int* __restrict__ offs,
                      int* __restrict__ ssrc, int n){
  __shared__ int hist[1024];
  __shared__ int wsum[256];
  int t = threadIdx.x, b = blockIdx.x;
  int nbase = b << 10;
  int s0 = bbase[b], s1 = bbase[b + 1];
  for (int i = t; i < 1024; i += 256) hist[i] = 0;
  __syncthreads();
  for (int i = s0 + t; i < s1; i += 256){
    unsigned int pk = ebuf2[i];
    atomicAdd(&hist[(int)(pk >> 16) - nbase], 1);
  }
  __syncthreads();
  int base4 = t * 4;
  int v0 = hist[base4], v1 = hist[base4 + 1], v2 = hist[base4 + 2], v3 = hist[base4 + 3];
  int s = v0 + v1 + v2 + v3;
  wsum[t] = s; __syncthreads();
  for (int off = 1; off < 256; off <<= 1){
    int x2 = (t >= off) ? wsum[t - off] : 0;
    __syncthreads();
    wsum[t] += x2;
    __syncthreads();
  }
  int run = s0 + wsum[t] - s;
  int node = nbase + base4;
  if (node < n) offs[node] = run;  hist[base4] = run;  run += v0;
  if (node + 1 < n) offs[node + 1] = run;  hist[base4 + 1] = run;  run += v1;
  if (node + 2 < n) offs[node + 2] = run;  hist[base4 + 2] = run;  run += v2;
  if (node + 3 < n) offs[node + 3] = run;  hist[base4 + 3] = run;
  if (b == NB - 1 && t == 255) offs[n] = s1;
  __syncthreads();
  for (int i = s0 + t; i < s1; i += 256){
    unsigned int pk = ebuf2[i];
    int p = atomicAdd(&hist[(int)(pk >> 16) - nbase], 1);
    ssrc[p] = (int)(pk & 0xFFFFu);
  }
}

// ---------------- fused MFMA GEMM ----------------
// FIRST: Ain = raw x. else: Ain = fp16 post-attn; BN (from 16 partial slots)+ELU fused.
template<int MT, bool FIRST>
__global__ __launch_bounds__(256) void k_gemm(
    const void* __restrict__ Ain, const int* __restrict__ flags,
    const float* __restrict__ bnslots,
    const float* __restrict__ g, const float* __restrict__ be,
    const _Float16* __restrict__ Wt16,
    const float* __restrict__ a_s, const float* __restrict__ a_d,
    _Float16* __restrict__ h16, float* __restrict__ als, float* __restrict__ ald,
    int n){
  __shared__ _Float16 AhL[64 * 136];
  __shared__ _Float16 WtL[MT * 72];
  __shared__ float scale[128], shift[128];
  const int t = threadIdx.x;
  const int rowBase = blockIdx.x * 64;
  if (!FIRST){
    if (t < 128){
      float s = 0.f, q = 0.f;
      #pragma unroll
      for (int sl = 0; sl < BNSLOTS; sl++){
        s += bnslots[sl * 256 + t];
        q += bnslots[sl * 256 + 128 + t];
      }
      float inv_n = 1.f / (float)n;
      float mu = s * inv_n;
      float var = q * inv_n - mu * mu;
      float sc = g[t] * rsqrtf(var + 1e-5f);
      scale[t] = sc; shift[t] = be[t] - mu * sc;
    }
    __syncthreads();
  }
  for (int f = t; f < 64 * 16; f += 256){
    int r = f >> 4, c8 = (f & 15) << 3;
    int row = rowBase + r;
    float v[8];
    if (row < n){
      if (FIRST){
        if (flags[1]){
          float4 x0 = *(const float4*)((const float*)Ain + (size_t)row * 128 + c8);
          float4 x1 = *(const float4*)((const float*)Ain + (size_t)row * 128 + c8 + 4);
          v[0]=x0.x; v[1]=x0.y; v[2]=x0.z; v[3]=x0.w;
          v[4]=x1.x; v[5]=x1.y; v[6]=x1.z; v[7]=x1.w;
        } else {
          const unsigned short* xp = (const unsigned short*)Ain + (size_t)row * 128 + c8;
          ushort4 u0 = *(const ushort4*)xp; ushort4 u1 = *(const ushort4*)(xp + 4);
          v[0]=bf2f(u0.x); v[1]=bf2f(u0.y); v[2]=bf2f(u0.z); v[3]=bf2f(u0.w);
          v[4]=bf2f(u1.x); v[5]=bf2f(u1.y); v[6]=bf2f(u1.z); v[7]=bf2f(u1.w);
        }
      } else {
        half8_t a8 = *(const half8_t*)((const _Float16*)Ain + (size_t)row * 128 + c8);
        #pragma unroll
        for (int j = 0; j < 8; j++){
          float xv = (float)a8[j] * scale[c8 + j] + shift[c8 + j];
          v[j] = xv > 0.f ? xv : (__expf(xv) - 1.f);
        }
      }
    } else {
      #pragma unroll
      for (int j = 0; j < 8; j++) v[j] = 0.f;
    }
    half8_t h;
    #pragma unroll
    for (int j = 0; j < 8; j++) h[j] = (_Float16)v[j];
    *(half8_t*)&AhL[r * 136 + c8] = h;
  }
  const int lane = t & 63;
  const int m = lane & 15, quad = lane >> 4;
  const int band = (t >> 6) * 16;
  float4_t acc[MT / 16];
  #pragma unroll
  for (int ct = 0; ct < MT / 16; ct++) acc[ct] = (float4_t){0.f, 0.f, 0.f, 0.f};
  #pragma unroll
  for (int kh = 0; kh < 2; kh++){
    __syncthreads();
    for (int f = t; f < MT * 8; f += 256){
      int nn = f >> 3, c8 = (f & 7) << 3;
      *(half8_t*)&WtL[nn * 72 + c8] = *(const half8_t*)&Wt16[nn * 128 + kh * 64 + c8];
    }
    __syncthreads();
    half8_t a0 = *(half8_t*)&AhL[(band + m) * 136 + kh * 64 + quad * 8];
    half8_t a1 = *(half8_t*)&AhL[(band + m) * 136 + kh * 64 + 32 + quad * 8];
    #pragma unroll
    for (int ct = 0; ct < MT / 16; ct++){
      half8_t b0 = *(half8_t*)&WtL[(ct * 16 + m) * 72 + quad * 8];
      half8_t b1 = *(half8_t*)&WtL[(ct * 16 + m) * 72 + 32 + quad * 8];
      acc[ct] = __builtin_amdgcn_mfma_f32_16x16x32_f16(a0, b0, acc[ct], 0, 0, 0);
      acc[ct] = __builtin_amdgcn_mfma_f32_16x16x32_f16(a1, b1, acc[ct], 0, 0, 0);
    }
  }
  __syncthreads();
  #pragma unroll
  for (int ct = 0; ct < MT / 16; ct++)
    #pragma unroll
    for (int rg = 0; rg < 4; rg++)
      AhL[(band + quad * 4 + rg) * 136 + ct * 16 + m] = (_Float16)acc[ct][rg];
  __syncthreads();
  int r = t >> 2, q = t & 3;
  int row = rowBase + r;
  if (MT == 128){
    if (row < n){
      half8_t h0 = *(half8_t*)&AhL[r * 136 + q * 32];
      half8_t h1 = *(half8_t*)&AhL[r * 136 + q * 32 + 8];
      half8_t h2 = *(half8_t*)&AhL[r * 136 + q * 32 + 16];
      half8_t h3 = *(half8_t*)&AhL[r * 136 + q * 32 + 24];
      float pas = 0.f, pad = 0.f;
      #pragma unroll
      for (int j = 0; j < 8; j++){
        pas += (float)h0[j] * a_s[q * 32 + j]      + (float)h1[j] * a_s[q * 32 + 8 + j]
             + (float)h2[j] * a_s[q * 32 + 16 + j] + (float)h3[j] * a_s[q * 32 + 24 + j];
        pad += (float)h0[j] * a_d[q * 32 + j]      + (float)h1[j] * a_d[q * 32 + 8 + j]
             + (float)h2[j] * a_d[q * 32 + 16 + j] + (float)h3[j] * a_d[q * 32 + 24 + j];
      }
      als[(size_t)row * 4 + q] = pas;
      ald[(size_t)row * 4 + q] = pad;
      _Float16* hp = h16 + (size_t)row * 128 + q * 32;
      *(half8_t*)hp = h0; *(half8_t*)(hp + 8) = h1;
      *(half8_t*)(hp + 16) = h2; *(half8_t*)(hp + 24) = h3;
    }
  } else {
    half8_t h0 = *(half8_t*)&AhL[r * 136 + q * 16];
    half8_t h1 = *(half8_t*)&AhL[r * 136 + q * 16 + 8];
    float pas = 0.f, pad = 0.f;
    #pragma unroll
    for (int j = 0; j < 8; j++){
      pas += (float)h0[j] * a_s[q * 16 + j] + (float)h1[j] * a_s[q * 16 + 8 + j];
      pad += (float)h0[j] * a_d[q * 16 + j] + (float)h1[j] * a_d[q * 16 + 8 + j];
    }
    pas += __shfl_xor(pas, 1); pas += __shfl_xor(pas, 2);
    pad += __shfl_xor(pad, 1); pad += __shfl_xor(pad, 2);
    if (row < n){
      _Float16* hp = h16 + (size_t)row * 64 + q * 16;
      *(half8_t*)hp = h0; *(half8_t*)(hp + 8) = h1;
      if (q == 0){ als[row] = pas; ald[row] = pad; }
    }
  }
}

// ---------------- per-node GAT attention + aggregation (fused epilogues) ----------------
// 16-lane group per node; per-lane ssum; 8-wide gather unroll.
// MODE 0: fp16 out + BN partial sums into 16 slots. MODE 1: fused mean-pool.
// Grid is exactly n/16 blocks (n % 16 == 0) — no early returns (LDS sync).
template<int H, int C, int MODE>
__global__ __launch_bounds__(256) void k_attn(const _Float16* __restrict__ h16,
                      const float* __restrict__ als, const float* __restrict__ ald,
                      const int* __restrict__ offs, const int* __restrict__ ssrc,
                      const float* __restrict__ bias,
                      _Float16* __restrict__ a16out, float* __restrict__ bnout,
                      const int* __restrict__ bids, const int* __restrict__ flags,
                      float* __restrict__ psum, int* __restrict__ gcnt, int n){
  constexpr int HC = H * C;
  constexpr int CPL = HC / 16;                 // 8 (4x32) or 4 (1x64)
  int t = threadIdx.x;
  int nib  = t >> 4;                           // node in block
  int node = blockIdx.x * 16 + nib;
  int sub  = t & 15;
  int c0   = sub * CPL;
  int head = c0 / C;

  float ald_h = ald[(size_t)node * H + head];
  float acc[CPL];
  float ssum;
  {
    float w = __expf(lrelu(als[(size_t)node * H + head] + ald_h));
    ssum = w;
    const _Float16* hp = h16 + (size_t)node * HC + c0;
    #pragma unroll
    for (int i = 0; i < CPL; i++) acc[i] = w * (float)hp[i];
  }
  int beg = offs[node];
  int deg = offs[node + 1] - beg;
  int j = 0;
  // 8-wide: 8 independent src->als,h chains in flight
  for (; j + 8 <= deg; j += 8){
    int ss[8]; float al[8]; float w[8];
    #pragma unroll
    for (int u = 0; u < 8; u++) ss[u] = ssrc[beg + j + u];
    #pragma unroll
    for (int u = 0; u < 8; u++) al[u] = als[(size_t)ss[u] * H + head];
    if constexpr (CPL == 8){
      half8_t v[8];
      #pragma unroll
      for (int u = 0; u < 8; u++) v[u] = *(const half8_t*)(h16 + (size_t)ss[u] * HC + c0);
      #pragma unroll
      for (int u = 0; u < 8; u++){ w[u] = __expf(lrelu(al[u] + ald_h)); ssum += w[u]; }
      #pragma unroll
      for (int i = 0; i < 8; i++){
        float a = 0.f;
        #pragma unroll
        for (int u = 0; u < 8; u++) a += w[u] * (float)v[u][i];
        acc[i] += a;
      }
    } else {
      half4_t v[8];
      #pragma unroll
      for (int u = 0; u < 8; u++) v[u] = *(const half4_t*)(h16 + (size_t)ss[u] * HC + c0);
      #pragma unroll
      for (int u = 0; u < 8; u++){ w[u] = __expf(lrelu(al[u] + ald_h)); ssum += w[u]; }
      #pragma unroll
      for (int i = 0; i < 4; i++){
        float a = 0.f;
        #pragma unroll
        for (int u = 0; u < 8; u++) a += w[u] * (float)v[u][i];
        acc[i] += a;
      }
    }
  }
  for (; j + 4 <= deg; j += 4){
    int s0 = ssrc[beg + j], s1 = ssrc[beg + j + 1];
    int s2 = ssrc[beg + j + 2], s3 = ssrc[beg + j + 3];
    float al0 = als[(size_t)s0 * H + head], al1 = als[(size_t)s1 * H + head];
    float al2 = als[(size_t)s2 * H + head], al3 = als[(size_t)s3 * H + head];
    float w0 = __expf(lrelu(al0 + ald_h)), w1 = __expf(lrelu(al1 + ald_h));
    float w2 = __expf(lrelu(al2 + ald_h)), w3 = __expf(lrelu(al3 + ald_h));
    ssum += (w0 + w1) + (w2 + w3);
    if constexpr (CPL == 8){
      half8_t v0 = *(const half8_t*)(h16 + (size_t)s0 * HC + c0);
      half8_t v1 = *(const half8_t*)(h16 + (size_t)s1 * HC + c0);
      half8_t v2 = *(const half8_t*)(h16 + (size_t)s2 * HC + c0);
      half8_t v3 = *(const half8_t*)(h16 + (size_t)s3 * HC + c0);
      #pragma unroll
      for (int i = 0; i < 8; i++)
        acc[i] += w0 * (float)v0[i] + w1 * (float)v1[i]
                + w2 * (float)v2[i] + w3 * (float)v3[i];
    } else {
      half4_t v0 = *(const half4_t*)(h16 + (size_t)s0 * HC + c0);
      half4_t v1 = *(const half4_t*)(h16 + (size_t)s1 * HC + c0);
      half4_t v2 = *(const half4_t*)(h16 + (size_t)s2 * HC + c0);
      half4_t v3 = *(const half4_t*)(h16 + (size_t)s3 * HC + c0);
      #pragma unroll
      for (int i = 0; i < 4; i++)
        acc[i] += w0 * (float)v0[i] + w1 * (float)v1[i]
                + w2 * (float)v2[i] + w3 * (float)v3[i];
    }
  }
  for (; j < deg; j++){
    int s0 = ssrc[beg + j];
    float w0 = __expf(lrelu(als[(size_t)s0 * H + head] + ald_h));
    ssum += w0;
    const _Float16* hp = h16 + (size_t)s0 * HC + c0;
    #pragma unroll
    for (int i = 0; i < CPL; i++) acc[i] += w0 * (float)hp[i];
  }
  float inv_s = 1.f / ssum;
  float v[CPL];
  #pragma unroll
  for (int i = 0; i < CPL; i++) v[i] = acc[i] * inv_s + bias[c0 + i];

  if constexpr (MODE == 0){
    // fp16 store + BN partial-sum epilogue
    _Float16* op = a16out + (size_t)node * HC + c0;
    half8_t o;
    #pragma unroll
    for (int i = 0; i < CPL; i++) o[i] = (_Float16)v[i];
    *(half8_t*)op = o;
    __shared__ float red[16][132];
    *(float4*)&red[nib][c0]     = make_float4(v[0], v[1], v[2], v[3]);
    *(float4*)&red[nib][c0 + 4] = make_float4(v[4], v[5], v[6], v[7]);
    __syncthreads();
    if (t < 128){
      float s = 0.f, q = 0.f;
      #pragma unroll
      for (int i = 0; i < 16; i++){ float x = red[i][t]; s += x; q += x * x; }
      int slot = blockIdx.x & (BNSLOTS - 1);
      atomicAdd(&bnout[slot * 256 + t], s);
      atomicAdd(&bnout[slot * 256 + 128 + t], q);
    }
  } else {
    // fused global-mean-pool epilogue (block spans <=2 sorted graphs normally)
    __shared__ float pacc[2][64];
    __shared__ int pcnt[2];
    int f = flags[0];
    if (t < 128) pacc[t >> 6][t & 63] = 0.f;
    if (t < 2) pcnt[t] = 0;
    __syncthreads();
    int g  = (int)bids[(size_t)node << f];
    int g0 = (int)bids[(size_t)(blockIdx.x * 16) << f];
    int g1 = (int)bids[(size_t)(blockIdx.x * 16 + 15) << f];
    if (g1 - g0 <= 1){
      int gl = g - g0;
      #pragma unroll
      for (int i = 0; i < 4; i++) atomicAdd(&pacc[gl][c0 + i], v[i]);
      if (sub == 0) atomicAdd(&pcnt[gl], 1);
      __syncthreads();
      if (t < 128){
        int gl2 = t >> 6;
        if (pcnt[gl2] > 0) atomicAdd(&psum[(g0 + gl2) * 64 + (t & 63)], pacc[gl2][t & 63]);
      }
      if (t < 2 && pcnt[t] > 0) atomicAdd(&gcnt[g0 + t], pcnt[t]);
    } else {
      #pragma unroll
      for (int i = 0; i < 4; i++) atomicAdd(&psum[g * 64 + c0 + i], v[i]);
      if (sub == 0) atomicAdd(&gcnt[g], 1);
      __syncthreads();
    }
  }
}

__global__ void k_pool_fin(const float* __restrict__ psum, const int* __restrict__ gcnt,
                           float* __restrict__ out){
  int i = blockIdx.x * 256 + threadIdx.x;
  if (i >= NG * OUTC) return;
  int cnt = gcnt[i >> 6];
  out[i] = psum[i] / (float)(cnt > 1 ? cnt : 1);
}

extern "C" void kernel_launch(void* const* d_in, const int* in_sizes, int n_in,
                              void* d_out, int out_size, void* d_ws, size_t ws_size,
                              hipStream_t stream){
  const unsigned short* x    = (const unsigned short*)d_in[0];
  const int*            ei   = (const int*)d_in[1];
  const int*            bids = (const int*)d_in[2];

  char* p = (char*)d_ws;
  auto carve = [&](size_t bytes) -> void* {
    void* r = (void*)p; p += (bytes + 255) & ~size_t(255); return r;
  };
  _Float16* a16    = (_Float16*)carve((size_t)N_NODES * HD * 2);
  _Float16* h16    = (_Float16*)carve((size_t)N_NODES * HD * 2);
  float*    par    = (float*)carve((size_t)PAR_TOTAL * 4);
  _Float16* wt16   = (_Float16*)carve((size_t)WT_TOTAL * 2);
  float*    als    = (float*)carve((size_t)N_NODES * 4 * 4);
  float*    ald    = (float*)carve((size_t)N_NODES * 4 * 4);
  int*      offs   = (int*)carve((size_t)(N_NODES + 1) * 4);
  int*      ssrc   = (int*)carve((size_t)E_EDGES * 4);
  unsigned int* ebuf2 = (unsigned int*)carve((size_t)E_EDGES * 4);
  int*      cntmat = (int*)carve((size_t)NBLKC * NB * 4);
  int*      gbase  = (int*)carve((size_t)NBLKC * NB * 4);
  int*      bbase  = (int*)carve((size_t)(NB + 1) * 4);
  int*      flags  = (int*)carve(256);
  // contiguous zero-region (single memset)
  char*     zbeg   = p;
  float*    bnbuf  = (float*)carve((size_t)3 * BNSLOTS * 256 * 4);  // 48 KB
  float*    psum   = (float*)carve(NG * OUTC * 4);
  int*      gcnt   = (int*)carve(256);
  size_t    zlen   = (size_t)(p - zbeg);

  // param table (dict order indices 3..24)
  PtrTab tab;
  int sizes[NPAR];
  for (int l = 0; l < 4; l++){
    int base = 3 + 4 * l;
    tab.p[4 * l + 0] = d_in[base + 0]; sizes[4 * l + 0] = (l < 3) ? 16384 : 8192;
    tab.p[4 * l + 1] = d_in[base + 1]; sizes[4 * l + 1] = (l < 3) ? 128 : 64;
    tab.p[4 * l + 2] = d_in[base + 2]; sizes[4 * l + 2] = (l < 3) ? 128 : 64;
    tab.p[4 * l + 3] = d_in[base + 3]; sizes[4 * l + 3] = (l < 3) ? 128 : 64;
  }
  for (int l = 0; l < 3; l++){
    tab.p[16 + 2 * l]     = d_in[19 + 2 * l];     sizes[16 + 2 * l] = 128;
    tab.p[16 + 2 * l + 1] = d_in[19 + 2 * l + 1]; sizes[16 + 2 * l + 1] = 128;
  }
  tab.off[0] = 0;
  for (int k = 0; k < NPAR; k++) tab.off[k + 1] = tab.off[k] + sizes[k];
  const float* pAS[4], *pAD[4], *pB[4], *pG[3], *pBE[3];
  for (int l = 0; l < 4; l++){
    pAS[l] = par + tab.off[4 * l + 1];
    pAD[l] = par + tab.off[4 * l + 2];
    pB[l]  = par + tab.off[4 * l + 3];
  }
  for (int l = 0; l < 3; l++){
    pG[l]  = par + tab.off[16 + 2 * l];
    pBE[l] = par + tab.off[16 + 2 * l + 1];
  }
  const _Float16* pWT[4] = { wt16, wt16 + 16384, wt16 + 32768, wt16 + 49152 };
  float* bnS[3];
  for (int l = 0; l < 3; l++) bnS[l] = bnbuf + (size_t)l * BNSLOTS * 256;

  hipMemsetAsync(zbeg, 0, zlen, stream);

  // prep (self-sniffing dtype flags)
  k_prep<<<(PAR_TOTAL + WT_TOTAL + 255) / 256, 256, 0, stream>>>(
      tab, x, ei, flags, par, d_in[3], d_in[7], d_in[11], d_in[15], wt16);

  // CSR build (wide 4-phase)
  k_count<<<NBLKC, 256, 0, stream>>>(ei, flags, cntmat);
  k_scanmat<<<1, 256, 0, stream>>>(cntmat, gbase, bbase);
  k_binscatter<<<NBLKC, 256, 0, stream>>>(ei, flags, gbase, ebuf2);
  k_csrD<<<NB, 256, 0, stream>>>(ebuf2, bbase, offs, ssrc, N_NODES);

  int gemmBlocks = (N_NODES + 63) / 64;
  int attnBlocks = N_NODES / 16;   // 3125, exact

  // layer 0
  k_gemm<128, true><<<gemmBlocks, 256, 0, stream>>>(
      (const void*)x, flags, nullptr, nullptr, nullptr,
      pWT[0], pAS[0], pAD[0], h16, als, ald, N_NODES);
  k_attn<4, 32, 0><<<attnBlocks, 256, 0, stream>>>(h16, als, ald, offs, ssrc, pB[0],
      a16, bnS[0], nullptr, nullptr, nullptr, nullptr, N_NODES);
  // layers 1,2
  for (int l = 1; l < 3; l++){
    k_gemm<128, false><<<gemmBlocks, 256, 0, stream>>>(
        (const void*)a16, flags, bnS[l-1], pG[l-1], pBE[l-1],
        pWT[l], pAS[l], pAD[l], h16, als, ald, N_NODES);
    k_attn<4, 32, 0><<<attnBlocks, 256, 0, stream>>>(h16, als, ald, offs, ssrc, pB[l],
        a16, bnS[l], nullptr, nullptr, nullptr, nullptr, N_NODES);
  }
  // final layer (1 head, 64 ch) + fused pool
  k_gemm<64, false><<<gemmBlocks, 256, 0, stream>>>(
      (const void*)a16, flags, bnS[2], pG[2], pBE[2],
      pWT[3], pAS[3], pAD[3], h16, als, ald, N_NODES);
  k_attn<1, 64, 1><<<attnBlocks, 256, 0, stream>>>(h16, als, ald, offs, ssrc, pB[3],
      nullptr, nullptr, bids, flags, psum, gcnt, N_NODES);

  k_pool_fin<<<16, 256, 0, stream>>>(psum, gcnt, (float*)d_out);
}